// Round 8
// baseline (469.326 us; speedup 1.0000x reference)
//
#include <hip/hip_runtime.h>
#include <stdint.h>

#define NN 20000
#define NE 160000
#define NG 500
#define FIN 128
#define HID 512
#define NCLS 10
#define BNG 256

typedef __attribute__((ext_vector_type(8))) short short8;
typedef __attribute__((ext_vector_type(4))) float f32x4;
typedef __attribute__((ext_vector_type(4))) unsigned short ushort4v;

__device__ __forceinline__ float bf2f(unsigned int u){
  union{unsigned int i; float f;} x; x.i = u<<16; return x.f;
}
__device__ __forceinline__ unsigned short f2bf(float f){
  union{float f; unsigned int i;} x; x.f=f;
  unsigned int r = x.i + 0x7fffu + ((x.i>>16)&1u);
  return (unsigned short)(r>>16);
}
__device__ __forceinline__ unsigned int pk2(float a, float b){
  return (unsigned int)f2bf(a) | ((unsigned int)f2bf(b) << 16);
}

__device__ __forceinline__ void gload16(unsigned short* lds, const unsigned short* g){
  __builtin_amdgcn_global_load_lds((const __attribute__((address_space(1))) unsigned int*)g,
                                   (__attribute__((address_space(3))) unsigned int*)lds,
                                   16, 0, 0);
}

__device__ __forceinline__ void fma8(float* acc, uint4 v, float w){
  acc[0] += w*bf2f(v.x & 0xffffu); acc[1] += w*bf2f(v.x >> 16);
  acc[2] += w*bf2f(v.y & 0xffffu); acc[3] += w*bf2f(v.y >> 16);
  acc[4] += w*bf2f(v.z & 0xffffu); acc[5] += w*bf2f(v.z >> 16);
  acc[6] += w*bf2f(v.w & 0xffffu); acc[7] += w*bf2f(v.w >> 16);
}

__global__ void sentinel_k(float* out){ out[0] = 12345.0f; }

// ---------------- setup: all weight transposes + all init in one dispatch ----------------
struct W2BT { const float* src[9]; unsigned short* dst[9]; };
__global__ void setup_all(W2BT p, int* __restrict__ cnt, int* __restrict__ fillc,
                          float* __restrict__ degc, float* __restrict__ dego,
                          float* __restrict__ Sc, float* __restrict__ So,
                          float* __restrict__ stats6){
  int idx = blockIdx.x*blockDim.x + threadIdx.x;
  if (idx < FIN*HID + 8*HID*HID){
    int seg, off, K;
    if (idx < FIN*HID){ seg = 0; off = idx; K = FIN; }
    else {
      int r = idx - FIN*HID;
      seg = 1 + (r >> 18); off = r & (HID*HID-1); K = HID;
    }
    int k = off >> 9, n = off & 511;
    p.dst[seg][(size_t)n*K + k] = f2bf(p.src[seg][off]);
  }
  if (idx < NN){ cnt[idx]=0; fillc[idx]=0; degc[idx]=1.0f; dego[idx]=1.0f; Sc[idx]=0.f; So[idx]=0.f; }
  if (idx < 6*1024) stats6[idx] = 0.f;
}

// ---------------- D1: csr_count + conv BN stats stage 1 (blockIdx split) ----------------
__global__ __launch_bounds__(1024) void d1_count_stats(const int* __restrict__ ei, int* __restrict__ cnt,
                                                       const float* __restrict__ X, float* __restrict__ partials){
  __shared__ float lds[1024*9];
  const int t = threadIdx.x;
  if (blockIdx.x >= BNG){
    int e = (blockIdx.x - BNG)*1024 + t;
    if (e < NE) atomicAdd(&cnt[ei[e]], 1);
    return;
  }
  // bnstats over x: F=FIN=128
  const int cg = FIN >> 2;            // 32
  const int cid = t & (cg-1);
  const int rid = t / cg;
  const int rpb = 1024 / cg;          // 32
  float s0=0,s1=0,s2=0,s3=0,q0=0,q1=0,q2=0,q3=0;
  const int rowsPer = (NN + BNG - 1)/BNG;
  int r0 = blockIdx.x*rowsPer, r1 = r0 + rowsPer; if (r1 > NN) r1 = NN;
  for (int r = r0 + rid; r < r1; r += rpb){
    float4 v = *(const float4*)&X[(size_t)r*FIN + cid*4];
    s0+=v.x; q0+=v.x*v.x; s1+=v.y; q1+=v.y*v.y; s2+=v.z; q2+=v.z*v.z; s3+=v.w; q3+=v.w*v.w;
  }
  int base = (rid*cg + cid)*9;
  lds[base+0]=s0; lds[base+1]=s1; lds[base+2]=s2; lds[base+3]=s3;
  lds[base+4]=q0; lds[base+5]=q1; lds[base+6]=q2; lds[base+7]=q3;
  __syncthreads();
  if (t < cg*8){
    int ci = t >> 3, i = t & 7;
    float acc = 0.f;
    for (int g=0; g<rpb; ++g) acc += lds[(g*cg + ci)*9 + i];
    int col = ci*4 + (i & 3);
    partials[(size_t)blockIdx.x*(2*FIN) + ((i < 4) ? col : FIN + col)] = acc;
  }
}

// ---------------- D2: scan1 + conv bnfin (blockIdx split) ----------------
__global__ __launch_bounds__(1024) void d2_scan_fin(const int* __restrict__ cnt, int* __restrict__ rowp,
                                                    float* __restrict__ dis1, int* __restrict__ bsum,
                                                    const float* __restrict__ partials, float* __restrict__ mstat){
  __shared__ int buf[1024];
  __shared__ float lds[4][64][2];
  int t = threadIdx.x;
  if (blockIdx.x < 20){
    int i = blockIdx.x*1024 + t;
    int v = 0;
    if (i < NN){ v = cnt[i] + 1; dis1[i] = rsqrtf((float)v); }
    buf[t] = v;
    __syncthreads();
    for (int off=1; off<1024; off<<=1){
      int xv = (t >= off) ? buf[t-off] : 0;
      __syncthreads();
      buf[t] += xv;
      __syncthreads();
    }
    if (i < NN) rowp[i+1] = buf[t];
    if (t == 1023) bsum[blockIdx.x] = buf[1023];
    return;
  }
  // bnfin for conv input (F=FIN, M=NN, 256 partial blocks, stride 2*FIN)
  if (t >= 256) return;
  int cl = t & 63, ch = t >> 6;
  int c = (blockIdx.x - 20)*64 + cl;
  float s = 0.f, q = 0.f;
  for (int b = ch*64; b < ch*64 + 64; ++b){
    s += partials[(size_t)b*(2*FIN) + c];
    q += partials[(size_t)b*(2*FIN) + FIN + c];
  }
  lds[ch][cl][0] = s; lds[ch][cl][1] = q;
  __syncthreads();
  if (ch == 0){
    s = lds[0][cl][0]+lds[1][cl][0]+lds[2][cl][0]+lds[3][cl][0];
    q = lds[0][cl][1]+lds[1][cl][1]+lds[2][cl][1]+lds[3][cl][1];
    float m = s/(float)NN;
    float v = q/(float)NN - m*m;
    mstat[c] = m;
    mstat[FIN+c] = rsqrtf(v + 1e-5f);
  }
}

// ---------------- D3: scan3 + conv bncast (blockIdx split) ----------------
__global__ __launch_bounds__(1024) void d3_scan_cast(int* __restrict__ rowp, const int* __restrict__ bsum,
                                                     const float* __restrict__ X, const float* __restrict__ mstat,
                                                     unsigned short* __restrict__ out){
  __shared__ int base;
  int t = threadIdx.x;
  if (blockIdx.x < 20){
    int bx = blockIdx.x;
    if (t == 0){
      int a = 0;
      for (int b=0; b<bx; ++b) a += bsum[b];
      base = a;
    }
    __syncthreads();
    int i = bx*1024 + t;
    if (i < NN) rowp[i+1] += base;
    if (i == 0) rowp[0] = 0;
    return;
  }
  int idx = (blockIdx.x - 20)*1024 + t;
  int total4 = NN*FIN/4;
  if (idx >= total4) return;
  int b4 = idx*4;
  int c = b4 & (FIN-1);
  float4 v = *(const float4*)&X[b4];
  ushort4v o;
  o[0] = f2bf((v.x - mstat[c+0])*mstat[FIN+c+0] + 1e-4f);
  o[1] = f2bf((v.y - mstat[c+1])*mstat[FIN+c+1] + 1e-4f);
  o[2] = f2bf((v.z - mstat[c+2])*mstat[FIN+c+2] + 1e-4f);
  o[3] = f2bf((v.w - mstat[c+3])*mstat[FIN+c+3] + 1e-4f);
  *(ushort4v*)&out[b4] = o;
}

// csr_fill + w1 fused; also builds interleaved {col, w1} pairs
__global__ void csr_fill(const int* __restrict__ ei, const int* __restrict__ rowp,
                         const int* __restrict__ cnt, int* __restrict__ fillc,
                         const float* __restrict__ dis1,
                         int* __restrict__ ccol, int* __restrict__ crow, int* __restrict__ ceid,
                         int2* __restrict__ cw1){
  int id = blockIdx.x*blockDim.x + threadIdx.x;
  if (id < NE){
    int r = ei[id], c = ei[NE + id];
    int pos = atomicAdd(&fillc[r], 1);
    int idx = rowp[r] + pos;
    ccol[idx] = c; crow[idx] = r; ceid[idx] = id;
    cw1[idx] = make_int2(c, __float_as_int(dis1[r]*dis1[c]));
  } else if (id < NE + NN){
    int i = id - NE;
    int idx = rowp[i] + cnt[i];
    ccol[idx] = i; crow[idx] = i; ceid[idx] = -1;
    cw1[idx] = make_int2(i, __float_as_int(dis1[i]*dis1[i]));
  }
}

// ---------------- dual BN stats on bf16 X ----------------
__global__ __launch_bounds__(1024) void bnstats_dual(const unsigned short* __restrict__ X,
                                                     const float* __restrict__ na,
                                                     float* __restrict__ partials){
  __shared__ float lds[1024*17];
  const int t = threadIdx.x;
  const int cid = t & 127;
  const int rid = t >> 7;
  float sC[4]={0,0,0,0}, qC[4]={0,0,0,0}, sO[4]={0,0,0,0}, qO[4]={0,0,0,0};
  const int rowsPer = (NN + BNG - 1)/BNG;
  int r0 = blockIdx.x*rowsPer, r1 = r0 + rowsPer; if (r1 > NN) r1 = NN;
  for (int r = r0 + rid; r < r1; r += 8){
    float a0 = na[2*r], a1 = na[2*r+1];
    uint2 u = *(const uint2*)&X[(size_t)r*HID + cid*4];
    float e[4] = {bf2f(u.x & 0xffffu), bf2f(u.x >> 16), bf2f(u.y & 0xffffu), bf2f(u.y >> 16)};
#pragma unroll
    for (int i=0;i<4;i++){
      float vc = e[i]*a0, vo = e[i]*a1;
      sC[i]+=vc; qC[i]+=vc*vc; sO[i]+=vo; qO[i]+=vo*vo;
    }
  }
  int base = (rid*128 + cid)*17;
#pragma unroll
  for (int i=0;i<4;i++){
    lds[base+i]=sC[i]; lds[base+4+i]=qC[i]; lds[base+8+i]=sO[i]; lds[base+12+i]=qO[i];
  }
  __syncthreads();
  for (int idx = t; idx < 2048; idx += 1024){
    int ci = idx >> 4, i = idx & 15;
    float acc = 0.f;
    for (int g=0; g<8; ++g) acc += lds[(g*128 + ci)*17 + i];
    int grp = i >> 2, col = ci*4 + (i & 3);
    partials[(size_t)blockIdx.x*2048 + grp*HID + col] = acc;
  }
}

__global__ void bnfin_red2(const float* __restrict__ partials, float* __restrict__ mstatCO){
  __shared__ float lds[4][64][2];
  int t = threadIdx.x;
  int cl = t & 63, ch = t >> 6;
  int c = blockIdx.x*64 + cl;
  int off = blockIdx.y*1024;
  float s = 0.f, q = 0.f;
  for (int b = ch*64; b < ch*64 + 64; ++b){
    s += partials[(size_t)b*2048 + off + c];
    q += partials[(size_t)b*2048 + off + HID + c];
  }
  lds[ch][cl][0] = s; lds[ch][cl][1] = q;
  __syncthreads();
  if (ch == 0){
    s = lds[0][cl][0]+lds[1][cl][0]+lds[2][cl][0]+lds[3][cl][0];
    q = lds[0][cl][1]+lds[1][cl][1]+lds[2][cl][1]+lds[3][cl][1];
    float m = s/(float)NN;
    float v = q/(float)NN - m*m;
    mstatCO[blockIdx.y*1024 + c] = m;
    mstatCO[blockIdx.y*1024 + HID + c] = rsqrtf(v + 1e-5f);
  }
}

// ---------------- attention (bf16 X), weights staged in LDS ----------------
__global__ void att_node(const unsigned short* __restrict__ X, const float* __restrict__ nW,
                         const float* __restrict__ nb, const float* __restrict__ eW,
                         float* __restrict__ na, float* __restrict__ eab){
  __shared__ float wnl[1024], wet[1024], web[1024];
  int t = threadIdx.x;
  for (int i=t; i<1024; i+=256){ wnl[i]=nW[i]; wet[i]=eW[i]; web[i]=eW[1024+i]; }
  __syncthreads();
  int wv = blockIdx.x*4 + (t >> 6);
  int l = t & 63;
  uint4 u = ((const uint4*)(X + (size_t)wv*HID))[l];
  float xv[8] = {bf2f(u.x&0xffffu), bf2f(u.x>>16), bf2f(u.y&0xffffu), bf2f(u.y>>16),
                 bf2f(u.z&0xffffu), bf2f(u.z>>16), bf2f(u.w&0xffffu), bf2f(u.w>>16)};
  float s0=0,s1=0,s2=0,s3=0,s4=0,s5=0;
#pragma unroll
  for (int j=0; j<8; ++j){
    int k = l*8 + j;
    float x = xv[j];
    s0 += x * wnl[2*k];   s1 += x * wnl[2*k+1];
    s2 += x * wet[2*k];   s3 += x * wet[2*k+1];
    s4 += x * web[2*k];   s5 += x * web[2*k+1];
  }
  for (int m=1; m<64; m<<=1){
    s0 += __shfl_xor(s0,m); s1 += __shfl_xor(s1,m); s2 += __shfl_xor(s2,m);
    s3 += __shfl_xor(s3,m); s4 += __shfl_xor(s4,m); s5 += __shfl_xor(s5,m);
  }
  if (l == 0){
    float z0 = s0 + nb[0], z1 = s1 + nb[1];
    float mx = fmaxf(z0,z1);
    float e0 = expf(z0-mx), e1 = expf(z1-mx);
    float inv = 1.0f/(e0+e1);
    na[2*wv] = e0*inv; na[2*wv+1] = e1*inv;
    eab[4*wv] = s2; eab[4*wv+1] = s3; eab[4*wv+2] = s4; eab[4*wv+3] = s5;
  }
}

__global__ void att_edge(const int* __restrict__ ei, const float* __restrict__ eab,
                         const float* __restrict__ eb, float* __restrict__ att,
                         float* __restrict__ degc, float* __restrict__ dego){
  int e = blockIdx.x*blockDim.x + threadIdx.x;
  if (e >= NE) return;
  int r = ei[e], c = ei[NE+e];
  float z0 = eab[4*r]   + eab[4*c+2] + eb[0];
  float z1 = eab[4*r+1] + eab[4*c+3] + eb[1];
  float mx = fmaxf(z0,z1);
  float e0 = expf(z0-mx), e1 = expf(z1-mx);
  float inv = 1.0f/(e0+e1);
  float a0 = e0*inv, a1 = e1*inv;
  att[2*e] = a0; att[2*e+1] = a1;
  atomicAdd(&degc[r], a0);
  atomicAdd(&dego[r], a1);
}

__global__ void wco_kernel(const int* __restrict__ crow, const int* __restrict__ ccol,
                           const int* __restrict__ ceid, const float* __restrict__ att,
                           const float* __restrict__ degc, const float* __restrict__ dego,
                           const float* __restrict__ na,
                           float* __restrict__ wcv, float* __restrict__ wov,
                           float* __restrict__ Sc, float* __restrict__ So){
  int j = blockIdx.x*blockDim.x + threadIdx.x;
  if (j >= NE + NN) return;
  int r = crow[j], c = ccol[j], e = ceid[j];
  float a0 = (e < 0) ? 1.0f : att[2*e];
  float a1 = (e < 0) ? 1.0f : att[2*e+1];
  float wc = rsqrtf(degc[r]) * a0 * rsqrtf(degc[c]);
  float wo = rsqrtf(dego[r]) * a1 * rsqrtf(dego[c]);
  wcv[j] = wc * na[2*c];
  wov[j] = wo * na[2*c+1];
  atomicAdd(&Sc[r], wc);
  atomicAdd(&So[r], wo);
}

// ---------------- wave-per-row aggregation (int2 pairs), 8-deep ILP, BN affine epilogue ----------------
__global__ __launch_bounds__(256) void aggregate_bn(const unsigned short* __restrict__ A,
                                                    const int* __restrict__ rowp,
                                                    const int2* __restrict__ cw,
                                                    const float* __restrict__ stats,
                                                    float invM,
                                                    unsigned short* __restrict__ out){
  int row = blockIdx.x*4 + (threadIdx.x >> 6);
  int l = threadIdx.x & 63;
  const uint4* Av = (const uint4*)A;
  int s = rowp[row], e = rowp[row+1];
  float acc[8] = {0,0,0,0,0,0,0,0};
  float sw = 0.f;
  int j = s;
  for (; j+7 < e; j += 8){
    int2 p[8]; uint4 v[8];
#pragma unroll
    for (int k=0;k<8;k++) p[k] = cw[j+k];
#pragma unroll
    for (int k=0;k<8;k++) v[k] = Av[(size_t)p[k].x*64 + l];
#pragma unroll
    for (int k=0;k<8;k++){ float w = __int_as_float(p[k].y); fma8(acc, v[k], w); sw += w; }
  }
  for (; j+3 < e; j += 4){
    int2 p[4]; uint4 v[4];
#pragma unroll
    for (int k=0;k<4;k++) p[k] = cw[j+k];
#pragma unroll
    for (int k=0;k<4;k++) v[k] = Av[(size_t)p[k].x*64 + l];
#pragma unroll
    for (int k=0;k<4;k++){ float w = __int_as_float(p[k].y); fma8(acc, v[k], w); sw += w; }
  }
  for (; j < e; ++j){
    int2 p = cw[j];
    float w = __int_as_float(p.y);
    uint4 v = Av[(size_t)p.x*64 + l];
    fma8(acc, v, w);
    sw += w;
  }
  float g[8];
#pragma unroll
  for (int i=0;i<8;i++){
    int c = l*8 + i;
    float m = stats[c]*invM;
    float rs = rsqrtf(stats[512+c]*invM - m*m + 1e-5f);
    g[i] = rs*acc[i] + sw*(1e-4f - m*rs);
  }
  uint4 o;
  o.x = pk2(g[0],g[1]); o.y = pk2(g[2],g[3]); o.z = pk2(g[4],g[5]); o.w = pk2(g[6],g[7]);
  ((uint4*)out)[(size_t)row*64 + l] = o;
}

__global__ __launch_bounds__(256) void aggregate_dual(const unsigned short* __restrict__ A,
                                                      const int* __restrict__ rowp,
                                                      const int* __restrict__ ccol,
                                                      const float* __restrict__ wc,
                                                      const float* __restrict__ wo,
                                                      const float* __restrict__ Sc,
                                                      const float* __restrict__ So,
                                                      const float* __restrict__ mstatCO,
                                                      unsigned short* __restrict__ outC,
                                                      unsigned short* __restrict__ outO){
  int row = blockIdx.x*4 + (threadIdx.x >> 6);
  int l = threadIdx.x & 63;
  const uint4* Av = (const uint4*)A;
  int s = rowp[row], e = rowp[row+1];
  float aC[8] = {0,0,0,0,0,0,0,0};
  float aO[8] = {0,0,0,0,0,0,0,0};
  int j = s;
  for (; j+7 < e; j += 8){
    int cc[8]; uint4 v[8];
#pragma unroll
    for (int k=0;k<8;k++) cc[k] = ccol[j+k];
#pragma unroll
    for (int k=0;k<8;k++) v[k] = Av[(size_t)cc[k]*64 + l];
#pragma unroll
    for (int k=0;k<8;k++){ fma8(aC, v[k], wc[j+k]); fma8(aO, v[k], wo[j+k]); }
  }
  for (; j+3 < e; j += 4){
    int cc[4]; uint4 v[4];
#pragma unroll
    for (int k=0;k<4;k++) cc[k] = ccol[j+k];
#pragma unroll
    for (int k=0;k<4;k++) v[k] = Av[(size_t)cc[k]*64 + l];
#pragma unroll
    for (int k=0;k<4;k++){ fma8(aC, v[k], wc[j+k]); fma8(aO, v[k], wo[j+k]); }
  }
  for (; j < e; ++j){
    uint4 v = Av[(size_t)ccol[j]*64 + l];
    fma8(aC, v, wc[j]); fma8(aO, v, wo[j]);
  }
  float ScR = Sc[row], SoR = So[row];
  float gC[8], gO[8];
#pragma unroll
  for (int i=0;i<8;i++){
    int c = l*8 + i;
    float mc = mstatCO[c],      rc = mstatCO[512+c];
    float mo = mstatCO[1024+c], ro = mstatCO[1536+c];
    gC[i] = rc*aC[i] + ScR*(1e-4f - mc*rc);
    gO[i] = ro*aO[i] + SoR*(1e-4f - mo*ro);
  }
  uint4 oc, oo;
  oc.x = pk2(gC[0],gC[1]); oc.y = pk2(gC[2],gC[3]); oc.z = pk2(gC[4],gC[5]); oc.w = pk2(gC[6],gC[7]);
  oo.x = pk2(gO[0],gO[1]); oo.y = pk2(gO[2],gO[3]); oo.z = pk2(gO[4],gO[5]); oo.w = pk2(gO[6],gO[7]);
  ((uint4*)outC)[(size_t)row*64 + l] = oc;
  ((uint4*)outO)[(size_t)row*64 + l] = oo;
}

// ---------------- bf16 MFMA GEMM: XCD-chunked 1D grid, 3-buffer ring (vmcnt(8)), LDS-staged C ----------------
__global__ __launch_bounds__(256) void gemm_bt(const unsigned short* __restrict__ A,
                                               const unsigned short* __restrict__ Bt,
                                               unsigned short* __restrict__ O,
                                               const float* __restrict__ bias,
                                               float* __restrict__ stats,
                                               int M, int K, int relu, int split,
                                               const unsigned short* A2,
                                               const unsigned short* Bt2,
                                               unsigned short* O2,
                                               const float* bias2){
  extern __shared__ unsigned short smem[];   // 3 buffers of 8192 shorts (A 4096 + B 4096); Cs aliases
  unsigned short* Cs = smem;
  const int tid = threadIdx.x;
  const int w = tid >> 6, l = tid & 63;

  int lin = blockIdx.x;
  int total = gridDim.x;
  int q = total >> 3, r = total & 7;
  int xcd = lin & 7, idx = lin >> 3;
  int swz = (xcd < r ? xcd*(q+1) : r*(q+1) + (xcd - r)*q) + idx;
  if (split && swz >= split){ A = A2; Bt = Bt2; O = O2; bias = bias2; swz -= split; }
  const int m0 = (swz >> 2)*128, n0 = (swz & 3)*128;

  const int wm = w >> 1, wn = w & 1;
  const int lr = l & 15, lh = l >> 4;

  f32x4 acc[4][4];
#pragma unroll
  for (int i=0;i<4;i++)
#pragma unroll
    for (int j=0;j<4;j++) acc[i][j] = 0.0f;

  const int q0 = w*2, q1 = w*2+1;
  const int sub = l >> 2;
  const int kc  = (l & 3)*8;
  int ma0 = m0 + q0*16 + sub; if (ma0 >= M) ma0 = M-1;
  int ma1 = m0 + q1*16 + sub; if (ma1 >= M) ma1 = M-1;
  const int nb0 = n0 + q0*16 + sub;
  const int nb1 = n0 + q1*16 + sub;
  const unsigned short* Ar0 = A + (size_t)ma0*K + kc;
  const unsigned short* Ar1 = A + (size_t)ma1*K + kc;
  const unsigned short* Br0 = Bt + (size_t)nb0*K + kc;
  const unsigned short* Br1 = Bt + (size_t)nb1*K + kc;

  const int NT = K >> 5;
  // prologue: stage tiles 0 and 1
  gload16(&smem[0*8192 + q0*512], Ar0);
  gload16(&smem[0*8192 + q1*512], Ar1);
  gload16(&smem[0*8192 + 4096 + q0*512], Br0);
  gload16(&smem[0*8192 + 4096 + q1*512], Br1);
  if (NT > 1){
    gload16(&smem[1*8192 + q0*512], Ar0 + 32);
    gload16(&smem[1*8192 + q1*512], Ar1 + 32);
    gload16(&smem[1*8192 + 4096 + q0*512], Br0 + 32);
    gload16(&smem[1*8192 + 4096 + q1*512], Br1 + 32);
  }
  int cur = 0;
  for (int t=0; t<NT; ++t){
    if (t+2 < NT){
      int k1 = (t+2) << 5;
      int nb = cur + 2; if (nb >= 3) nb -= 3;
      gload16(&smem[nb*8192 + q0*512], Ar0 + k1);
      gload16(&smem[nb*8192 + q1*512], Ar1 + k1);
      gload16(&smem[nb*8192 + 4096 + q0*512], Br0 + k1);
      gload16(&smem[nb*8192 + 4096 + q1*512], Br1 + k1);
      asm volatile("s_waitcnt vmcnt(8)" ::: "memory");   // tile t landed; t+1,t+2 in flight
    } else if (t+1 < NT){
      asm volatile("s_waitcnt vmcnt(4)" ::: "memory");
    } else {
      asm volatile("s_waitcnt vmcnt(0)" ::: "memory");
    }
    __builtin_amdgcn_s_barrier();
    asm volatile("" ::: "memory");
    short8 af[4], bfr[4];
#pragma unroll
    for (int fm=0; fm<4; ++fm) af[fm]  = *(const short8*)&smem[cur*8192 + (wm*64 + fm*16 + lr)*32 + lh*8];
#pragma unroll
    for (int fn=0; fn<4; ++fn) bfr[fn] = *(const short8*)&smem[cur*8192 + 4096 + (wn*64 + fn*16 + lr)*32 + lh*8];
#pragma unroll
    for (int fm=0; fm<4; ++fm)
#pragma unroll
      for (int fn=0; fn<4; ++fn)
        acc[fm][fn] = __builtin_amdgcn_mfma_f32_16x16x32_bf16(af[fm], bfr[fn], acc[fm][fn], 0, 0, 0);
    asm volatile("" ::: "memory");
    __builtin_amdgcn_s_barrier();
    asm volatile("" ::: "memory");
    cur += 1; if (cur >= 3) cur = 0;
  }
  // bias pointer made data-dependent on acc so loads can't hoist into the counted-vmcnt region
  int dep = __float_as_int(acc[0][0][0]);
  int z_;
  asm volatile("v_and_b32 %0, 0, %1" : "=v"(z_) : "v"(dep));
  const float* biasp = bias + z_;

  float bv[4], cs[4]={0,0,0,0}, cq[4]={0,0,0,0};
  int col[4];
#pragma unroll
  for (int fn=0; fn<4; ++fn){ col[fn] = n0 + wn*64 + fn*16 + lr; bv[fn] = biasp[col[fn]]; }
#pragma unroll
  for (int fm=0; fm<4; ++fm){
#pragma unroll
    for (int j=0; j<4; ++j){
      int trow = wm*64 + fm*16 + lh*4 + j;
      bool valid = (m0 + trow) < M;
#pragma unroll
      for (int fn=0; fn<4; ++fn){
        float v = acc[fm][fn][j] + bv[fn];
        if (relu) v = fmaxf(v, 0.f);
        Cs[trow*136 + wn*64 + fn*16 + lr] = f2bf(v);
        if (valid){ cs[fn] += v; cq[fn] += v*v; }
      }
    }
  }
  __syncthreads();
#pragma unroll
  for (int i=0;i<8;i++){
    int trow = i*16 + (tid>>4);
    int colb = (tid&15)*8;
    uint4 vv = *(const uint4*)&Cs[trow*136 + colb];
    int grow = m0 + trow;
    if (grow < M) *(uint4*)&O[(size_t)grow*HID + n0 + colb] = vv;
  }
  if (stats){
#pragma unroll
    for (int m=16; m<64; m<<=1){
#pragma unroll
      for (int fn=0; fn<4; ++fn){ cs[fn] += __shfl_xor(cs[fn], m); cq[fn] += __shfl_xor(cq[fn], m); }
    }
    if (lh == 0){
#pragma unroll
      for (int fn=0; fn<4; ++fn){
        atomicAdd(&stats[col[fn]], cs[fn]);
        atomicAdd(&stats[512+col[fn]], cq[fn]);
      }
    }
  }
}

// batched fc1 gemm: M=1536 (3 branches x 512 rows), 3-buffer ring
struct FC1P { const unsigned short* Bt[3]; const float* bias[3]; };
__global__ __launch_bounds__(256) void gemm_fc1(const unsigned short* __restrict__ A, FC1P p,
                                                unsigned short* __restrict__ O,
                                                float* __restrict__ statsB){
  extern __shared__ unsigned short smem[];
  const int tid = threadIdx.x;
  const int w = tid >> 6, l = tid & 63;
  const int m0 = blockIdx.x*128, n0 = blockIdx.y*128;
  const int branch = blockIdx.x >> 2;
  const unsigned short* Bt = p.Bt[branch];
  const float* bias = p.bias[branch];
  float* stats = statsB + branch*1024;
  const int K = HID;
  const int wm = w >> 1, wn = w & 1;
  const int lr = l & 15, lh = l >> 4;

  f32x4 acc[4][4];
#pragma unroll
  for (int i=0;i<4;i++)
#pragma unroll
    for (int j=0;j<4;j++) acc[i][j] = 0.0f;

  const int q0 = w*2, q1 = w*2+1;
  const int sub = l >> 2;
  const int kc  = (l & 3)*8;
  const int ma0 = m0 + q0*16 + sub;
  const int ma1 = m0 + q1*16 + sub;
  const int nb0 = n0 + q0*16 + sub;
  const int nb1 = n0 + q1*16 + sub;
  const unsigned short* Ar0 = A + (size_t)ma0*K + kc;
  const unsigned short* Ar1 = A + (size_t)ma1*K + kc;
  const unsigned short* Br0 = Bt + (size_t)nb0*K + kc;
  const unsigned short* Br1 = Bt + (size_t)nb1*K + kc;

  const int NT = K >> 5;
  gload16(&smem[0*8192 + q0*512], Ar0);
  gload16(&smem[0*8192 + q1*512], Ar1);
  gload16(&smem[0*8192 + 4096 + q0*512], Br0);
  gload16(&smem[0*8192 + 4096 + q1*512], Br1);
  gload16(&smem[1*8192 + q0*512], Ar0 + 32);
  gload16(&smem[1*8192 + q1*512], Ar1 + 32);
  gload16(&smem[1*8192 + 4096 + q0*512], Br0 + 32);
  gload16(&smem[1*8192 + 4096 + q1*512], Br1 + 32);
  int cur = 0;
  for (int t=0; t<NT; ++t){
    if (t+2 < NT){
      int k1 = (t+2) << 5;
      int nb = cur + 2; if (nb >= 3) nb -= 3;
      gload16(&smem[nb*8192 + q0*512], Ar0 + k1);
      gload16(&smem[nb*8192 + q1*512], Ar1 + k1);
      gload16(&smem[nb*8192 + 4096 + q0*512], Br0 + k1);
      gload16(&smem[nb*8192 + 4096 + q1*512], Br1 + k1);
      asm volatile("s_waitcnt vmcnt(8)" ::: "memory");
    } else if (t+1 < NT){
      asm volatile("s_waitcnt vmcnt(4)" ::: "memory");
    } else {
      asm volatile("s_waitcnt vmcnt(0)" ::: "memory");
    }
    __builtin_amdgcn_s_barrier();
    asm volatile("" ::: "memory");
    short8 af[4], bfr[4];
#pragma unroll
    for (int fm=0; fm<4; ++fm) af[fm]  = *(const short8*)&smem[cur*8192 + (wm*64 + fm*16 + lr)*32 + lh*8];
#pragma unroll
    for (int fn=0; fn<4; ++fn) bfr[fn] = *(const short8*)&smem[cur*8192 + 4096 + (wn*64 + fn*16 + lr)*32 + lh*8];
#pragma unroll
    for (int fm=0; fm<4; ++fm)
#pragma unroll
      for (int fn=0; fn<4; ++fn)
        acc[fm][fn] = __builtin_amdgcn_mfma_f32_16x16x32_bf16(af[fm], bfr[fn], acc[fm][fn], 0, 0, 0);
    asm volatile("" ::: "memory");
    __builtin_amdgcn_s_barrier();
    asm volatile("" ::: "memory");
    cur += 1; if (cur >= 3) cur = 0;
  }
  int dep = __float_as_int(acc[0][0][0]);
  int z_;
  asm volatile("v_and_b32 %0, 0, %1" : "=v"(z_) : "v"(dep));
  const float* biasp = bias + z_;

  float bv[4], cs[4]={0,0,0,0}, cq[4]={0,0,0,0};
  int col[4];
#pragma unroll
  for (int fn=0; fn<4; ++fn){ col[fn] = n0 + wn*64 + fn*16 + lr; bv[fn] = biasp[col[fn]]; }
#pragma unroll
  for (int fm=0; fm<4; ++fm){
#pragma unroll
    for (int j=0; j<4; ++j){
      int row = m0 + wm*64 + fm*16 + lh*4 + j;
      bool real = (row & 511) < NG;
#pragma unroll
      for (int fn=0; fn<4; ++fn){
        float v = fmaxf(acc[fm][fn][j] + bv[fn], 0.f);
        O[(size_t)row*HID + col[fn]] = f2bf(v);
        if (real){ cs[fn] += v; cq[fn] += v*v; }
      }
    }
  }
#pragma unroll
  for (int m=16; m<64; m<<=1){
#pragma unroll
    for (int fn=0; fn<4; ++fn){ cs[fn] += __shfl_xor(cs[fn], m); cq[fn] += __shfl_xor(cq[fn], m); }
  }
  if (lh == 0){
#pragma unroll
    for (int fn=0; fn<4; ++fn){
      atomicAdd(&stats[col[fn]], cs[fn]);
      atomicAdd(&stats[512+col[fn]], cq[fn]);
    }
  }
}

// ---------------- pooling, both branches in one dispatch ----------------
__global__ void pool2(const unsigned short* __restrict__ XC, const unsigned short* __restrict__ XO,
                      const int* __restrict__ batch, float* __restrict__ gc, float* __restrict__ go){
  int g = blockIdx.x;
  int t = threadIdx.x;
  const unsigned short* X = blockIdx.y ? XO : XC;
  float* out = blockIdx.y ? go : gc;
  int lo = 0, hi = NN;
  while (lo < hi){ int mid = (lo+hi) >> 1; if (batch[mid] < g) lo = mid+1; else hi = mid; }
  int s = lo;
  lo = 0; hi = NN;
  while (lo < hi){ int mid = (lo+hi) >> 1; if (batch[mid] < g+1) lo = mid+1; else hi = mid; }
  int e = lo;
  float a0 = 0.f, a1 = 0.f;
  for (int i=s; i<e; ++i){
    unsigned int v = *(const unsigned int*)&X[(size_t)i*HID + t*2];
    a0 += bf2f(v & 0xffffu); a1 += bf2f(v >> 16);
  }
  out[(size_t)g*HID + t*2]     = a0;
  out[(size_t)g*HID + t*2 + 1] = a1;
}

// ---------------- readout BN1: one block per branch, full stats -> mstat3 ----------------
__global__ __launch_bounds__(1024) void bnstats3f(const float* __restrict__ gc, const float* __restrict__ go,
                                                  const int* __restrict__ perm, float* __restrict__ mstat3){
  __shared__ float lds[8*128*9];
  __shared__ float colsum[512], colsq[512];
  int br = blockIdx.x;
  int t = threadIdx.x;
  int cid = t & 127, rid = t >> 7;
  float s[4]={0,0,0,0}, q[4]={0,0,0,0};
  for (int r = rid; r < NG; r += 8){
    float4 v;
    if (br == 0)      v = *(const float4*)&gc[(size_t)r*HID + cid*4];
    else if (br == 1) v = *(const float4*)&go[(size_t)r*HID + cid*4];
    else {
      int ps = perm[r];
      float4 a = *(const float4*)&gc[(size_t)ps*HID + cid*4];
      float4 b = *(const float4*)&go[(size_t)r*HID + cid*4];
      v = make_float4(a.x+b.x, a.y+b.y, a.z+b.z, a.w+b.w);
    }
    float e[4] = {v.x, v.y, v.z, v.w};
#pragma unroll
    for (int i=0;i<4;i++){ s[i]+=e[i]; q[i]+=e[i]*e[i]; }
  }
  int base = (rid*128 + cid)*9;
#pragma unroll
  for (int i=0;i<4;i++){ lds[base+i]=s[i]; lds[base+4+i]=q[i]; }
  __syncthreads();
  {
    int ci = t >> 3, i = t & 7;
    float a = 0.f;
    for (int g=0; g<8; ++g) a += lds[(g*128 + ci)*9 + i];
    int col = ci*4 + (i & 3);
    if (i < 4) colsum[col] = a; else colsq[col] = a;
  }
  __syncthreads();
  if (t < 512){
    float m = colsum[t]/(float)NG;
    float v = colsq[t]/(float)NG - m*m;
    mstat3[br*1024 + t] = m;
    mstat3[br*1024 + 512 + t] = rsqrtf(v + 1e-5f);
  }
}

__global__ void bncast3(const float* __restrict__ gc, const float* __restrict__ go,
                        const int* __restrict__ perm, const float* __restrict__ mstat3,
                        unsigned short* __restrict__ out){
  int idx = blockIdx.x*blockDim.x + threadIdx.x;
  if (idx >= 1536*128) return;
  int r = idx >> 7;
  int cg = idx & 127;
  int br = r >> 9, lr = r & 511;
  ushort4v o;
  if (lr >= NG){ o[0]=0; o[1]=0; o[2]=0; o[3]=0; }
  else {
    float4 v;
    if (br == 0)      v = *(const float4*)&gc[(size_t)lr*HID + cg*4];
    else if (br == 1) v = *(const float4*)&go[(size_t)lr*HID + cg*4];
    else {
      int ps = perm[lr];
      float4 a = *(const float4*)&gc[(size_t)ps*HID + cg*4];
      float4 b = *(const float4*)&go[(size_t)lr*HID + cg*4];
      v = make_float4(a.x+b.x, a.y+b.y, a.z+b.z, a.w+b.w);
    }
    const float* ms = mstat3 + br*1024;
    int c = cg*4;
    o[0] = f2bf((v.x - ms[c+0])*ms[512+c+0] + 1e-4f);
    o[1] = f2bf((v.y - ms[c+1])*ms[512+c+1] + 1e-4f);
    o[2] = f2bf((v.z - ms[c+2])*ms[512+c+2] + 1e-4f);
    o[3] = f2bf((v.w - ms[c+3])*ms[512+c+3] + 1e-4f);
  }
  *(ushort4v*)&out[(size_t)r*HID + cg*4] = o;
}

// ---------------- final: batched BN2 -> fc2 -> log_softmax ----------------
struct ROP { const float* W2[3]; const float* b2[3]; };
__global__ void readout_final3(const unsigned short* __restrict__ T, const float* __restrict__ statsB,
                               float invM, ROP p, float* __restrict__ out){
  int g = blockIdx.x;
  int br = blockIdx.y;
  int l = threadIdx.x;
  const float* stats = statsB + br*1024;
  const float* W2 = p.W2[br];
  const float* b2 = p.b2[br];
  float acc[NCLS];
#pragma unroll
  for (int c=0; c<NCLS; ++c) acc[c] = 0.f;
  uint4 u = ((const uint4*)(T + (size_t)(br*512 + g)*HID))[l];
  float xv[8] = {bf2f(u.x&0xffffu), bf2f(u.x>>16), bf2f(u.y&0xffffu), bf2f(u.y>>16),
                 bf2f(u.z&0xffffu), bf2f(u.z>>16), bf2f(u.w&0xffffu), bf2f(u.w>>16)};
#pragma unroll
  for (int j=0; j<8; ++j){
    int k = l*8 + j;
    float m = stats[k]*invM;
    float rs = rsqrtf(stats[512+k]*invM - m*m + 1e-5f);
    float v = (xv[j] - m)*rs + 1e-4f;
#pragma unroll
    for (int c=0; c<NCLS; ++c) acc[c] += v * W2[k*NCLS + c];
  }
  for (int m=1; m<64; m<<=1){
#pragma unroll
    for (int c=0; c<NCLS; ++c) acc[c] += __shfl_xor(acc[c], m);
  }
  if (l == 0){
    float z[NCLS];
    float mx = -1e30f;
#pragma unroll
    for (int c=0; c<NCLS; ++c){ z[c] = acc[c] + b2[c]; mx = fmaxf(mx, z[c]); }
    float s = 0.f;
#pragma unroll
    for (int c=0; c<NCLS; ++c) s += expf(z[c]-mx);
    float lse = mx + logf(s);
#pragma unroll
    for (int c=0; c<NCLS; ++c) out[(size_t)(br*NG + g)*NCLS + c] = z[c] - lse;
  }
}

extern "C" void kernel_launch(void* const* d_in, const int* in_sizes, int n_in,
                              void* d_out, int out_size, void* d_ws, size_t ws_size,
                              hipStream_t stream){
  (void)in_sizes; (void)n_in; (void)out_size;
  const float* x      = (const float*)d_in[0];
  const int*   ei     = (const int*)d_in[1];
  const int*   batch  = (const int*)d_in[2];
  const int*   perm   = (const int*)d_in[3];
  const float* convfW = (const float*)d_in[4];
  const float* convfB = (const float*)d_in[5];
  const float* convsW = (const float*)d_in[6];
  const float* convsB = (const float*)d_in[7];
  const float* eattW  = (const float*)d_in[8];
  const float* eattB  = (const float*)d_in[9];
  const float* nattW  = (const float*)d_in[10];
  const float* nattB  = (const float*)d_in[11];
  const float* ctxW   = (const float*)d_in[12];
  const float* ctxB   = (const float*)d_in[13];
  const float* objW   = (const float*)d_in[14];
  const float* objB   = (const float*)d_in[15];
  const float* fc1W[3] = {(const float*)d_in[16], (const float*)d_in[20], (const float*)d_in[24]};
  const float* fc1B[3] = {(const float*)d_in[17], (const float*)d_in[21], (const float*)d_in[25]};
  const float* fc2W[3] = {(const float*)d_in[18], (const float*)d_in[22], (const float*)d_in[26]};
  const float* fc2B[3] = {(const float*)d_in[19], (const float*)d_in[23], (const float*)d_in[27]};
  float* out = (float*)d_out;

  char* p = (char*)d_ws;
  auto alloc = [&](size_t bytes)->char*{ char* r = p; p += (bytes + 255) & ~((size_t)255); return r; };
  const int T = NE + NN;
  unsigned short* Xbf = (unsigned short*)alloc((size_t)NN*HID*2);
  unsigned short* Gbf = (unsigned short*)alloc((size_t)NN*HID*2);
  unsigned short* GbfO= (unsigned short*)alloc((size_t)NN*HID*2);
  unsigned short* XbfO= (unsigned short*)alloc((size_t)NN*HID*2);
  unsigned short* Abf = (unsigned short*)alloc((size_t)NN*FIN*2);
  unsigned short* WtF = (unsigned short*)alloc((size_t)HID*FIN*2);
  unsigned short* WtL = (unsigned short*)alloc((size_t)3*HID*HID*2);
  unsigned short* WtC = (unsigned short*)alloc((size_t)HID*HID*2);
  unsigned short* WtO = (unsigned short*)alloc((size_t)HID*HID*2);
  unsigned short* WtR = (unsigned short*)alloc((size_t)3*HID*HID*2);
  int* cnt   = (int*)alloc((size_t)NN*4);
  int* fillc = (int*)alloc((size_t)NN*4);
  int* rowp  = (int*)alloc((size_t)(NN+1)*4);
  int* bsum  = (int*)alloc(32*4);
  int* ccol  = (int*)alloc((size_t)T*4);
  int* crow  = (int*)alloc((size_t)T*4);
  int* ceid  = (int*)alloc((size_t)T*4);
  int2* cw1  = (int2*)alloc((size_t)T*8);
  float* wcv = (float*)alloc((size_t)T*4);
  float* wov = (float*)alloc((size_t)T*4);
  float* dis1 = (float*)alloc((size_t)NN*4);
  float* degc = (float*)alloc((size_t)NN*4);
  float* dego = (float*)alloc((size_t)NN*4);
  float* Sc   = (float*)alloc((size_t)NN*4);
  float* So   = (float*)alloc((size_t)NN*4);
  float* stats6 = (float*)alloc(6*1024*4);
  float* mstat  = (float*)alloc(2*HID*4);
  float* mstatCO= (float*)alloc(2*1024*4);
  float* mstat3 = (float*)alloc(3*1024*4);
  float* na   = (float*)alloc((size_t)NN*2*4);
  float* eab  = (float*)alloc((size_t)NN*4*4);
  float* att  = (float*)alloc((size_t)NE*2*4);
  float* gc   = (float*)alloc((size_t)NG*HID*4);
  float* go   = (float*)alloc((size_t)NG*HID*4);
  float* part = (float*)alloc((size_t)BNG*2048*4);
  if ((size_t)(p - (char*)d_ws) > ws_size){
    sentinel_k<<<1,1,0,stream>>>(out);
    return;
  }
  unsigned short* Abf3 = Abf;
  unsigned short* Gbf3 = GbfO;
  const float invNN = 1.0f/(float)NN;
  const float invNG = 1.0f/(float)NG;
  const int GEMM_LDS = 3*8192*2;   // 49152 B: 3-buffer ring; Cs (34816B) aliases

  // setup
  W2BT wp;
  wp.src[0]=convfW; wp.dst[0]=WtF;
  for (int i=0;i<3;i++){ wp.src[1+i]=convsW+(size_t)i*HID*HID; wp.dst[1+i]=WtL+(size_t)i*HID*HID; }
  wp.src[4]=ctxW; wp.dst[4]=WtC;
  wp.src[5]=objW; wp.dst[5]=WtO;
  for (int i=0;i<3;i++){ wp.src[6+i]=fc1W[i]; wp.dst[6+i]=WtR+(size_t)i*HID*HID; }
  setup_all<<<(FIN*HID + 8*HID*HID + 255)/256, 256, 0, stream>>>(wp, cnt, fillc, degc, dego, Sc, So, stats6);

  // D1: csr_count + conv bnstats
  d1_count_stats<<<BNG + (NE+1023)/1024, 1024, 0, stream>>>(ei, cnt, x, part);
  // D2: scan1 + conv bnfin
  d2_scan_fin<<<20 + FIN/64, 1024, 0, stream>>>(cnt, rowp, dis1, bsum, part, mstat);
  // D3: scan3 + conv bncast
  d3_scan_cast<<<20 + (NN*FIN/4 + 1023)/1024, 1024, 0, stream>>>(rowp, bsum, x, mstat, Abf);
  // CSR fill
  csr_fill<<<(T+255)/256,256,0,stream>>>(ei, rowp, cnt, fillc, dis1, ccol, crow, ceid, cw1);

  const int NBLK = ((NN+127)/128)*4;   // 628

  // conv_feat gemm
  gemm_bt<<<NBLK,256,GEMM_LDS,stream>>>(Abf, WtF, Xbf, convfB, stats6, NN, FIN, 1,
                                        0, nullptr, nullptr, nullptr, nullptr);

  // 3 GCN layers
  for (int i=0;i<3;i++){
    aggregate_bn<<<NN/4,256,0,stream>>>(Xbf, rowp, cw1, stats6 + i*1024, invNN, Gbf);
    gemm_bt<<<NBLK,256,GEMM_LDS,stream>>>(Gbf, WtL+(size_t)i*HID*HID, Xbf,
                                          convsB+(size_t)i*HID,
                                          (i<2) ? (stats6 + (i+1)*1024) : nullptr,
                                          NN, HID, 1, 0, nullptr, nullptr, nullptr, nullptr);
  }

  // attention
  att_node<<<NN/4,256,0,stream>>>(Xbf, nattW, nattB, eattW, na, eab);
  att_edge<<<(NE+255)/256,256,0,stream>>>(ei, eab, eattB, att, degc, dego);
  wco_kernel<<<(T+255)/256,256,0,stream>>>(crow, ccol, ceid, att, degc, dego, na, wcv, wov, Sc, So);

  // ctx + obj
  bnstats_dual<<<BNG,1024,0,stream>>>(Xbf, na, part);
  bnfin_red2<<<dim3(8,2),256,0,stream>>>(part, mstatCO);
  aggregate_dual<<<NN/4,256,0,stream>>>(Xbf, rowp, ccol, wcv, wov, Sc, So, mstatCO, Gbf, GbfO);
  gemm_bt<<<2*NBLK,256,GEMM_LDS,stream>>>(Gbf, WtC, Xbf, ctxB, nullptr, NN, HID, 1,
                                          NBLK, GbfO, WtO, XbfO, objB);
  pool2<<<dim3(NG,2),256,0,stream>>>(Xbf, XbfO, batch, gc, go);

  // readouts, batched across the 3 branches
  bnstats3f<<<3,1024,0,stream>>>(gc, go, perm, mstat3);
  bncast3<<<(1536*128+255)/256,256,0,stream>>>(gc, go, perm, mstat3, Abf3);
  FC1P fp;
  for (int i=0;i<3;i++){ fp.Bt[i] = WtR+(size_t)i*HID*HID; fp.bias[i] = fc1B[i]; }
  gemm_fc1<<<dim3(12,4),256,GEMM_LDS,stream>>>(Abf3, fp, Gbf3, stats6 + 3*1024);
  ROP rp;
  for (int i=0;i<3;i++){ rp.W2[i] = fc2W[i]; rp.b2[i] = fc2B[i]; }
  readout_final3<<<dim3(NG,3),64,0,stream>>>(Gbf3, stats6 + 3*1024, invNG, rp, out);
}

// Round 9
// 433.520 us; speedup vs baseline: 1.0826x; 1.0826x over previous
//
#include <hip/hip_runtime.h>
#include <stdint.h>

#define NN 20000
#define NE 160000
#define NG 500
#define FIN 128
#define HID 512
#define NCLS 10
#define BNG 256
#define NB3 32

typedef __attribute__((ext_vector_type(8))) short short8;
typedef __attribute__((ext_vector_type(4))) float f32x4;
typedef __attribute__((ext_vector_type(4))) unsigned short ushort4v;

__device__ __forceinline__ float bf2f(unsigned int u){
  union{unsigned int i; float f;} x; x.i = u<<16; return x.f;
}
__device__ __forceinline__ unsigned short f2bf(float f){
  union{float f; unsigned int i;} x; x.f=f;
  unsigned int r = x.i + 0x7fffu + ((x.i>>16)&1u);
  return (unsigned short)(r>>16);
}
__device__ __forceinline__ unsigned int pk2(float a, float b){
  return (unsigned int)f2bf(a) | ((unsigned int)f2bf(b) << 16);
}

__device__ __forceinline__ void gload16(unsigned short* lds, const unsigned short* g){
  __builtin_amdgcn_global_load_lds((const __attribute__((address_space(1))) unsigned int*)g,
                                   (__attribute__((address_space(3))) unsigned int*)lds,
                                   16, 0, 0);
}

__device__ __forceinline__ void fma8(float* acc, uint4 v, float w){
  acc[0] += w*bf2f(v.x & 0xffffu); acc[1] += w*bf2f(v.x >> 16);
  acc[2] += w*bf2f(v.y & 0xffffu); acc[3] += w*bf2f(v.y >> 16);
  acc[4] += w*bf2f(v.z & 0xffffu); acc[5] += w*bf2f(v.z >> 16);
  acc[6] += w*bf2f(v.w & 0xffffu); acc[7] += w*bf2f(v.w >> 16);
}

__global__ void sentinel_k(float* out){ out[0] = 12345.0f; }

// ---------------- setup: all weight transposes + all init in one dispatch ----------------
struct W2BT { const float* src[9]; unsigned short* dst[9]; };
__global__ void setup_all(W2BT p, int* __restrict__ cnt, int* __restrict__ fillc,
                          float* __restrict__ degc, float* __restrict__ dego,
                          float* __restrict__ Sc, float* __restrict__ So,
                          float* __restrict__ stats6){
  int idx = blockIdx.x*blockDim.x + threadIdx.x;
  if (idx < FIN*HID + 8*HID*HID){
    int seg, off, K;
    if (idx < FIN*HID){ seg = 0; off = idx; K = FIN; }
    else {
      int r = idx - FIN*HID;
      seg = 1 + (r >> 18); off = r & (HID*HID-1); K = HID;
    }
    int k = off >> 9, n = off & 511;
    p.dst[seg][(size_t)n*K + k] = f2bf(p.src[seg][off]);
  }
  if (idx < NN){ cnt[idx]=0; fillc[idx]=0; degc[idx]=1.0f; dego[idx]=1.0f; Sc[idx]=0.f; So[idx]=0.f; }
  if (idx < 6*1024) stats6[idx] = 0.f;
}

// ---------------- D1: csr_count + conv BN stats stage 1 (blockIdx split) ----------------
__global__ __launch_bounds__(1024) void d1_count_stats(const int* __restrict__ ei, int* __restrict__ cnt,
                                                       const float* __restrict__ X, float* __restrict__ partials){
  __shared__ float lds[1024*9];
  const int t = threadIdx.x;
  if (blockIdx.x >= BNG){
    int e = (blockIdx.x - BNG)*1024 + t;
    if (e < NE) atomicAdd(&cnt[ei[e]], 1);
    return;
  }
  const int cg = FIN >> 2;            // 32
  const int cid = t & (cg-1);
  const int rid = t / cg;
  const int rpb = 1024 / cg;          // 32
  float s0=0,s1=0,s2=0,s3=0,q0=0,q1=0,q2=0,q3=0;
  const int rowsPer = (NN + BNG - 1)/BNG;
  int r0 = blockIdx.x*rowsPer, r1 = r0 + rowsPer; if (r1 > NN) r1 = NN;
  for (int r = r0 + rid; r < r1; r += rpb){
    float4 v = *(const float4*)&X[(size_t)r*FIN + cid*4];
    s0+=v.x; q0+=v.x*v.x; s1+=v.y; q1+=v.y*v.y; s2+=v.z; q2+=v.z*v.z; s3+=v.w; q3+=v.w*v.w;
  }
  int base = (rid*cg + cid)*9;
  lds[base+0]=s0; lds[base+1]=s1; lds[base+2]=s2; lds[base+3]=s3;
  lds[base+4]=q0; lds[base+5]=q1; lds[base+6]=q2; lds[base+7]=q3;
  __syncthreads();
  if (t < cg*8){
    int ci = t >> 3, i = t & 7;
    float acc = 0.f;
    for (int g=0; g<rpb; ++g) acc += lds[(g*cg + ci)*9 + i];
    int col = ci*4 + (i & 3);
    partials[(size_t)blockIdx.x*(2*FIN) + ((i < 4) ? col : FIN + col)] = acc;
  }
}

// ---------------- D2: scan1 + conv bnfin (blockIdx split) ----------------
__global__ __launch_bounds__(1024) void d2_scan_fin(const int* __restrict__ cnt, int* __restrict__ rowp,
                                                    float* __restrict__ dis1, int* __restrict__ bsum,
                                                    const float* __restrict__ partials, float* __restrict__ mstat){
  __shared__ int buf[1024];
  __shared__ float lds[4][64][2];
  int t = threadIdx.x;
  if (blockIdx.x < 20){
    int i = blockIdx.x*1024 + t;
    int v = 0;
    if (i < NN){ v = cnt[i] + 1; dis1[i] = rsqrtf((float)v); }
    buf[t] = v;
    __syncthreads();
    for (int off=1; off<1024; off<<=1){
      int xv = (t >= off) ? buf[t-off] : 0;
      __syncthreads();
      buf[t] += xv;
      __syncthreads();
    }
    if (i < NN) rowp[i+1] = buf[t];
    if (t == 1023) bsum[blockIdx.x] = buf[1023];
    return;
  }
  if (t >= 256) return;
  int cl = t & 63, ch = t >> 6;
  int c = (blockIdx.x - 20)*64 + cl;
  float s = 0.f, q = 0.f;
  for (int b = ch*64; b < ch*64 + 64; ++b){
    s += partials[(size_t)b*(2*FIN) + c];
    q += partials[(size_t)b*(2*FIN) + FIN + c];
  }
  lds[ch][cl][0] = s; lds[ch][cl][1] = q;
  __syncthreads();
  if (ch == 0){
    s = lds[0][cl][0]+lds[1][cl][0]+lds[2][cl][0]+lds[3][cl][0];
    q = lds[0][cl][1]+lds[1][cl][1]+lds[2][cl][1]+lds[3][cl][1];
    float m = s/(float)NN;
    float v = q/(float)NN - m*m;
    mstat[c] = m;
    mstat[FIN+c] = rsqrtf(v + 1e-5f);
  }
}

// ---------------- D3: scan3 + conv bncast (blockIdx split) ----------------
__global__ __launch_bounds__(1024) void d3_scan_cast(int* __restrict__ rowp, const int* __restrict__ bsum,
                                                     const float* __restrict__ X, const float* __restrict__ mstat,
                                                     unsigned short* __restrict__ out){
  __shared__ int base;
  int t = threadIdx.x;
  if (blockIdx.x < 20){
    int bx = blockIdx.x;
    if (t == 0){
      int a = 0;
      for (int b=0; b<bx; ++b) a += bsum[b];
      base = a;
    }
    __syncthreads();
    int i = bx*1024 + t;
    if (i < NN) rowp[i+1] += base;
    if (i == 0) rowp[0] = 0;
    return;
  }
  int idx = (blockIdx.x - 20)*1024 + t;
  int total4 = NN*FIN/4;
  if (idx >= total4) return;
  int b4 = idx*4;
  int c = b4 & (FIN-1);
  float4 v = *(const float4*)&X[b4];
  ushort4v o;
  o[0] = f2bf((v.x - mstat[c+0])*mstat[FIN+c+0] + 1e-4f);
  o[1] = f2bf((v.y - mstat[c+1])*mstat[FIN+c+1] + 1e-4f);
  o[2] = f2bf((v.z - mstat[c+2])*mstat[FIN+c+2] + 1e-4f);
  o[3] = f2bf((v.w - mstat[c+3])*mstat[FIN+c+3] + 1e-4f);
  *(ushort4v*)&out[b4] = o;
}

// csr_fill + w1 fused; also builds interleaved {col, w1} pairs
__global__ void csr_fill(const int* __restrict__ ei, const int* __restrict__ rowp,
                         const int* __restrict__ cnt, int* __restrict__ fillc,
                         const float* __restrict__ dis1,
                         int* __restrict__ ccol, int* __restrict__ crow, int* __restrict__ ceid,
                         int2* __restrict__ cw1){
  int id = blockIdx.x*blockDim.x + threadIdx.x;
  if (id < NE){
    int r = ei[id], c = ei[NE + id];
    int pos = atomicAdd(&fillc[r], 1);
    int idx = rowp[r] + pos;
    ccol[idx] = c; crow[idx] = r; ceid[idx] = id;
    cw1[idx] = make_int2(c, __float_as_int(dis1[r]*dis1[c]));
  } else if (id < NE + NN){
    int i = id - NE;
    int idx = rowp[i] + cnt[i];
    ccol[idx] = i; crow[idx] = i; ceid[idx] = -1;
    cw1[idx] = make_int2(i, __float_as_int(dis1[i]*dis1[i]));
  }
}

// ---------------- dual BN stats on bf16 X ----------------
__global__ __launch_bounds__(1024) void bnstats_dual(const unsigned short* __restrict__ X,
                                                     const float* __restrict__ na,
                                                     float* __restrict__ partials){
  __shared__ float lds[1024*17];
  const int t = threadIdx.x;
  const int cid = t & 127;
  const int rid = t >> 7;
  float sC[4]={0,0,0,0}, qC[4]={0,0,0,0}, sO[4]={0,0,0,0}, qO[4]={0,0,0,0};
  const int rowsPer = (NN + BNG - 1)/BNG;
  int r0 = blockIdx.x*rowsPer, r1 = r0 + rowsPer; if (r1 > NN) r1 = NN;
  for (int r = r0 + rid; r < r1; r += 8){
    float a0 = na[2*r], a1 = na[2*r+1];
    uint2 u = *(const uint2*)&X[(size_t)r*HID + cid*4];
    float e[4] = {bf2f(u.x & 0xffffu), bf2f(u.x >> 16), bf2f(u.y & 0xffffu), bf2f(u.y >> 16)};
#pragma unroll
    for (int i=0;i<4;i++){
      float vc = e[i]*a0, vo = e[i]*a1;
      sC[i]+=vc; qC[i]+=vc*vc; sO[i]+=vo; qO[i]+=vo*vo;
    }
  }
  int base = (rid*128 + cid)*17;
#pragma unroll
  for (int i=0;i<4;i++){
    lds[base+i]=sC[i]; lds[base+4+i]=qC[i]; lds[base+8+i]=sO[i]; lds[base+12+i]=qO[i];
  }
  __syncthreads();
  for (int idx = t; idx < 2048; idx += 1024){
    int ci = idx >> 4, i = idx & 15;
    float acc = 0.f;
    for (int g=0; g<8; ++g) acc += lds[(g*128 + ci)*17 + i];
    int grp = i >> 2, col = ci*4 + (i & 3);
    partials[(size_t)blockIdx.x*2048 + grp*HID + col] = acc;
  }
}

__global__ void bnfin_red2(const float* __restrict__ partials, float* __restrict__ mstatCO){
  __shared__ float lds[4][64][2];
  int t = threadIdx.x;
  int cl = t & 63, ch = t >> 6;
  int c = blockIdx.x*64 + cl;
  int off = blockIdx.y*1024;
  float s = 0.f, q = 0.f;
  for (int b = ch*64; b < ch*64 + 64; ++b){
    s += partials[(size_t)b*2048 + off + c];
    q += partials[(size_t)b*2048 + off + HID + c];
  }
  lds[ch][cl][0] = s; lds[ch][cl][1] = q;
  __syncthreads();
  if (ch == 0){
    s = lds[0][cl][0]+lds[1][cl][0]+lds[2][cl][0]+lds[3][cl][0];
    q = lds[0][cl][1]+lds[1][cl][1]+lds[2][cl][1]+lds[3][cl][1];
    float m = s/(float)NN;
    float v = q/(float)NN - m*m;
    mstatCO[blockIdx.y*1024 + c] = m;
    mstatCO[blockIdx.y*1024 + HID + c] = rsqrtf(v + 1e-5f);
  }
}

// ---------------- attention (bf16 X), weights staged in LDS ----------------
__global__ void att_node(const unsigned short* __restrict__ X, const float* __restrict__ nW,
                         const float* __restrict__ nb, const float* __restrict__ eW,
                         float* __restrict__ na, float* __restrict__ eab){
  __shared__ float wnl[1024], wet[1024], web[1024];
  int t = threadIdx.x;
  for (int i=t; i<1024; i+=256){ wnl[i]=nW[i]; wet[i]=eW[i]; web[i]=eW[1024+i]; }
  __syncthreads();
  int wv = blockIdx.x*4 + (t >> 6);
  int l = t & 63;
  uint4 u = ((const uint4*)(X + (size_t)wv*HID))[l];
  float xv[8] = {bf2f(u.x&0xffffu), bf2f(u.x>>16), bf2f(u.y&0xffffu), bf2f(u.y>>16),
                 bf2f(u.z&0xffffu), bf2f(u.z>>16), bf2f(u.w&0xffffu), bf2f(u.w>>16)};
  float s0=0,s1=0,s2=0,s3=0,s4=0,s5=0;
#pragma unroll
  for (int j=0; j<8; ++j){
    int k = l*8 + j;
    float x = xv[j];
    s0 += x * wnl[2*k];   s1 += x * wnl[2*k+1];
    s2 += x * wet[2*k];   s3 += x * wet[2*k+1];
    s4 += x * web[2*k];   s5 += x * web[2*k+1];
  }
  for (int m=1; m<64; m<<=1){
    s0 += __shfl_xor(s0,m); s1 += __shfl_xor(s1,m); s2 += __shfl_xor(s2,m);
    s3 += __shfl_xor(s3,m); s4 += __shfl_xor(s4,m); s5 += __shfl_xor(s5,m);
  }
  if (l == 0){
    float z0 = s0 + nb[0], z1 = s1 + nb[1];
    float mx = fmaxf(z0,z1);
    float e0 = expf(z0-mx), e1 = expf(z1-mx);
    float inv = 1.0f/(e0+e1);
    na[2*wv] = e0*inv; na[2*wv+1] = e1*inv;
    eab[4*wv] = s2; eab[4*wv+1] = s3; eab[4*wv+2] = s4; eab[4*wv+3] = s5;
  }
}

__global__ void att_edge(const int* __restrict__ ei, const float* __restrict__ eab,
                         const float* __restrict__ eb, float* __restrict__ att,
                         float* __restrict__ degc, float* __restrict__ dego){
  int e = blockIdx.x*blockDim.x + threadIdx.x;
  if (e >= NE) return;
  int r = ei[e], c = ei[NE+e];
  float z0 = eab[4*r]   + eab[4*c+2] + eb[0];
  float z1 = eab[4*r+1] + eab[4*c+3] + eb[1];
  float mx = fmaxf(z0,z1);
  float e0 = expf(z0-mx), e1 = expf(z1-mx);
  float inv = 1.0f/(e0+e1);
  float a0 = e0*inv, a1 = e1*inv;
  att[2*e] = a0; att[2*e+1] = a1;
  atomicAdd(&degc[r], a0);
  atomicAdd(&dego[r], a1);
}

__global__ void wco_kernel(const int* __restrict__ crow, const int* __restrict__ ccol,
                           const int* __restrict__ ceid, const float* __restrict__ att,
                           const float* __restrict__ degc, const float* __restrict__ dego,
                           const float* __restrict__ na,
                           float* __restrict__ wcv, float* __restrict__ wov,
                           float* __restrict__ Sc, float* __restrict__ So){
  int j = blockIdx.x*blockDim.x + threadIdx.x;
  if (j >= NE + NN) return;
  int r = crow[j], c = ccol[j], e = ceid[j];
  float a0 = (e < 0) ? 1.0f : att[2*e];
  float a1 = (e < 0) ? 1.0f : att[2*e+1];
  float wc = rsqrtf(degc[r]) * a0 * rsqrtf(degc[c]);
  float wo = rsqrtf(dego[r]) * a1 * rsqrtf(dego[c]);
  wcv[j] = wc * na[2*c];
  wov[j] = wo * na[2*c+1];
  atomicAdd(&Sc[r], wc);
  atomicAdd(&So[r], wo);
}

// ---------------- wave-per-row aggregation (int2 pairs), 8-deep ILP, BN affine epilogue ----------------
__global__ __launch_bounds__(256) void aggregate_bn(const unsigned short* __restrict__ A,
                                                    const int* __restrict__ rowp,
                                                    const int2* __restrict__ cw,
                                                    const float* __restrict__ stats,
                                                    float invM,
                                                    unsigned short* __restrict__ out){
  int row = blockIdx.x*4 + (threadIdx.x >> 6);
  int l = threadIdx.x & 63;
  const uint4* Av = (const uint4*)A;
  int s = rowp[row], e = rowp[row+1];
  float acc[8] = {0,0,0,0,0,0,0,0};
  float sw = 0.f;
  int j = s;
  for (; j+7 < e; j += 8){
    int2 p[8]; uint4 v[8];
#pragma unroll
    for (int k=0;k<8;k++) p[k] = cw[j+k];
#pragma unroll
    for (int k=0;k<8;k++) v[k] = Av[(size_t)p[k].x*64 + l];
#pragma unroll
    for (int k=0;k<8;k++){ float w = __int_as_float(p[k].y); fma8(acc, v[k], w); sw += w; }
  }
  for (; j+3 < e; j += 4){
    int2 p[4]; uint4 v[4];
#pragma unroll
    for (int k=0;k<4;k++) p[k] = cw[j+k];
#pragma unroll
    for (int k=0;k<4;k++) v[k] = Av[(size_t)p[k].x*64 + l];
#pragma unroll
    for (int k=0;k<4;k++){ float w = __int_as_float(p[k].y); fma8(acc, v[k], w); sw += w; }
  }
  for (; j < e; ++j){
    int2 p = cw[j];
    float w = __int_as_float(p.y);
    uint4 v = Av[(size_t)p.x*64 + l];
    fma8(acc, v, w);
    sw += w;
  }
  float g[8];
#pragma unroll
  for (int i=0;i<8;i++){
    int c = l*8 + i;
    float m = stats[c]*invM;
    float rs = rsqrtf(stats[512+c]*invM - m*m + 1e-5f);
    g[i] = rs*acc[i] + sw*(1e-4f - m*rs);
  }
  uint4 o;
  o.x = pk2(g[0],g[1]); o.y = pk2(g[2],g[3]); o.z = pk2(g[4],g[5]); o.w = pk2(g[6],g[7]);
  ((uint4*)out)[(size_t)row*64 + l] = o;
}

__global__ __launch_bounds__(256) void aggregate_dual(const unsigned short* __restrict__ A,
                                                      const int* __restrict__ rowp,
                                                      const int* __restrict__ ccol,
                                                      const float* __restrict__ wc,
                                                      const float* __restrict__ wo,
                                                      const float* __restrict__ Sc,
                                                      const float* __restrict__ So,
                                                      const float* __restrict__ mstatCO,
                                                      unsigned short* __restrict__ outC,
                                                      unsigned short* __restrict__ outO){
  int row = blockIdx.x*4 + (threadIdx.x >> 6);
  int l = threadIdx.x & 63;
  const uint4* Av = (const uint4*)A;
  int s = rowp[row], e = rowp[row+1];
  float aC[8] = {0,0,0,0,0,0,0,0};
  float aO[8] = {0,0,0,0,0,0,0,0};
  int j = s;
  for (; j+7 < e; j += 8){
    int cc[8]; uint4 v[8];
#pragma unroll
    for (int k=0;k<8;k++) cc[k] = ccol[j+k];
#pragma unroll
    for (int k=0;k<8;k++) v[k] = Av[(size_t)cc[k]*64 + l];
#pragma unroll
    for (int k=0;k<8;k++){ fma8(aC, v[k], wc[j+k]); fma8(aO, v[k], wo[j+k]); }
  }
  for (; j+3 < e; j += 4){
    int cc[4]; uint4 v[4];
#pragma unroll
    for (int k=0;k<4;k++) cc[k] = ccol[j+k];
#pragma unroll
    for (int k=0;k<4;k++) v[k] = Av[(size_t)cc[k]*64 + l];
#pragma unroll
    for (int k=0;k<4;k++){ fma8(aC, v[k], wc[j+k]); fma8(aO, v[k], wo[j+k]); }
  }
  for (; j < e; ++j){
    uint4 v = Av[(size_t)ccol[j]*64 + l];
    fma8(aC, v, wc[j]); fma8(aO, v, wo[j]);
  }
  float ScR = Sc[row], SoR = So[row];
  float gC[8], gO[8];
#pragma unroll
  for (int i=0;i<8;i++){
    int c = l*8 + i;
    float mc = mstatCO[c],      rc = mstatCO[512+c];
    float mo = mstatCO[1024+c], ro = mstatCO[1536+c];
    gC[i] = rc*aC[i] + ScR*(1e-4f - mc*rc);
    gO[i] = ro*aO[i] + SoR*(1e-4f - mo*ro);
  }
  uint4 oc, oo;
  oc.x = pk2(gC[0],gC[1]); oc.y = pk2(gC[2],gC[3]); oc.z = pk2(gC[4],gC[5]); oc.w = pk2(gC[6],gC[7]);
  oo.x = pk2(gO[0],gO[1]); oo.y = pk2(gO[2],gO[3]); oo.z = pk2(gO[4],gO[5]); oo.w = pk2(gO[6],gO[7]);
  ((uint4*)outC)[(size_t)row*64 + l] = oc;
  ((uint4*)outO)[(size_t)row*64 + l] = oo;
}

// ---------------- bf16 MFMA GEMM: XCD-chunked 1D grid, 3-buffer ring (vmcnt(8)), LDS-staged C ----------------
__global__ __launch_bounds__(256) void gemm_bt(const unsigned short* __restrict__ A,
                                               const unsigned short* __restrict__ Bt,
                                               unsigned short* __restrict__ O,
                                               const float* __restrict__ bias,
                                               float* __restrict__ stats,
                                               int M, int K, int relu, int split,
                                               const unsigned short* A2,
                                               const unsigned short* Bt2,
                                               unsigned short* O2,
                                               const float* bias2){
  extern __shared__ unsigned short smem[];   // 3 buffers of 8192 shorts (A 4096 + B 4096); Cs aliases
  unsigned short* Cs = smem;
  const int tid = threadIdx.x;
  const int w = tid >> 6, l = tid & 63;

  int lin = blockIdx.x;
  int total = gridDim.x;
  int q = total >> 3, r = total & 7;
  int xcd = lin & 7, idx = lin >> 3;
  int swz = (xcd < r ? xcd*(q+1) : r*(q+1) + (xcd - r)*q) + idx;
  if (split && swz >= split){ A = A2; Bt = Bt2; O = O2; bias = bias2; swz -= split; }
  const int m0 = (swz >> 2)*128, n0 = (swz & 3)*128;

  const int wm = w >> 1, wn = w & 1;
  const int lr = l & 15, lh = l >> 4;

  f32x4 acc[4][4];
#pragma unroll
  for (int i=0;i<4;i++)
#pragma unroll
    for (int j=0;j<4;j++) acc[i][j] = 0.0f;

  const int q0 = w*2, q1 = w*2+1;
  const int sub = l >> 2;
  const int kc  = (l & 3)*8;
  int ma0 = m0 + q0*16 + sub; if (ma0 >= M) ma0 = M-1;
  int ma1 = m0 + q1*16 + sub; if (ma1 >= M) ma1 = M-1;
  const int nb0 = n0 + q0*16 + sub;
  const int nb1 = n0 + q1*16 + sub;
  const unsigned short* Ar0 = A + (size_t)ma0*K + kc;
  const unsigned short* Ar1 = A + (size_t)ma1*K + kc;
  const unsigned short* Br0 = Bt + (size_t)nb0*K + kc;
  const unsigned short* Br1 = Bt + (size_t)nb1*K + kc;

  const int NT = K >> 5;
  gload16(&smem[0*8192 + q0*512], Ar0);
  gload16(&smem[0*8192 + q1*512], Ar1);
  gload16(&smem[0*8192 + 4096 + q0*512], Br0);
  gload16(&smem[0*8192 + 4096 + q1*512], Br1);
  if (NT > 1){
    gload16(&smem[1*8192 + q0*512], Ar0 + 32);
    gload16(&smem[1*8192 + q1*512], Ar1 + 32);
    gload16(&smem[1*8192 + 4096 + q0*512], Br0 + 32);
    gload16(&smem[1*8192 + 4096 + q1*512], Br1 + 32);
  }
  int cur = 0;
  for (int t=0; t<NT; ++t){
    if (t+2 < NT){
      int k1 = (t+2) << 5;
      int nb = cur + 2; if (nb >= 3) nb -= 3;
      gload16(&smem[nb*8192 + q0*512], Ar0 + k1);
      gload16(&smem[nb*8192 + q1*512], Ar1 + k1);
      gload16(&smem[nb*8192 + 4096 + q0*512], Br0 + k1);
      gload16(&smem[nb*8192 + 4096 + q1*512], Br1 + k1);
      asm volatile("s_waitcnt vmcnt(8)" ::: "memory");   // tile t landed; t+1,t+2 in flight
    } else if (t+1 < NT){
      asm volatile("s_waitcnt vmcnt(4)" ::: "memory");
    } else {
      asm volatile("s_waitcnt vmcnt(0)" ::: "memory");
    }
    __builtin_amdgcn_s_barrier();
    asm volatile("" ::: "memory");
    short8 af[4], bfr[4];
#pragma unroll
    for (int fm=0; fm<4; ++fm) af[fm]  = *(const short8*)&smem[cur*8192 + (wm*64 + fm*16 + lr)*32 + lh*8];
#pragma unroll
    for (int fn=0; fn<4; ++fn) bfr[fn] = *(const short8*)&smem[cur*8192 + 4096 + (wn*64 + fn*16 + lr)*32 + lh*8];
#pragma unroll
    for (int fm=0; fm<4; ++fm)
#pragma unroll
      for (int fn=0; fn<4; ++fn)
        acc[fm][fn] = __builtin_amdgcn_mfma_f32_16x16x32_bf16(af[fm], bfr[fn], acc[fm][fn], 0, 0, 0);
    asm volatile("" ::: "memory");
    __builtin_amdgcn_s_barrier();
    asm volatile("" ::: "memory");
    cur += 1; if (cur >= 3) cur = 0;
  }
  int dep = __float_as_int(acc[0][0][0]);
  int z_;
  asm volatile("v_and_b32 %0, 0, %1" : "=v"(z_) : "v"(dep));
  const float* biasp = bias + z_;

  float bv[4], cs[4]={0,0,0,0}, cq[4]={0,0,0,0};
  int col[4];
#pragma unroll
  for (int fn=0; fn<4; ++fn){ col[fn] = n0 + wn*64 + fn*16 + lr; bv[fn] = biasp[col[fn]]; }
#pragma unroll
  for (int fm=0; fm<4; ++fm){
#pragma unroll
    for (int j=0; j<4; ++j){
      int trow = wm*64 + fm*16 + lh*4 + j;
      bool valid = (m0 + trow) < M;
#pragma unroll
      for (int fn=0; fn<4; ++fn){
        float v = acc[fm][fn][j] + bv[fn];
        if (relu) v = fmaxf(v, 0.f);
        Cs[trow*136 + wn*64 + fn*16 + lr] = f2bf(v);
        if (valid){ cs[fn] += v; cq[fn] += v*v; }
      }
    }
  }
  __syncthreads();
#pragma unroll
  for (int i=0;i<8;i++){
    int trow = i*16 + (tid>>4);
    int colb = (tid&15)*8;
    uint4 vv = *(const uint4*)&Cs[trow*136 + colb];
    int grow = m0 + trow;
    if (grow < M) *(uint4*)&O[(size_t)grow*HID + n0 + colb] = vv;
  }
  if (stats){
#pragma unroll
    for (int m=16; m<64; m<<=1){
#pragma unroll
      for (int fn=0; fn<4; ++fn){ cs[fn] += __shfl_xor(cs[fn], m); cq[fn] += __shfl_xor(cq[fn], m); }
    }
    if (lh == 0){
#pragma unroll
      for (int fn=0; fn<4; ++fn){
        atomicAdd(&stats[col[fn]], cs[fn]);
        atomicAdd(&stats[512+col[fn]], cq[fn]);
      }
    }
  }
}

// batched fc1 gemm: M=1536 (3 branches x 512 rows), 3-buffer ring
struct FC1P { const unsigned short* Bt[3]; const float* bias[3]; };
__global__ __launch_bounds__(256) void gemm_fc1(const unsigned short* __restrict__ A, FC1P p,
                                                unsigned short* __restrict__ O,
                                                float* __restrict__ statsB){
  extern __shared__ unsigned short smem[];
  const int tid = threadIdx.x;
  const int w = tid >> 6, l = tid & 63;
  const int m0 = blockIdx.x*128, n0 = blockIdx.y*128;
  const int branch = blockIdx.x >> 2;
  const unsigned short* Bt = p.Bt[branch];
  const float* bias = p.bias[branch];
  float* stats = statsB + branch*1024;
  const int K = HID;
  const int wm = w >> 1, wn = w & 1;
  const int lr = l & 15, lh = l >> 4;

  f32x4 acc[4][4];
#pragma unroll
  for (int i=0;i<4;i++)
#pragma unroll
    for (int j=0;j<4;j++) acc[i][j] = 0.0f;

  const int q0 = w*2, q1 = w*2+1;
  const int sub = l >> 2;
  const int kc  = (l & 3)*8;
  const int ma0 = m0 + q0*16 + sub;
  const int ma1 = m0 + q1*16 + sub;
  const int nb0 = n0 + q0*16 + sub;
  const int nb1 = n0 + q1*16 + sub;
  const unsigned short* Ar0 = A + (size_t)ma0*K + kc;
  const unsigned short* Ar1 = A + (size_t)ma1*K + kc;
  const unsigned short* Br0 = Bt + (size_t)nb0*K + kc;
  const unsigned short* Br1 = Bt + (size_t)nb1*K + kc;

  const int NT = K >> 5;
  gload16(&smem[0*8192 + q0*512], Ar0);
  gload16(&smem[0*8192 + q1*512], Ar1);
  gload16(&smem[0*8192 + 4096 + q0*512], Br0);
  gload16(&smem[0*8192 + 4096 + q1*512], Br1);
  gload16(&smem[1*8192 + q0*512], Ar0 + 32);
  gload16(&smem[1*8192 + q1*512], Ar1 + 32);
  gload16(&smem[1*8192 + 4096 + q0*512], Br0 + 32);
  gload16(&smem[1*8192 + 4096 + q1*512], Br1 + 32);
  int cur = 0;
  for (int t=0; t<NT; ++t){
    if (t+2 < NT){
      int k1 = (t+2) << 5;
      int nb = cur + 2; if (nb >= 3) nb -= 3;
      gload16(&smem[nb*8192 + q0*512], Ar0 + k1);
      gload16(&smem[nb*8192 + q1*512], Ar1 + k1);
      gload16(&smem[nb*8192 + 4096 + q0*512], Br0 + k1);
      gload16(&smem[nb*8192 + 4096 + q1*512], Br1 + k1);
      asm volatile("s_waitcnt vmcnt(8)" ::: "memory");
    } else if (t+1 < NT){
      asm volatile("s_waitcnt vmcnt(4)" ::: "memory");
    } else {
      asm volatile("s_waitcnt vmcnt(0)" ::: "memory");
    }
    __builtin_amdgcn_s_barrier();
    asm volatile("" ::: "memory");
    short8 af[4], bfr[4];
#pragma unroll
    for (int fm=0; fm<4; ++fm) af[fm]  = *(const short8*)&smem[cur*8192 + (wm*64 + fm*16 + lr)*32 + lh*8];
#pragma unroll
    for (int fn=0; fn<4; ++fn) bfr[fn] = *(const short8*)&smem[cur*8192 + 4096 + (wn*64 + fn*16 + lr)*32 + lh*8];
#pragma unroll
    for (int fm=0; fm<4; ++fm)
#pragma unroll
      for (int fn=0; fn<4; ++fn)
        acc[fm][fn] = __builtin_amdgcn_mfma_f32_16x16x32_bf16(af[fm], bfr[fn], acc[fm][fn], 0, 0, 0);
    asm volatile("" ::: "memory");
    __builtin_amdgcn_s_barrier();
    asm volatile("" ::: "memory");
    cur += 1; if (cur >= 3) cur = 0;
  }
  int dep = __float_as_int(acc[0][0][0]);
  int z_;
  asm volatile("v_and_b32 %0, 0, %1" : "=v"(z_) : "v"(dep));
  const float* biasp = bias + z_;

  float bv[4], cs[4]={0,0,0,0}, cq[4]={0,0,0,0};
  int col[4];
#pragma unroll
  for (int fn=0; fn<4; ++fn){ col[fn] = n0 + wn*64 + fn*16 + lr; bv[fn] = biasp[col[fn]]; }
#pragma unroll
  for (int fm=0; fm<4; ++fm){
#pragma unroll
    for (int j=0; j<4; ++j){
      int row = m0 + wm*64 + fm*16 + lh*4 + j;
      bool real = (row & 511) < NG;
#pragma unroll
      for (int fn=0; fn<4; ++fn){
        float v = fmaxf(acc[fm][fn][j] + bv[fn], 0.f);
        O[(size_t)row*HID + col[fn]] = f2bf(v);
        if (real){ cs[fn] += v; cq[fn] += v*v; }
      }
    }
  }
#pragma unroll
  for (int m=16; m<64; m<<=1){
#pragma unroll
    for (int fn=0; fn<4; ++fn){ cs[fn] += __shfl_xor(cs[fn], m); cq[fn] += __shfl_xor(cq[fn], m); }
  }
  if (lh == 0){
#pragma unroll
    for (int fn=0; fn<4; ++fn){
      atomicAdd(&stats[col[fn]], cs[fn]);
      atomicAdd(&stats[512+col[fn]], cq[fn]);
    }
  }
}

// ---------------- pooling, both branches in one dispatch ----------------
__global__ void pool2(const unsigned short* __restrict__ XC, const unsigned short* __restrict__ XO,
                      const int* __restrict__ batch, float* __restrict__ gc, float* __restrict__ go){
  int g = blockIdx.x;
  int t = threadIdx.x;
  const unsigned short* X = blockIdx.y ? XO : XC;
  float* out = blockIdx.y ? go : gc;
  int lo = 0, hi = NN;
  while (lo < hi){ int mid = (lo+hi) >> 1; if (batch[mid] < g) lo = mid+1; else hi = mid; }
  int s = lo;
  lo = 0; hi = NN;
  while (lo < hi){ int mid = (lo+hi) >> 1; if (batch[mid] < g+1) lo = mid+1; else hi = mid; }
  int e = lo;
  float a0 = 0.f, a1 = 0.f;
  for (int i=s; i<e; ++i){
    unsigned int v = *(const unsigned int*)&X[(size_t)i*HID + t*2];
    a0 += bf2f(v & 0xffffu); a1 += bf2f(v >> 16);
  }
  out[(size_t)g*HID + t*2]     = a0;
  out[(size_t)g*HID + t*2 + 1] = a1;
}

// ---------------- readout BN1: batched 3-branch stats (two-stage, 32 blocks/branch) ----------------
__global__ __launch_bounds__(256) void bnstats3(const float* __restrict__ gc, const float* __restrict__ go,
                                                const int* __restrict__ perm, float* __restrict__ partials){
  __shared__ float lds[256*9];
  int br = blockIdx.y;
  int t = threadIdx.x;
  int cid = t & 127, rid = t >> 7;
  float s[4]={0,0,0,0}, q[4]={0,0,0,0};
  const int rowsPer = (NG + NB3 - 1)/NB3;
  int r0 = blockIdx.x*rowsPer, r1 = r0 + rowsPer; if (r1 > NG) r1 = NG;
  for (int r = r0 + rid; r < r1; r += 2){
    float4 v;
    if (br == 0)      v = *(const float4*)&gc[(size_t)r*HID + cid*4];
    else if (br == 1) v = *(const float4*)&go[(size_t)r*HID + cid*4];
    else {
      int ps = perm[r];
      float4 a = *(const float4*)&gc[(size_t)ps*HID + cid*4];
      float4 b = *(const float4*)&go[(size_t)r*HID + cid*4];
      v = make_float4(a.x+b.x, a.y+b.y, a.z+b.z, a.w+b.w);
    }
    float e[4] = {v.x, v.y, v.z, v.w};
#pragma unroll
    for (int i=0;i<4;i++){ s[i]+=e[i]; q[i]+=e[i]*e[i]; }
  }
  int base = (rid*128 + cid)*9;
#pragma unroll
  for (int i=0;i<4;i++){ lds[base+i]=s[i]; lds[base+4+i]=q[i]; }
  __syncthreads();
  for (int o = t; o < 1024; o += 256){
    int issq = o >> 9, col = o & 511;
    int ci = col >> 2, i = col & 3;
    float acc = lds[(0*128 + ci)*9 + issq*4 + i] + lds[(1*128 + ci)*9 + issq*4 + i];
    partials[(size_t)(br*NB3 + blockIdx.x)*1024 + issq*512 + col] = acc;
  }
}

__global__ void bnfin3(const float* __restrict__ partials, float* __restrict__ mstat3){
  __shared__ float lds[4][64][2];
  int t = threadIdx.x;
  int cl = t & 63, ch = t >> 6;
  int c = blockIdx.x*64 + cl;
  int br = blockIdx.y;
  float s = 0.f, q = 0.f;
  for (int b = ch*8; b < ch*8 + 8; ++b){
    s += partials[(size_t)(br*NB3 + b)*1024 + c];
    q += partials[(size_t)(br*NB3 + b)*1024 + 512 + c];
  }
  lds[ch][cl][0] = s; lds[ch][cl][1] = q;
  __syncthreads();
  if (ch == 0){
    s = lds[0][cl][0]+lds[1][cl][0]+lds[2][cl][0]+lds[3][cl][0];
    q = lds[0][cl][1]+lds[1][cl][1]+lds[2][cl][1]+lds[3][cl][1];
    float m = s/(float)NG;
    float v = q/(float)NG - m*m;
    mstat3[br*1024 + c] = m;
    mstat3[br*1024 + 512 + c] = rsqrtf(v + 1e-5f);
  }
}

__global__ void bncast3(const float* __restrict__ gc, const float* __restrict__ go,
                        const int* __restrict__ perm, const float* __restrict__ mstat3,
                        unsigned short* __restrict__ out){
  int idx = blockIdx.x*blockDim.x + threadIdx.x;
  if (idx >= 1536*128) return;
  int r = idx >> 7;
  int cg = idx & 127;
  int br = r >> 9, lr = r & 511;
  ushort4v o;
  if (lr >= NG){ o[0]=0; o[1]=0; o[2]=0; o[3]=0; }
  else {
    float4 v;
    if (br == 0)      v = *(const float4*)&gc[(size_t)lr*HID + cg*4];
    else if (br == 1) v = *(const float4*)&go[(size_t)lr*HID + cg*4];
    else {
      int ps = perm[lr];
      float4 a = *(const float4*)&gc[(size_t)ps*HID + cg*4];
      float4 b = *(const float4*)&go[(size_t)lr*HID + cg*4];
      v = make_float4(a.x+b.x, a.y+b.y, a.z+b.z, a.w+b.w);
    }
    const float* ms = mstat3 + br*1024;
    int c = cg*4;
    o[0] = f2bf((v.x - ms[c+0])*ms[512+c+0] + 1e-4f);
    o[1] = f2bf((v.y - ms[c+1])*ms[512+c+1] + 1e-4f);
    o[2] = f2bf((v.z - ms[c+2])*ms[512+c+2] + 1e-4f);
    o[3] = f2bf((v.w - ms[c+3])*ms[512+c+3] + 1e-4f);
  }
  *(ushort4v*)&out[(size_t)r*HID + cg*4] = o;
}

// ---------------- final: batched BN2 -> fc2 -> log_softmax ----------------
struct ROP { const float* W2[3]; const float* b2[3]; };
__global__ void readout_final3(const unsigned short* __restrict__ T, const float* __restrict__ statsB,
                               float invM, ROP p, float* __restrict__ out){
  int g = blockIdx.x;
  int br = blockIdx.y;
  int l = threadIdx.x;
  const float* stats = statsB + br*1024;
  const float* W2 = p.W2[br];
  const float* b2 = p.b2[br];
  float acc[NCLS];
#pragma unroll
  for (int c=0; c<NCLS; ++c) acc[c] = 0.f;
  uint4 u = ((const uint4*)(T + (size_t)(br*512 + g)*HID))[l];
  float xv[8] = {bf2f(u.x&0xffffu), bf2f(u.x>>16), bf2f(u.y&0xffffu), bf2f(u.y>>16),
                 bf2f(u.z&0xffffu), bf2f(u.z>>16), bf2f(u.w&0xffffu), bf2f(u.w>>16)};
#pragma unroll
  for (int j=0; j<8; ++j){
    int k = l*8 + j;
    float m = stats[k]*invM;
    float rs = rsqrtf(stats[512+k]*invM - m*m + 1e-5f);
    float v = (xv[j] - m)*rs + 1e-4f;
#pragma unroll
    for (int c=0; c<NCLS; ++c) acc[c] += v * W2[k*NCLS + c];
  }
  for (int m=1; m<64; m<<=1){
#pragma unroll
    for (int c=0; c<NCLS; ++c) acc[c] += __shfl_xor(acc[c], m);
  }
  if (l == 0){
    float z[NCLS];
    float mx = -1e30f;
#pragma unroll
    for (int c=0; c<NCLS; ++c){ z[c] = acc[c] + b2[c]; mx = fmaxf(mx, z[c]); }
    float s = 0.f;
#pragma unroll
    for (int c=0; c<NCLS; ++c) s += expf(z[c]-mx);
    float lse = mx + logf(s);
#pragma unroll
    for (int c=0; c<NCLS; ++c) out[(size_t)(br*NG + g)*NCLS + c] = z[c] - lse;
  }
}

extern "C" void kernel_launch(void* const* d_in, const int* in_sizes, int n_in,
                              void* d_out, int out_size, void* d_ws, size_t ws_size,
                              hipStream_t stream){
  (void)in_sizes; (void)n_in; (void)out_size;
  const float* x      = (const float*)d_in[0];
  const int*   ei     = (const int*)d_in[1];
  const int*   batch  = (const int*)d_in[2];
  const int*   perm   = (const int*)d_in[3];
  const float* convfW = (const float*)d_in[4];
  const float* convfB = (const float*)d_in[5];
  const float* convsW = (const float*)d_in[6];
  const float* convsB = (const float*)d_in[7];
  const float* eattW  = (const float*)d_in[8];
  const float* eattB  = (const float*)d_in[9];
  const float* nattW  = (const float*)d_in[10];
  const float* nattB  = (const float*)d_in[11];
  const float* ctxW   = (const float*)d_in[12];
  const float* ctxB   = (const float*)d_in[13];
  const float* objW   = (const float*)d_in[14];
  const float* objB   = (const float*)d_in[15];
  const float* fc1W[3] = {(const float*)d_in[16], (const float*)d_in[20], (const float*)d_in[24]};
  const float* fc1B[3] = {(const float*)d_in[17], (const float*)d_in[21], (const float*)d_in[25]};
  const float* fc2W[3] = {(const float*)d_in[18], (const float*)d_in[22], (const float*)d_in[26]};
  const float* fc2B[3] = {(const float*)d_in[19], (const float*)d_in[23], (const float*)d_in[27]};
  float* out = (float*)d_out;

  char* p = (char*)d_ws;
  auto alloc = [&](size_t bytes)->char*{ char* r = p; p += (bytes + 255) & ~((size_t)255); return r; };
  const int T = NE + NN;
  unsigned short* Xbf = (unsigned short*)alloc((size_t)NN*HID*2);
  unsigned short* Gbf = (unsigned short*)alloc((size_t)NN*HID*2);
  unsigned short* GbfO= (unsigned short*)alloc((size_t)NN*HID*2);
  unsigned short* XbfO= (unsigned short*)alloc((size_t)NN*HID*2);
  unsigned short* Abf = (unsigned short*)alloc((size_t)NN*FIN*2);
  unsigned short* WtF = (unsigned short*)alloc((size_t)HID*FIN*2);
  unsigned short* WtL = (unsigned short*)alloc((size_t)3*HID*HID*2);
  unsigned short* WtC = (unsigned short*)alloc((size_t)HID*HID*2);
  unsigned short* WtO = (unsigned short*)alloc((size_t)HID*HID*2);
  unsigned short* WtR = (unsigned short*)alloc((size_t)3*HID*HID*2);
  int* cnt   = (int*)alloc((size_t)NN*4);
  int* fillc = (int*)alloc((size_t)NN*4);
  int* rowp  = (int*)alloc((size_t)(NN+1)*4);
  int* bsum  = (int*)alloc(32*4);
  int* ccol  = (int*)alloc((size_t)T*4);
  int* crow  = (int*)alloc((size_t)T*4);
  int* ceid  = (int*)alloc((size_t)T*4);
  int2* cw1  = (int2*)alloc((size_t)T*8);
  float* wcv = (float*)alloc((size_t)T*4);
  float* wov = (float*)alloc((size_t)T*4);
  float* dis1 = (float*)alloc((size_t)NN*4);
  float* degc = (float*)alloc((size_t)NN*4);
  float* dego = (float*)alloc((size_t)NN*4);
  float* Sc   = (float*)alloc((size_t)NN*4);
  float* So   = (float*)alloc((size_t)NN*4);
  float* stats6 = (float*)alloc(6*1024*4);
  float* mstat  = (float*)alloc(2*HID*4);
  float* mstatCO= (float*)alloc(2*1024*4);
  float* mstat3 = (float*)alloc(3*1024*4);
  float* na   = (float*)alloc((size_t)NN*2*4);
  float* eab  = (float*)alloc((size_t)NN*4*4);
  float* att  = (float*)alloc((size_t)NE*2*4);
  float* gc   = (float*)alloc((size_t)NG*HID*4);
  float* go   = (float*)alloc((size_t)NG*HID*4);
  float* part = (float*)alloc((size_t)BNG*2048*4);
  if ((size_t)(p - (char*)d_ws) > ws_size){
    sentinel_k<<<1,1,0,stream>>>(out);
    return;
  }
  unsigned short* Abf3 = Abf;
  unsigned short* Gbf3 = GbfO;
  const float invNN = 1.0f/(float)NN;
  const float invNG = 1.0f/(float)NG;
  const int GEMM_LDS = 3*8192*2;   // 49152 B: 3-buffer ring; Cs (34816B) aliases

  // setup
  W2BT wp;
  wp.src[0]=convfW; wp.dst[0]=WtF;
  for (int i=0;i<3;i++){ wp.src[1+i]=convsW+(size_t)i*HID*HID; wp.dst[1+i]=WtL+(size_t)i*HID*HID; }
  wp.src[4]=ctxW; wp.dst[4]=WtC;
  wp.src[5]=objW; wp.dst[5]=WtO;
  for (int i=0;i<3;i++){ wp.src[6+i]=fc1W[i]; wp.dst[6+i]=WtR+(size_t)i*HID*HID; }
  setup_all<<<(FIN*HID + 8*HID*HID + 255)/256, 256, 0, stream>>>(wp, cnt, fillc, degc, dego, Sc, So, stats6);

  // D1: csr_count + conv bnstats
  d1_count_stats<<<BNG + (NE+1023)/1024, 1024, 0, stream>>>(ei, cnt, x, part);
  // D2: scan1 + conv bnfin
  d2_scan_fin<<<20 + FIN/64, 1024, 0, stream>>>(cnt, rowp, dis1, bsum, part, mstat);
  // D3: scan3 + conv bncast
  d3_scan_cast<<<20 + (NN*FIN/4 + 1023)/1024, 1024, 0, stream>>>(rowp, bsum, x, mstat, Abf);
  // CSR fill
  csr_fill<<<(T+255)/256,256,0,stream>>>(ei, rowp, cnt, fillc, dis1, ccol, crow, ceid, cw1);

  const int NBLK = ((NN+127)/128)*4;   // 628

  // conv_feat gemm
  gemm_bt<<<NBLK,256,GEMM_LDS,stream>>>(Abf, WtF, Xbf, convfB, stats6, NN, FIN, 1,
                                        0, nullptr, nullptr, nullptr, nullptr);

  // 3 GCN layers
  for (int i=0;i<3;i++){
    aggregate_bn<<<NN/4,256,0,stream>>>(Xbf, rowp, cw1, stats6 + i*1024, invNN, Gbf);
    gemm_bt<<<NBLK,256,GEMM_LDS,stream>>>(Gbf, WtL+(size_t)i*HID*HID, Xbf,
                                          convsB+(size_t)i*HID,
                                          (i<2) ? (stats6 + (i+1)*1024) : nullptr,
                                          NN, HID, 1, 0, nullptr, nullptr, nullptr, nullptr);
  }

  // attention
  att_node<<<NN/4,256,0,stream>>>(Xbf, nattW, nattB, eattW, na, eab);
  att_edge<<<(NE+255)/256,256,0,stream>>>(ei, eab, eattB, att, degc, dego);
  wco_kernel<<<(T+255)/256,256,0,stream>>>(crow, ccol, ceid, att, degc, dego, na, wcv, wov, Sc, So);

  // ctx + obj
  bnstats_dual<<<BNG,1024,0,stream>>>(Xbf, na, part);
  bnfin_red2<<<dim3(8,2),256,0,stream>>>(part, mstatCO);
  aggregate_dual<<<NN/4,256,0,stream>>>(Xbf, rowp, ccol, wcv, wov, Sc, So, mstatCO, Gbf, GbfO);
  gemm_bt<<<2*NBLK,256,GEMM_LDS,stream>>>(Gbf, WtC, Xbf, ctxB, nullptr, NN, HID, 1,
                                          NBLK, GbfO, WtO, XbfO, objB);
  pool2<<<dim3(NG,2),256,0,stream>>>(Xbf, XbfO, batch, gc, go);

  // readouts, batched across the 3 branches (two-stage stats: 32 blocks/branch)
  bnstats3<<<dim3(NB3,3),256,0,stream>>>(gc, go, perm, part);
  bnfin3<<<dim3(8,3),256,0,stream>>>(part, mstat3);
  bncast3<<<(1536*128+255)/256,256,0,stream>>>(gc, go, perm, mstat3, Abf3);
  FC1P fp;
  for (int i=0;i<3;i++){ fp.Bt[i] = WtR+(size_t)i*HID*HID; fp.bias[i] = fc1B[i]; }
  gemm_fc1<<<dim3(12,4),256,GEMM_LDS,stream>>>(Abf3, fp, Gbf3, stats6 + 3*1024);
  ROP rp;
  for (int i=0;i<3;i++){ rp.W2[i] = fc2W[i]; rp.b2[i] = fc2B[i]; }
  readout_final3<<<dim3(NG,3),64,0,stream>>>(Gbf3, stats6 + 3*1024, invNG, rp, out);
}

// Round 10
// 430.119 us; speedup vs baseline: 1.0912x; 1.0079x over previous
//
#include <hip/hip_runtime.h>
#include <stdint.h>

#define NN 20000
#define NE 160000
#define NG 500
#define FIN 128
#define HID 512
#define NCLS 10
#define BNG 256
#define NB3 32

typedef __attribute__((ext_vector_type(8))) short short8;
typedef __attribute__((ext_vector_type(4))) float f32x4;
typedef __attribute__((ext_vector_type(4))) unsigned short ushort4v;

__device__ __forceinline__ float bf2f(unsigned int u){
  union{unsigned int i; float f;} x; x.i = u<<16; return x.f;
}
__device__ __forceinline__ unsigned short f2bf(float f){
  union{float f; unsigned int i;} x; x.f=f;
  unsigned int r = x.i + 0x7fffu + ((x.i>>16)&1u);
  return (unsigned short)(r>>16);
}
__device__ __forceinline__ unsigned int pk2(float a, float b){
  return (unsigned int)f2bf(a) | ((unsigned int)f2bf(b) << 16);
}

__device__ __forceinline__ void gload16(unsigned short* lds, const unsigned short* g){
  __builtin_amdgcn_global_load_lds((const __attribute__((address_space(1))) unsigned int*)g,
                                   (__attribute__((address_space(3))) unsigned int*)lds,
                                   16, 0, 0);
}

__device__ __forceinline__ void fma8(float* acc, uint4 v, float w){
  acc[0] += w*bf2f(v.x & 0xffffu); acc[1] += w*bf2f(v.x >> 16);
  acc[2] += w*bf2f(v.y & 0xffffu); acc[3] += w*bf2f(v.y >> 16);
  acc[4] += w*bf2f(v.z & 0xffffu); acc[5] += w*bf2f(v.z >> 16);
  acc[6] += w*bf2f(v.w & 0xffffu); acc[7] += w*bf2f(v.w >> 16);
}

__global__ void sentinel_k(float* out){ out[0] = 12345.0f; }

// statsA layout (floats, all zeroed in setup):
//   [0..1023]      L0-input stats (conv gemm out)     sum/sumsq 512+512
//   [1024..2047]   L1-input stats
//   [2048..3071]   L2-input stats
//   [3072..6143]   fc1-out stats x3 (readout BN2)
//   [6144..6399]   conv-input stats (F=128): sum[128], sumsq[128]
//   [6400..8447]   dual stats: sC[512] qC[512] sO[512] qO[512]
//   [8448..11519]  readout BN1 stats x3 branches (sum[512] sumsq[512] each)
#define STATSA_N 12288

// ---------------- setup: all weight transposes + all init in one dispatch ----------------
struct W2BT { const float* src[9]; unsigned short* dst[9]; };
__global__ void setup_all(W2BT p, int* __restrict__ cnt, int* __restrict__ fillc,
                          float* __restrict__ degc, float* __restrict__ dego,
                          float* __restrict__ Sc, float* __restrict__ So,
                          float* __restrict__ statsA){
  int idx = blockIdx.x*blockDim.x + threadIdx.x;
  if (idx < FIN*HID + 8*HID*HID){
    int seg, off, K;
    if (idx < FIN*HID){ seg = 0; off = idx; K = FIN; }
    else {
      int r = idx - FIN*HID;
      seg = 1 + (r >> 18); off = r & (HID*HID-1); K = HID;
    }
    int k = off >> 9, n = off & 511;
    p.dst[seg][(size_t)n*K + k] = f2bf(p.src[seg][off]);
  }
  if (idx < NN){ cnt[idx]=0; fillc[idx]=0; degc[idx]=1.0f; dego[idx]=1.0f; Sc[idx]=0.f; So[idx]=0.f; }
  if (idx < STATSA_N) statsA[idx] = 0.f;
}

// ---------------- D1: csr_count + conv BN stats stage 1 (blockIdx split, atomic out) ----------------
__global__ __launch_bounds__(1024) void d1_count_stats(const int* __restrict__ ei, int* __restrict__ cnt,
                                                       const float* __restrict__ X, float* __restrict__ cstat){
  __shared__ float lds[1024*9];
  const int t = threadIdx.x;
  if (blockIdx.x >= BNG){
    int e = (blockIdx.x - BNG)*1024 + t;
    if (e < NE) atomicAdd(&cnt[ei[e]], 1);
    return;
  }
  const int cg = FIN >> 2;            // 32
  const int cid = t & (cg-1);
  const int rid = t / cg;
  const int rpb = 1024 / cg;          // 32
  float s0=0,s1=0,s2=0,s3=0,q0=0,q1=0,q2=0,q3=0;
  const int rowsPer = (NN + BNG - 1)/BNG;
  int r0 = blockIdx.x*rowsPer, r1 = r0 + rowsPer; if (r1 > NN) r1 = NN;
  for (int r = r0 + rid; r < r1; r += rpb){
    float4 v = *(const float4*)&X[(size_t)r*FIN + cid*4];
    s0+=v.x; q0+=v.x*v.x; s1+=v.y; q1+=v.y*v.y; s2+=v.z; q2+=v.z*v.z; s3+=v.w; q3+=v.w*v.w;
  }
  int base = (rid*cg + cid)*9;
  lds[base+0]=s0; lds[base+1]=s1; lds[base+2]=s2; lds[base+3]=s3;
  lds[base+4]=q0; lds[base+5]=q1; lds[base+6]=q2; lds[base+7]=q3;
  __syncthreads();
  if (t < cg*8){
    int ci = t >> 3, i = t & 7;
    float acc = 0.f;
    for (int g=0; g<rpb; ++g) acc += lds[(g*cg + ci)*9 + i];
    int col = ci*4 + (i & 3);
    atomicAdd(&cstat[(i < 4) ? col : FIN + col], acc);
  }
}

// ---------------- D2: rowptr scan stage 1 ----------------
__global__ __launch_bounds__(1024) void d2_scan(const int* __restrict__ cnt, int* __restrict__ rowp,
                                                float* __restrict__ dis1, int* __restrict__ bsum){
  __shared__ int buf[1024];
  int t = threadIdx.x;
  int i = blockIdx.x*1024 + t;
  int v = 0;
  if (i < NN){ v = cnt[i] + 1; dis1[i] = rsqrtf((float)v); }
  buf[t] = v;
  __syncthreads();
  for (int off=1; off<1024; off<<=1){
    int xv = (t >= off) ? buf[t-off] : 0;
    __syncthreads();
    buf[t] += xv;
    __syncthreads();
  }
  if (i < NN) rowp[i+1] = buf[t];
  if (t == 1023) bsum[blockIdx.x] = buf[1023];
}

// ---------------- D3: scan3 + conv bncast (blockIdx split, inline BN from raw sums) ----------------
__global__ __launch_bounds__(1024) void d3_scan_cast(int* __restrict__ rowp, const int* __restrict__ bsum,
                                                     const float* __restrict__ X, const float* __restrict__ cstat,
                                                     float invM, unsigned short* __restrict__ out){
  __shared__ int base;
  int t = threadIdx.x;
  if (blockIdx.x < 20){
    int bx = blockIdx.x;
    if (t == 0){
      int a = 0;
      for (int b=0; b<bx; ++b) a += bsum[b];
      base = a;
    }
    __syncthreads();
    int i = bx*1024 + t;
    if (i < NN) rowp[i+1] += base;
    if (i == 0) rowp[0] = 0;
    return;
  }
  int idx = (blockIdx.x - 20)*1024 + t;
  int total4 = NN*FIN/4;
  if (idx >= total4) return;
  int b4 = idx*4;
  int c = b4 & (FIN-1);
  float4 v = *(const float4*)&X[b4];
  float e[4] = {v.x, v.y, v.z, v.w};
  ushort4v o;
#pragma unroll
  for (int i=0;i<4;i++){
    float m = cstat[c+i]*invM;
    float rs = rsqrtf(cstat[FIN+c+i]*invM - m*m + 1e-5f);
    o[i] = f2bf((e[i] - m)*rs + 1e-4f);
  }
  *(ushort4v*)&out[b4] = o;
}

// csr_fill + w1 fused; also builds interleaved {col, w1} pairs
__global__ void csr_fill(const int* __restrict__ ei, const int* __restrict__ rowp,
                         const int* __restrict__ cnt, int* __restrict__ fillc,
                         const float* __restrict__ dis1,
                         int* __restrict__ ccol, int* __restrict__ crow, int* __restrict__ ceid,
                         int2* __restrict__ cw1){
  int id = blockIdx.x*blockDim.x + threadIdx.x;
  if (id < NE){
    int r = ei[id], c = ei[NE + id];
    int pos = atomicAdd(&fillc[r], 1);
    int idx = rowp[r] + pos;
    ccol[idx] = c; crow[idx] = r; ceid[idx] = id;
    cw1[idx] = make_int2(c, __float_as_int(dis1[r]*dis1[c]));
  } else if (id < NE + NN){
    int i = id - NE;
    int idx = rowp[i] + cnt[i];
    ccol[idx] = i; crow[idx] = i; ceid[idx] = -1;
    cw1[idx] = make_int2(i, __float_as_int(dis1[i]*dis1[i]));
  }
}

// ---------------- dual BN stats on bf16 X (atomic out) ----------------
__global__ __launch_bounds__(1024) void bnstats_dual(const unsigned short* __restrict__ X,
                                                     const float* __restrict__ na,
                                                     float* __restrict__ dstat){
  __shared__ float lds[1024*17];
  const int t = threadIdx.x;
  const int cid = t & 127;
  const int rid = t >> 7;
  float sC[4]={0,0,0,0}, qC[4]={0,0,0,0}, sO[4]={0,0,0,0}, qO[4]={0,0,0,0};
  const int rowsPer = (NN + BNG - 1)/BNG;
  int r0 = blockIdx.x*rowsPer, r1 = r0 + rowsPer; if (r1 > NN) r1 = NN;
  for (int r = r0 + rid; r < r1; r += 8){
    float a0 = na[2*r], a1 = na[2*r+1];
    uint2 u = *(const uint2*)&X[(size_t)r*HID + cid*4];
    float e[4] = {bf2f(u.x & 0xffffu), bf2f(u.x >> 16), bf2f(u.y & 0xffffu), bf2f(u.y >> 16)};
#pragma unroll
    for (int i=0;i<4;i++){
      float vc = e[i]*a0, vo = e[i]*a1;
      sC[i]+=vc; qC[i]+=vc*vc; sO[i]+=vo; qO[i]+=vo*vo;
    }
  }
  int base = (rid*128 + cid)*17;
#pragma unroll
  for (int i=0;i<4;i++){
    lds[base+i]=sC[i]; lds[base+4+i]=qC[i]; lds[base+8+i]=sO[i]; lds[base+12+i]=qO[i];
  }
  __syncthreads();
  for (int idx = t; idx < 2048; idx += 1024){
    int ci = idx >> 4, i = idx & 15;
    float acc = 0.f;
    for (int g=0; g<8; ++g) acc += lds[(g*128 + ci)*17 + i];
    int grp = i >> 2, col = ci*4 + (i & 3);
    atomicAdd(&dstat[grp*HID + col], acc);
  }
}

// ---------------- attention (bf16 X), weights staged in LDS ----------------
__global__ void att_node(const unsigned short* __restrict__ X, const float* __restrict__ nW,
                         const float* __restrict__ nb, const float* __restrict__ eW,
                         float* __restrict__ na, float* __restrict__ eab){
  __shared__ float wnl[1024], wet[1024], web[1024];
  int t = threadIdx.x;
  for (int i=t; i<1024; i+=256){ wnl[i]=nW[i]; wet[i]=eW[i]; web[i]=eW[1024+i]; }
  __syncthreads();
  int wv = blockIdx.x*4 + (t >> 6);
  int l = t & 63;
  uint4 u = ((const uint4*)(X + (size_t)wv*HID))[l];
  float xv[8] = {bf2f(u.x&0xffffu), bf2f(u.x>>16), bf2f(u.y&0xffffu), bf2f(u.y>>16),
                 bf2f(u.z&0xffffu), bf2f(u.z>>16), bf2f(u.w&0xffffu), bf2f(u.w>>16)};
  float s0=0,s1=0,s2=0,s3=0,s4=0,s5=0;
#pragma unroll
  for (int j=0; j<8; ++j){
    int k = l*8 + j;
    float x = xv[j];
    s0 += x * wnl[2*k];   s1 += x * wnl[2*k+1];
    s2 += x * wet[2*k];   s3 += x * wet[2*k+1];
    s4 += x * web[2*k];   s5 += x * web[2*k+1];
  }
  for (int m=1; m<64; m<<=1){
    s0 += __shfl_xor(s0,m); s1 += __shfl_xor(s1,m); s2 += __shfl_xor(s2,m);
    s3 += __shfl_xor(s3,m); s4 += __shfl_xor(s4,m); s5 += __shfl_xor(s5,m);
  }
  if (l == 0){
    float z0 = s0 + nb[0], z1 = s1 + nb[1];
    float mx = fmaxf(z0,z1);
    float e0 = expf(z0-mx), e1 = expf(z1-mx);
    float inv = 1.0f/(e0+e1);
    na[2*wv] = e0*inv; na[2*wv+1] = e1*inv;
    eab[4*wv] = s2; eab[4*wv+1] = s3; eab[4*wv+2] = s4; eab[4*wv+3] = s5;
  }
}

__global__ void att_edge(const int* __restrict__ ei, const float* __restrict__ eab,
                         const float* __restrict__ eb, float* __restrict__ att,
                         float* __restrict__ degc, float* __restrict__ dego){
  int e = blockIdx.x*blockDim.x + threadIdx.x;
  if (e >= NE) return;
  int r = ei[e], c = ei[NE+e];
  float z0 = eab[4*r]   + eab[4*c+2] + eb[0];
  float z1 = eab[4*r+1] + eab[4*c+3] + eb[1];
  float mx = fmaxf(z0,z1);
  float e0 = expf(z0-mx), e1 = expf(z1-mx);
  float inv = 1.0f/(e0+e1);
  float a0 = e0*inv, a1 = e1*inv;
  att[2*e] = a0; att[2*e+1] = a1;
  atomicAdd(&degc[r], a0);
  atomicAdd(&dego[r], a1);
}

__global__ void wco_kernel(const int* __restrict__ crow, const int* __restrict__ ccol,
                           const int* __restrict__ ceid, const float* __restrict__ att,
                           const float* __restrict__ degc, const float* __restrict__ dego,
                           const float* __restrict__ na,
                           float* __restrict__ wcv, float* __restrict__ wov,
                           float* __restrict__ Sc, float* __restrict__ So){
  int j = blockIdx.x*blockDim.x + threadIdx.x;
  if (j >= NE + NN) return;
  int r = crow[j], c = ccol[j], e = ceid[j];
  float a0 = (e < 0) ? 1.0f : att[2*e];
  float a1 = (e < 0) ? 1.0f : att[2*e+1];
  float wc = rsqrtf(degc[r]) * a0 * rsqrtf(degc[c]);
  float wo = rsqrtf(dego[r]) * a1 * rsqrtf(dego[c]);
  wcv[j] = wc * na[2*c];
  wov[j] = wo * na[2*c+1];
  atomicAdd(&Sc[r], wc);
  atomicAdd(&So[r], wo);
}

// ---------------- wave-per-row aggregation (int2 pairs), 8-deep ILP, BN affine epilogue ----------------
__global__ __launch_bounds__(256) void aggregate_bn(const unsigned short* __restrict__ A,
                                                    const int* __restrict__ rowp,
                                                    const int2* __restrict__ cw,
                                                    const float* __restrict__ stats,
                                                    float invM,
                                                    unsigned short* __restrict__ out){
  int row = blockIdx.x*4 + (threadIdx.x >> 6);
  int l = threadIdx.x & 63;
  const uint4* Av = (const uint4*)A;
  int s = rowp[row], e = rowp[row+1];
  float acc[8] = {0,0,0,0,0,0,0,0};
  float sw = 0.f;
  int j = s;
  for (; j+7 < e; j += 8){
    int2 p[8]; uint4 v[8];
#pragma unroll
    for (int k=0;k<8;k++) p[k] = cw[j+k];
#pragma unroll
    for (int k=0;k<8;k++) v[k] = Av[(size_t)p[k].x*64 + l];
#pragma unroll
    for (int k=0;k<8;k++){ float w = __int_as_float(p[k].y); fma8(acc, v[k], w); sw += w; }
  }
  for (; j+3 < e; j += 4){
    int2 p[4]; uint4 v[4];
#pragma unroll
    for (int k=0;k<4;k++) p[k] = cw[j+k];
#pragma unroll
    for (int k=0;k<4;k++) v[k] = Av[(size_t)p[k].x*64 + l];
#pragma unroll
    for (int k=0;k<4;k++){ float w = __int_as_float(p[k].y); fma8(acc, v[k], w); sw += w; }
  }
  for (; j < e; ++j){
    int2 p = cw[j];
    float w = __int_as_float(p.y);
    uint4 v = Av[(size_t)p.x*64 + l];
    fma8(acc, v, w);
    sw += w;
  }
  float g[8];
#pragma unroll
  for (int i=0;i<8;i++){
    int c = l*8 + i;
    float m = stats[c]*invM;
    float rs = rsqrtf(stats[512+c]*invM - m*m + 1e-5f);
    g[i] = rs*acc[i] + sw*(1e-4f - m*rs);
  }
  uint4 o;
  o.x = pk2(g[0],g[1]); o.y = pk2(g[2],g[3]); o.z = pk2(g[4],g[5]); o.w = pk2(g[6],g[7]);
  ((uint4*)out)[(size_t)row*64 + l] = o;
}

// dual aggregation; BN affine computed inline from raw dual sums
__global__ __launch_bounds__(256) void aggregate_dual(const unsigned short* __restrict__ A,
                                                      const int* __restrict__ rowp,
                                                      const int* __restrict__ ccol,
                                                      const float* __restrict__ wc,
                                                      const float* __restrict__ wo,
                                                      const float* __restrict__ Sc,
                                                      const float* __restrict__ So,
                                                      const float* __restrict__ dstat,
                                                      float invM,
                                                      unsigned short* __restrict__ outC,
                                                      unsigned short* __restrict__ outO){
  int row = blockIdx.x*4 + (threadIdx.x >> 6);
  int l = threadIdx.x & 63;
  const uint4* Av = (const uint4*)A;
  int s = rowp[row], e = rowp[row+1];
  float aC[8] = {0,0,0,0,0,0,0,0};
  float aO[8] = {0,0,0,0,0,0,0,0};
  int j = s;
  for (; j+7 < e; j += 8){
    int cc[8]; uint4 v[8];
#pragma unroll
    for (int k=0;k<8;k++) cc[k] = ccol[j+k];
#pragma unroll
    for (int k=0;k<8;k++) v[k] = Av[(size_t)cc[k]*64 + l];
#pragma unroll
    for (int k=0;k<8;k++){ fma8(aC, v[k], wc[j+k]); fma8(aO, v[k], wo[j+k]); }
  }
  for (; j+3 < e; j += 4){
    int cc[4]; uint4 v[4];
#pragma unroll
    for (int k=0;k<4;k++) cc[k] = ccol[j+k];
#pragma unroll
    for (int k=0;k<4;k++) v[k] = Av[(size_t)cc[k]*64 + l];
#pragma unroll
    for (int k=0;k<4;k++){ fma8(aC, v[k], wc[j+k]); fma8(aO, v[k], wo[j+k]); }
  }
  for (; j < e; ++j){
    uint4 v = Av[(size_t)ccol[j]*64 + l];
    fma8(aC, v, wc[j]); fma8(aO, v, wo[j]);
  }
  float ScR = Sc[row], SoR = So[row];
  float gC[8], gO[8];
#pragma unroll
  for (int i=0;i<8;i++){
    int c = l*8 + i;
    float mc = dstat[c]*invM;
    float rc = rsqrtf(dstat[512+c]*invM - mc*mc + 1e-5f);
    float mo = dstat[1024+c]*invM;
    float ro = rsqrtf(dstat[1536+c]*invM - mo*mo + 1e-5f);
    gC[i] = rc*aC[i] + ScR*(1e-4f - mc*rc);
    gO[i] = ro*aO[i] + SoR*(1e-4f - mo*ro);
  }
  uint4 oc, oo;
  oc.x = pk2(gC[0],gC[1]); oc.y = pk2(gC[2],gC[3]); oc.z = pk2(gC[4],gC[5]); oc.w = pk2(gC[6],gC[7]);
  oo.x = pk2(gO[0],gO[1]); oo.y = pk2(gO[2],gO[3]); oo.z = pk2(gO[4],gO[5]); oo.w = pk2(gO[6],gO[7]);
  ((uint4*)outC)[(size_t)row*64 + l] = oc;
  ((uint4*)outO)[(size_t)row*64 + l] = oo;
}

// ---------------- bf16 MFMA GEMM: XCD-chunked 1D grid, 3-buffer ring (vmcnt(8)), LDS-staged C ----------------
__global__ __launch_bounds__(256) void gemm_bt(const unsigned short* __restrict__ A,
                                               const unsigned short* __restrict__ Bt,
                                               unsigned short* __restrict__ O,
                                               const float* __restrict__ bias,
                                               float* __restrict__ stats,
                                               int M, int K, int relu, int split,
                                               const unsigned short* A2,
                                               const unsigned short* Bt2,
                                               unsigned short* O2,
                                               const float* bias2){
  extern __shared__ unsigned short smem[];
  unsigned short* Cs = smem;
  const int tid = threadIdx.x;
  const int w = tid >> 6, l = tid & 63;

  int lin = blockIdx.x;
  int total = gridDim.x;
  int q = total >> 3, r = total & 7;
  int xcd = lin & 7, idx = lin >> 3;
  int swz = (xcd < r ? xcd*(q+1) : r*(q+1) + (xcd - r)*q) + idx;
  if (split && swz >= split){ A = A2; Bt = Bt2; O = O2; bias = bias2; swz -= split; }
  const int m0 = (swz >> 2)*128, n0 = (swz & 3)*128;

  const int wm = w >> 1, wn = w & 1;
  const int lr = l & 15, lh = l >> 4;

  f32x4 acc[4][4];
#pragma unroll
  for (int i=0;i<4;i++)
#pragma unroll
    for (int j=0;j<4;j++) acc[i][j] = 0.0f;

  const int q0 = w*2, q1 = w*2+1;
  const int sub = l >> 2;
  const int kc  = (l & 3)*8;
  int ma0 = m0 + q0*16 + sub; if (ma0 >= M) ma0 = M-1;
  int ma1 = m0 + q1*16 + sub; if (ma1 >= M) ma1 = M-1;
  const int nb0 = n0 + q0*16 + sub;
  const int nb1 = n0 + q1*16 + sub;
  const unsigned short* Ar0 = A + (size_t)ma0*K + kc;
  const unsigned short* Ar1 = A + (size_t)ma1*K + kc;
  const unsigned short* Br0 = Bt + (size_t)nb0*K + kc;
  const unsigned short* Br1 = Bt + (size_t)nb1*K + kc;

  const int NT = K >> 5;
  gload16(&smem[0*8192 + q0*512], Ar0);
  gload16(&smem[0*8192 + q1*512], Ar1);
  gload16(&smem[0*8192 + 4096 + q0*512], Br0);
  gload16(&smem[0*8192 + 4096 + q1*512], Br1);
  if (NT > 1){
    gload16(&smem[1*8192 + q0*512], Ar0 + 32);
    gload16(&smem[1*8192 + q1*512], Ar1 + 32);
    gload16(&smem[1*8192 + 4096 + q0*512], Br0 + 32);
    gload16(&smem[1*8192 + 4096 + q1*512], Br1 + 32);
  }
  int cur = 0;
  for (int t=0; t<NT; ++t){
    if (t+2 < NT){
      int k1 = (t+2) << 5;
      int nb = cur + 2; if (nb >= 3) nb -= 3;
      gload16(&smem[nb*8192 + q0*512], Ar0 + k1);
      gload16(&smem[nb*8192 + q1*512], Ar1 + k1);
      gload16(&smem[nb*8192 + 4096 + q0*512], Br0 + k1);
      gload16(&smem[nb*8192 + 4096 + q1*512], Br1 + k1);
      asm volatile("s_waitcnt vmcnt(8)" ::: "memory");
    } else if (t+1 < NT){
      asm volatile("s_waitcnt vmcnt(4)" ::: "memory");
    } else {
      asm volatile("s_waitcnt vmcnt(0)" ::: "memory");
    }
    __builtin_amdgcn_s_barrier();
    asm volatile("" ::: "memory");
    short8 af[4], bfr[4];
#pragma unroll
    for (int fm=0; fm<4; ++fm) af[fm]  = *(const short8*)&smem[cur*8192 + (wm*64 + fm*16 + lr)*32 + lh*8];
#pragma unroll
    for (int fn=0; fn<4; ++fn) bfr[fn] = *(const short8*)&smem[cur*8192 + 4096 + (wn*64 + fn*16 + lr)*32 + lh*8];
#pragma unroll
    for (int fm=0; fm<4; ++fm)
#pragma unroll
      for (int fn=0; fn<4; ++fn)
        acc[fm][fn] = __builtin_amdgcn_mfma_f32_16x16x32_bf16(af[fm], bfr[fn], acc[fm][fn], 0, 0, 0);
    asm volatile("" ::: "memory");
    __builtin_amdgcn_s_barrier();
    asm volatile("" ::: "memory");
    cur += 1; if (cur >= 3) cur = 0;
  }
  int dep = __float_as_int(acc[0][0][0]);
  int z_;
  asm volatile("v_and_b32 %0, 0, %1" : "=v"(z_) : "v"(dep));
  const float* biasp = bias + z_;

  float bv[4], cs[4]={0,0,0,0}, cq[4]={0,0,0,0};
  int col[4];
#pragma unroll
  for (int fn=0; fn<4; ++fn){ col[fn] = n0 + wn*64 + fn*16 + lr; bv[fn] = biasp[col[fn]]; }
#pragma unroll
  for (int fm=0; fm<4; ++fm){
#pragma unroll
    for (int j=0; j<4; ++j){
      int trow = wm*64 + fm*16 + lh*4 + j;
      bool valid = (m0 + trow) < M;
#pragma unroll
      for (int fn=0; fn<4; ++fn){
        float v = acc[fm][fn][j] + bv[fn];
        if (relu) v = fmaxf(v, 0.f);
        Cs[trow*136 + wn*64 + fn*16 + lr] = f2bf(v);
        if (valid){ cs[fn] += v; cq[fn] += v*v; }
      }
    }
  }
  __syncthreads();
#pragma unroll
  for (int i=0;i<8;i++){
    int trow = i*16 + (tid>>4);
    int colb = (tid&15)*8;
    uint4 vv = *(const uint4*)&Cs[trow*136 + colb];
    int grow = m0 + trow;
    if (grow < M) *(uint4*)&O[(size_t)grow*HID + n0 + colb] = vv;
  }
  if (stats){
#pragma unroll
    for (int m=16; m<64; m<<=1){
#pragma unroll
      for (int fn=0; fn<4; ++fn){ cs[fn] += __shfl_xor(cs[fn], m); cq[fn] += __shfl_xor(cq[fn], m); }
    }
    if (lh == 0){
#pragma unroll
      for (int fn=0; fn<4; ++fn){
        atomicAdd(&stats[col[fn]], cs[fn]);
        atomicAdd(&stats[512+col[fn]], cq[fn]);
      }
    }
  }
}

// batched fc1 gemm: M=1536 (3 branches x 512 rows), 3-buffer ring
struct FC1P { const unsigned short* Bt[3]; const float* bias[3]; };
__global__ __launch_bounds__(256) void gemm_fc1(const unsigned short* __restrict__ A, FC1P p,
                                                unsigned short* __restrict__ O,
                                                float* __restrict__ statsB){
  extern __shared__ unsigned short smem[];
  const int tid = threadIdx.x;
  const int w = tid >> 6, l = tid & 63;
  const int m0 = blockIdx.x*128, n0 = blockIdx.y*128;
  const int branch = blockIdx.x >> 2;
  const unsigned short* Bt = p.Bt[branch];
  const float* bias = p.bias[branch];
  float* stats = statsB + branch*1024;
  const int K = HID;
  const int wm = w >> 1, wn = w & 1;
  const int lr = l & 15, lh = l >> 4;

  f32x4 acc[4][4];
#pragma unroll
  for (int i=0;i<4;i++)
#pragma unroll
    for (int j=0;j<4;j++) acc[i][j] = 0.0f;

  const int q0 = w*2, q1 = w*2+1;
  const int sub = l >> 2;
  const int kc  = (l & 3)*8;
  const int ma0 = m0 + q0*16 + sub;
  const int ma1 = m0 + q1*16 + sub;
  const int nb0 = n0 + q0*16 + sub;
  const int nb1 = n0 + q1*16 + sub;
  const unsigned short* Ar0 = A + (size_t)ma0*K + kc;
  const unsigned short* Ar1 = A + (size_t)ma1*K + kc;
  const unsigned short* Br0 = Bt + (size_t)nb0*K + kc;
  const unsigned short* Br1 = Bt + (size_t)nb1*K + kc;

  const int NT = K >> 5;
  gload16(&smem[0*8192 + q0*512], Ar0);
  gload16(&smem[0*8192 + q1*512], Ar1);
  gload16(&smem[0*8192 + 4096 + q0*512], Br0);
  gload16(&smem[0*8192 + 4096 + q1*512], Br1);
  gload16(&smem[1*8192 + q0*512], Ar0 + 32);
  gload16(&smem[1*8192 + q1*512], Ar1 + 32);
  gload16(&smem[1*8192 + 4096 + q0*512], Br0 + 32);
  gload16(&smem[1*8192 + 4096 + q1*512], Br1 + 32);
  int cur = 0;
  for (int t=0; t<NT; ++t){
    if (t+2 < NT){
      int k1 = (t+2) << 5;
      int nb = cur + 2; if (nb >= 3) nb -= 3;
      gload16(&smem[nb*8192 + q0*512], Ar0 + k1);
      gload16(&smem[nb*8192 + q1*512], Ar1 + k1);
      gload16(&smem[nb*8192 + 4096 + q0*512], Br0 + k1);
      gload16(&smem[nb*8192 + 4096 + q1*512], Br1 + k1);
      asm volatile("s_waitcnt vmcnt(8)" ::: "memory");
    } else if (t+1 < NT){
      asm volatile("s_waitcnt vmcnt(4)" ::: "memory");
    } else {
      asm volatile("s_waitcnt vmcnt(0)" ::: "memory");
    }
    __builtin_amdgcn_s_barrier();
    asm volatile("" ::: "memory");
    short8 af[4], bfr[4];
#pragma unroll
    for (int fm=0; fm<4; ++fm) af[fm]  = *(const short8*)&smem[cur*8192 + (wm*64 + fm*16 + lr)*32 + lh*8];
#pragma unroll
    for (int fn=0; fn<4; ++fn) bfr[fn] = *(const short8*)&smem[cur*8192 + 4096 + (wn*64 + fn*16 + lr)*32 + lh*8];
#pragma unroll
    for (int fm=0; fm<4; ++fm)
#pragma unroll
      for (int fn=0; fn<4; ++fn)
        acc[fm][fn] = __builtin_amdgcn_mfma_f32_16x16x32_bf16(af[fm], bfr[fn], acc[fm][fn], 0, 0, 0);
    asm volatile("" ::: "memory");
    __builtin_amdgcn_s_barrier();
    asm volatile("" ::: "memory");
    cur += 1; if (cur >= 3) cur = 0;
  }
  int dep = __float_as_int(acc[0][0][0]);
  int z_;
  asm volatile("v_and_b32 %0, 0, %1" : "=v"(z_) : "v"(dep));
  const float* biasp = bias + z_;

  float bv[4], cs[4]={0,0,0,0}, cq[4]={0,0,0,0};
  int col[4];
#pragma unroll
  for (int fn=0; fn<4; ++fn){ col[fn] = n0 + wn*64 + fn*16 + lr; bv[fn] = biasp[col[fn]]; }
#pragma unroll
  for (int fm=0; fm<4; ++fm){
#pragma unroll
    for (int j=0; j<4; ++j){
      int row = m0 + wm*64 + fm*16 + lh*4 + j;
      bool real = (row & 511) < NG;
#pragma unroll
      for (int fn=0; fn<4; ++fn){
        float v = fmaxf(acc[fm][fn][j] + bv[fn], 0.f);
        O[(size_t)row*HID + col[fn]] = f2bf(v);
        if (real){ cs[fn] += v; cq[fn] += v*v; }
      }
    }
  }
#pragma unroll
  for (int m=16; m<64; m<<=1){
#pragma unroll
    for (int fn=0; fn<4; ++fn){ cs[fn] += __shfl_xor(cs[fn], m); cq[fn] += __shfl_xor(cq[fn], m); }
  }
  if (lh == 0){
#pragma unroll
    for (int fn=0; fn<4; ++fn){
      atomicAdd(&stats[col[fn]], cs[fn]);
      atomicAdd(&stats[512+col[fn]], cq[fn]);
    }
  }
}

// ---------------- pooling, both branches; emits branch-0/1 readout BN1 stats ----------------
__global__ void pool2(const unsigned short* __restrict__ XC, const unsigned short* __restrict__ XO,
                      const int* __restrict__ batch, float* __restrict__ gc, float* __restrict__ go,
                      float* __restrict__ rst){
  int g = blockIdx.x;
  int t = threadIdx.x;
  const unsigned short* X = blockIdx.y ? XO : XC;
  float* out = blockIdx.y ? go : gc;
  float* st = rst + blockIdx.y*1024;
  int lo = 0, hi = NN;
  while (lo < hi){ int mid = (lo+hi) >> 1; if (batch[mid] < g) lo = mid+1; else hi = mid; }
  int s = lo;
  lo = 0; hi = NN;
  while (lo < hi){ int mid = (lo+hi) >> 1; if (batch[mid] < g+1) lo = mid+1; else hi = mid; }
  int e = lo;
  float a0 = 0.f, a1 = 0.f;
  for (int i=s; i<e; ++i){
    unsigned int v = *(const unsigned int*)&X[(size_t)i*HID + t*2];
    a0 += bf2f(v & 0xffffu); a1 += bf2f(v >> 16);
  }
  int c0 = t*2, c1 = t*2+1;
  out[(size_t)g*HID + c0] = a0;
  out[(size_t)g*HID + c1] = a1;
  atomicAdd(&st[c0], a0); atomicAdd(&st[512+c0], a0*a0);
  atomicAdd(&st[c1], a1); atomicAdd(&st[512+c1], a1*a1);
}

// ---------------- readout BN1 stats, branch 2 only (gc[perm]+go), atomic out ----------------
__global__ __launch_bounds__(256) void bnstats_co(const float* __restrict__ gc, const float* __restrict__ go,
                                                  const int* __restrict__ perm, float* __restrict__ st2){
  __shared__ float lds[256*9];
  int t = threadIdx.x;
  int cid = t & 127, rid = t >> 7;
  float s[4]={0,0,0,0}, q[4]={0,0,0,0};
  const int rowsPer = (NG + NB3 - 1)/NB3;
  int r0 = blockIdx.x*rowsPer, r1 = r0 + rowsPer; if (r1 > NG) r1 = NG;
  for (int r = r0 + rid; r < r1; r += 2){
    int ps = perm[r];
    float4 a = *(const float4*)&gc[(size_t)ps*HID + cid*4];
    float4 b = *(const float4*)&go[(size_t)r*HID + cid*4];
    float e[4] = {a.x+b.x, a.y+b.y, a.z+b.z, a.w+b.w};
#pragma unroll
    for (int i=0;i<4;i++){ s[i]+=e[i]; q[i]+=e[i]*e[i]; }
  }
  int base = (rid*128 + cid)*9;
#pragma unroll
  for (int i=0;i<4;i++){ lds[base+i]=s[i]; lds[base+4+i]=q[i]; }
  __syncthreads();
  for (int o = t; o < 1024; o += 256){
    int issq = o >> 9, col = o & 511;
    int ci = col >> 2, i = col & 3;
    float acc = lds[(0*128 + ci)*9 + issq*4 + i] + lds[(1*128 + ci)*9 + issq*4 + i];
    atomicAdd(&st2[issq*512 + col], acc);
  }
}

// ---------------- cast 3 branches to bf16 with inline BN from raw sums ----------------
__global__ void bncast3(const float* __restrict__ gc, const float* __restrict__ go,
                        const int* __restrict__ perm, const float* __restrict__ rst,
                        float invM, unsigned short* __restrict__ out){
  int idx = blockIdx.x*blockDim.x + threadIdx.x;
  if (idx >= 1536*128) return;
  int r = idx >> 7;
  int cg = idx & 127;
  int br = r >> 9, lr = r & 511;
  ushort4v o;
  if (lr >= NG){ o[0]=0; o[1]=0; o[2]=0; o[3]=0; }
  else {
    float4 v;
    if (br == 0)      v = *(const float4*)&gc[(size_t)lr*HID + cg*4];
    else if (br == 1) v = *(const float4*)&go[(size_t)lr*HID + cg*4];
    else {
      int ps = perm[lr];
      float4 a = *(const float4*)&gc[(size_t)ps*HID + cg*4];
      float4 b = *(const float4*)&go[(size_t)lr*HID + cg*4];
      v = make_float4(a.x+b.x, a.y+b.y, a.z+b.z, a.w+b.w);
    }
    const float* ms = rst + br*1024;
    int c = cg*4;
    float e[4] = {v.x, v.y, v.z, v.w};
#pragma unroll
    for (int i=0;i<4;i++){
      float m = ms[c+i]*invM;
      float rs = rsqrtf(ms[512+c+i]*invM - m*m + 1e-5f);
      o[i] = f2bf((e[i] - m)*rs + 1e-4f);
    }
  }
  *(ushort4v*)&out[(size_t)r*HID + cg*4] = o;
}

// ---------------- final: batched BN2 -> fc2 -> log_softmax ----------------
struct ROP { const float* W2[3]; const float* b2[3]; };
__global__ void readout_final3(const unsigned short* __restrict__ T, const float* __restrict__ statsB,
                               float invM, ROP p, float* __restrict__ out){
  int g = blockIdx.x;
  int br = blockIdx.y;
  int l = threadIdx.x;
  const float* stats = statsB + br*1024;
  const float* W2 = p.W2[br];
  const float* b2 = p.b2[br];
  float acc[NCLS];
#pragma unroll
  for (int c=0; c<NCLS; ++c) acc[c] = 0.f;
  uint4 u = ((const uint4*)(T + (size_t)(br*512 + g)*HID))[l];
  float xv[8] = {bf2f(u.x&0xffffu), bf2f(u.x>>16), bf2f(u.y&0xffffu), bf2f(u.y>>16),
                 bf2f(u.z&0xffffu), bf2f(u.z>>16), bf2f(u.w&0xffffu), bf2f(u.w>>16)};
#pragma unroll
  for (int j=0; j<8; ++j){
    int k = l*8 + j;
    float m = stats[k]*invM;
    float rs = rsqrtf(stats[512+k]*invM - m*m + 1e-5f);
    float v = (xv[j] - m)*rs + 1e-4f;
#pragma unroll
    for (int c=0; c<NCLS; ++c) acc[c] += v * W2[k*NCLS + c];
  }
  for (int m=1; m<64; m<<=1){
#pragma unroll
    for (int c=0; c<NCLS; ++c) acc[c] += __shfl_xor(acc[c], m);
  }
  if (l == 0){
    float z[NCLS];
    float mx = -1e30f;
#pragma unroll
    for (int c=0; c<NCLS; ++c){ z[c] = acc[c] + b2[c]; mx = fmaxf(mx, z[c]); }
    float s = 0.f;
#pragma unroll
    for (int c=0; c<NCLS; ++c) s += expf(z[c]-mx);
    float lse = mx + logf(s);
#pragma unroll
    for (int c=0; c<NCLS; ++c) out[(size_t)(br*NG + g)*NCLS + c] = z[c] - lse;
  }
}

extern "C" void kernel_launch(void* const* d_in, const int* in_sizes, int n_in,
                              void* d_out, int out_size, void* d_ws, size_t ws_size,
                              hipStream_t stream){
  (void)in_sizes; (void)n_in; (void)out_size;
  const float* x      = (const float*)d_in[0];
  const int*   ei     = (const int*)d_in[1];
  const int*   batch  = (const int*)d_in[2];
  const int*   perm   = (const int*)d_in[3];
  const float* convfW = (const float*)d_in[4];
  const float* convfB = (const float*)d_in[5];
  const float* convsW = (const float*)d_in[6];
  const float* convsB = (const float*)d_in[7];
  const float* eattW  = (const float*)d_in[8];
  const float* eattB  = (const float*)d_in[9];
  const float* nattW  = (const float*)d_in[10];
  const float* nattB  = (const float*)d_in[11];
  const float* ctxW   = (const float*)d_in[12];
  const float* ctxB   = (const float*)d_in[13];
  const float* objW   = (const float*)d_in[14];
  const float* objB   = (const float*)d_in[15];
  const float* fc1W[3] = {(const float*)d_in[16], (const float*)d_in[20], (const float*)d_in[24]};
  const float* fc1B[3] = {(const float*)d_in[17], (const float*)d_in[21], (const float*)d_in[25]};
  const float* fc2W[3] = {(const float*)d_in[18], (const float*)d_in[22], (const float*)d_in[26]};
  const float* fc2B[3] = {(const float*)d_in[19], (const float*)d_in[23], (const float*)d_in[27]};
  float* out = (float*)d_out;

  char* p = (char*)d_ws;
  auto alloc = [&](size_t bytes)->char*{ char* r = p; p += (bytes + 255) & ~((size_t)255); return r; };
  const int T = NE + NN;
  unsigned short* Xbf = (unsigned short*)alloc((size_t)NN*HID*2);
  unsigned short* Gbf = (unsigned short*)alloc((size_t)NN*HID*2);
  unsigned short* GbfO= (unsigned short*)alloc((size_t)NN*HID*2);
  unsigned short* XbfO= (unsigned short*)alloc((size_t)NN*HID*2);
  unsigned short* Abf = (unsigned short*)alloc((size_t)NN*FIN*2);
  unsigned short* WtF = (unsigned short*)alloc((size_t)HID*FIN*2);
  unsigned short* WtL = (unsigned short*)alloc((size_t)3*HID*HID*2);
  unsigned short* WtC = (unsigned short*)alloc((size_t)HID*HID*2);
  unsigned short* WtO = (unsigned short*)alloc((size_t)HID*HID*2);
  unsigned short* WtR = (unsigned short*)alloc((size_t)3*HID*HID*2);
  int* cnt   = (int*)alloc((size_t)NN*4);
  int* fillc = (int*)alloc((size_t)NN*4);
  int* rowp  = (int*)alloc((size_t)(NN+1)*4);
  int* bsum  = (int*)alloc(32*4);
  int* ccol  = (int*)alloc((size_t)T*4);
  int* crow  = (int*)alloc((size_t)T*4);
  int* ceid  = (int*)alloc((size_t)T*4);
  int2* cw1  = (int2*)alloc((size_t)T*8);
  float* wcv = (float*)alloc((size_t)T*4);
  float* wov = (float*)alloc((size_t)T*4);
  float* dis1 = (float*)alloc((size_t)NN*4);
  float* degc = (float*)alloc((size_t)NN*4);
  float* dego = (float*)alloc((size_t)NN*4);
  float* Sc   = (float*)alloc((size_t)NN*4);
  float* So   = (float*)alloc((size_t)NN*4);
  float* statsA = (float*)alloc((size_t)STATSA_N*4);
  float* na   = (float*)alloc((size_t)NN*2*4);
  float* eab  = (float*)alloc((size_t)NN*4*4);
  float* att  = (float*)alloc((size_t)NE*2*4);
  float* gc   = (float*)alloc((size_t)NG*HID*4);
  float* go   = (float*)alloc((size_t)NG*HID*4);
  if ((size_t)(p - (char*)d_ws) > ws_size){
    sentinel_k<<<1,1,0,stream>>>(out);
    return;
  }
  unsigned short* Abf3 = Abf;
  unsigned short* Gbf3 = GbfO;
  float* stats6 = statsA;              // layer stats + fc1 stats (6*1024)
  float* cstat  = statsA + 6144;       // conv input stats (256)
  float* dstat  = statsA + 6400;       // dual stats (2048)
  float* rst    = statsA + 8448;       // readout BN1 stats (3*1024)
  const float invNN = 1.0f/(float)NN;
  const float invNG = 1.0f/(float)NG;
  const int GEMM_LDS = 3*8192*2;       // 49152 B: 3-buffer ring; Cs (34816B) aliases

  // setup
  W2BT wp;
  wp.src[0]=convfW; wp.dst[0]=WtF;
  for (int i=0;i<3;i++){ wp.src[1+i]=convsW+(size_t)i*HID*HID; wp.dst[1+i]=WtL+(size_t)i*HID*HID; }
  wp.src[4]=ctxW; wp.dst[4]=WtC;
  wp.src[5]=objW; wp.dst[5]=WtO;
  for (int i=0;i<3;i++){ wp.src[6+i]=fc1W[i]; wp.dst[6+i]=WtR+(size_t)i*HID*HID; }
  setup_all<<<(FIN*HID + 8*HID*HID + 255)/256, 256, 0, stream>>>(wp, cnt, fillc, degc, dego, Sc, So, statsA);

  // D1: csr_count + conv bnstats (atomic)
  d1_count_stats<<<BNG + (NE+1023)/1024, 1024, 0, stream>>>(ei, cnt, x, cstat);
  // D2: rowptr scan
  d2_scan<<<(NN+1023)/1024, 1024, 0, stream>>>(cnt, rowp, dis1, bsum);
  // D3: scan stage 2 + conv bncast (inline BN)
  d3_scan_cast<<<20 + (NN*FIN/4 + 1023)/1024, 1024, 0, stream>>>(rowp, bsum, x, cstat, invNN, Abf);
  // CSR fill
  csr_fill<<<(T+255)/256,256,0,stream>>>(ei, rowp, cnt, fillc, dis1, ccol, crow, ceid, cw1);

  const int NBLK = ((NN+127)/128)*4;   // 628

  // conv_feat gemm
  gemm_bt<<<NBLK,256,GEMM_LDS,stream>>>(Abf, WtF, Xbf, convfB, stats6, NN, FIN, 1,
                                        0, nullptr, nullptr, nullptr, nullptr);

  // 3 GCN layers
  for (int i=0;i<3;i++){
    aggregate_bn<<<NN/4,256,0,stream>>>(Xbf, rowp, cw1, stats6 + i*1024, invNN, Gbf);
    gemm_bt<<<NBLK,256,GEMM_LDS,stream>>>(Gbf, WtL+(size_t)i*HID*HID, Xbf,
                                          convsB+(size_t)i*HID,
                                          (i<2) ? (stats6 + (i+1)*1024) : nullptr,
                                          NN, HID, 1, 0, nullptr, nullptr, nullptr, nullptr);
  }

  // attention
  att_node<<<NN/4,256,0,stream>>>(Xbf, nattW, nattB, eattW, na, eab);
  att_edge<<<(NE+255)/256,256,0,stream>>>(ei, eab, eattB, att, degc, dego);
  wco_kernel<<<(T+255)/256,256,0,stream>>>(crow, ccol, ceid, att, degc, dego, na, wcv, wov, Sc, So);

  // ctx + obj
  bnstats_dual<<<BNG,1024,0,stream>>>(Xbf, na, dstat);
  aggregate_dual<<<NN/4,256,0,stream>>>(Xbf, rowp, ccol, wcv, wov, Sc, So, dstat, invNN, Gbf, GbfO);
  gemm_bt<<<2*NBLK,256,GEMM_LDS,stream>>>(Gbf, WtC, Xbf, ctxB, nullptr, NN, HID, 1,
                                          NBLK, GbfO, WtO, XbfO, objB);
  pool2<<<dim3(NG,2),256,0,stream>>>(Xbf, XbfO, batch, gc, go, rst);

  // readouts, batched across the 3 branches
  bnstats_co<<<NB3,256,0,stream>>>(gc, go, perm, rst + 2*1024);
  bncast3<<<(1536*128+255)/256,256,0,stream>>>(gc, go, perm, rst, invNG, Abf3);
  FC1P fp;
  for (int i=0;i<3;i++){ fp.Bt[i] = WtR+(size_t)i*HID*HID; fp.bias[i] = fc1B[i]; }
  gemm_fc1<<<dim3(12,4),256,GEMM_LDS,stream>>>(Abf3, fp, Gbf3, stats6 + 3*1024);
  ROP rp;
  for (int i=0;i<3;i++){ rp.W2[i] = fc2W[i]; rp.b2[i] = fc2B[i]; }
  readout_final3<<<dim3(NG,3),64,0,stream>>>(Gbf3, stats6 + 3*1024, invNG, rp, out);
}

// Round 11
// 428.265 us; speedup vs baseline: 1.0959x; 1.0043x over previous
//
#include <hip/hip_runtime.h>
#include <stdint.h>

#define NN 20000
#define NE 160000
#define NG 500
#define FIN 128
#define HID 512
#define NCLS 10
#define BNG 256
#define NB3 32

typedef __attribute__((ext_vector_type(8))) short short8;
typedef __attribute__((ext_vector_type(4))) float f32x4;
typedef __attribute__((ext_vector_type(4))) unsigned short ushort4v;

__device__ __forceinline__ float bf2f(unsigned int u){
  union{unsigned int i; float f;} x; x.i = u<<16; return x.f;
}
__device__ __forceinline__ unsigned short f2bf(float f){
  union{float f; unsigned int i;} x; x.f=f;
  unsigned int r = x.i + 0x7fffu + ((x.i>>16)&1u);
  return (unsigned short)(r>>16);
}
__device__ __forceinline__ unsigned int pk2(float a, float b){
  return (unsigned int)f2bf(a) | ((unsigned int)f2bf(b) << 16);
}

__device__ __forceinline__ void gload16(unsigned short* lds, const unsigned short* g){
  __builtin_amdgcn_global_load_lds((const __attribute__((address_space(1))) unsigned int*)g,
                                   (__attribute__((address_space(3))) unsigned int*)lds,
                                   16, 0, 0);
}

__device__ __forceinline__ void fma8(float* acc, uint4 v, float w){
  acc[0] += w*bf2f(v.x & 0xffffu); acc[1] += w*bf2f(v.x >> 16);
  acc[2] += w*bf2f(v.y & 0xffffu); acc[3] += w*bf2f(v.y >> 16);
  acc[4] += w*bf2f(v.z & 0xffffu); acc[5] += w*bf2f(v.z >> 16);
  acc[6] += w*bf2f(v.w & 0xffffu); acc[7] += w*bf2f(v.w >> 16);
}
__device__ __forceinline__ void add8(float* acc, uint4 v){
  acc[0] += bf2f(v.x & 0xffffu); acc[1] += bf2f(v.x >> 16);
  acc[2] += bf2f(v.y & 0xffffu); acc[3] += bf2f(v.y >> 16);
  acc[4] += bf2f(v.z & 0xffffu); acc[5] += bf2f(v.z >> 16);
  acc[6] += bf2f(v.w & 0xffffu); acc[7] += bf2f(v.w >> 16);
}

__global__ void sentinel_k(float* out){ out[0] = 12345.0f; }

// statsA layout (floats, all zeroed in setup):
//   [0..1023]      L0-input stats   [1024..2047] L1   [2048..3071] L2
//   [3072..6143]   fc1-out stats x3
//   [6144..6399]   conv-input stats (F=128)
//   [6400..8447]   dual stats
//   [8448..11519]  readout BN1 stats x3
#define STATSA_N 12288

// ---------------- setup ----------------
struct W2BT { const float* src[9]; unsigned short* dst[9]; };
__global__ void setup_all(W2BT p, int* __restrict__ cnt, int* __restrict__ fillc,
                          float* __restrict__ degc, float* __restrict__ dego,
                          float* __restrict__ Sc, float* __restrict__ So,
                          float* __restrict__ statsA){
  int idx = blockIdx.x*blockDim.x + threadIdx.x;
  if (idx < FIN*HID + 8*HID*HID){
    int seg, off, K;
    if (idx < FIN*HID){ seg = 0; off = idx; K = FIN; }
    else {
      int r = idx - FIN*HID;
      seg = 1 + (r >> 18); off = r & (HID*HID-1); K = HID;
    }
    int k = off >> 9, n = off & 511;
    p.dst[seg][(size_t)n*K + k] = f2bf(p.src[seg][off]);
  }
  if (idx < NN){ cnt[idx]=0; fillc[idx]=0; degc[idx]=1.0f; dego[idx]=1.0f; Sc[idx]=0.f; So[idx]=0.f; }
  if (idx < STATSA_N) statsA[idx] = 0.f;
}

// ---------------- D1: csr_count + conv BN stats (atomic out) ----------------
__global__ __launch_bounds__(1024) void d1_count_stats(const int* __restrict__ ei, int* __restrict__ cnt,
                                                       const float* __restrict__ X, float* __restrict__ cstat){
  __shared__ float lds[1024*9];
  const int t = threadIdx.x;
  if (blockIdx.x >= BNG){
    int e = (blockIdx.x - BNG)*1024 + t;
    if (e < NE) atomicAdd(&cnt[ei[e]], 1);
    return;
  }
  const int cg = FIN >> 2;
  const int cid = t & (cg-1);
  const int rid = t / cg;
  const int rpb = 1024 / cg;
  float s0=0,s1=0,s2=0,s3=0,q0=0,q1=0,q2=0,q3=0;
  const int rowsPer = (NN + BNG - 1)/BNG;
  int r0 = blockIdx.x*rowsPer, r1 = r0 + rowsPer; if (r1 > NN) r1 = NN;
  for (int r = r0 + rid; r < r1; r += rpb){
    float4 v = *(const float4*)&X[(size_t)r*FIN + cid*4];
    s0+=v.x; q0+=v.x*v.x; s1+=v.y; q1+=v.y*v.y; s2+=v.z; q2+=v.z*v.z; s3+=v.w; q3+=v.w*v.w;
  }
  int base = (rid*cg + cid)*9;
  lds[base+0]=s0; lds[base+1]=s1; lds[base+2]=s2; lds[base+3]=s3;
  lds[base+4]=q0; lds[base+5]=q1; lds[base+6]=q2; lds[base+7]=q3;
  __syncthreads();
  if (t < cg*8){
    int ci = t >> 3, i = t & 7;
    float acc = 0.f;
    for (int g=0; g<rpb; ++g) acc += lds[(g*cg + ci)*9 + i];
    int col = ci*4 + (i & 3);
    atomicAdd(&cstat[(i < 4) ? col : FIN + col], acc);
  }
}

// ---------------- D2: rowptr scan stage 1 ----------------
__global__ __launch_bounds__(1024) void d2_scan(const int* __restrict__ cnt, int* __restrict__ rowp,
                                                float* __restrict__ dis1, int* __restrict__ bsum){
  __shared__ int buf[1024];
  int t = threadIdx.x;
  int i = blockIdx.x*1024 + t;
  int v = 0;
  if (i < NN){ v = cnt[i] + 1; dis1[i] = rsqrtf((float)v); }
  buf[t] = v;
  __syncthreads();
  for (int off=1; off<1024; off<<=1){
    int xv = (t >= off) ? buf[t-off] : 0;
    __syncthreads();
    buf[t] += xv;
    __syncthreads();
  }
  if (i < NN) rowp[i+1] = buf[t];
  if (t == 1023) bsum[blockIdx.x] = buf[1023];
}

// ---------------- D3: scan stage 2 + conv bncast (inline BN) ----------------
__global__ __launch_bounds__(1024) void d3_scan_cast(int* __restrict__ rowp, const int* __restrict__ bsum,
                                                     const float* __restrict__ X, const float* __restrict__ cstat,
                                                     float invM, unsigned short* __restrict__ out){
  __shared__ int base;
  int t = threadIdx.x;
  if (blockIdx.x < 20){
    int bx = blockIdx.x;
    if (t == 0){
      int a = 0;
      for (int b=0; b<bx; ++b) a += bsum[b];
      base = a;
    }
    __syncthreads();
    int i = bx*1024 + t;
    if (i < NN) rowp[i+1] += base;
    if (i == 0) rowp[0] = 0;
    return;
  }
  int idx = (blockIdx.x - 20)*1024 + t;
  int total4 = NN*FIN/4;
  if (idx >= total4) return;
  int b4 = idx*4;
  int c = b4 & (FIN-1);
  float4 v = *(const float4*)&X[b4];
  float e[4] = {v.x, v.y, v.z, v.w};
  ushort4v o;
#pragma unroll
  for (int i=0;i<4;i++){
    float m = cstat[c+i]*invM;
    float rs = rsqrtf(cstat[FIN+c+i]*invM - m*m + 1e-5f);
    o[i] = f2bf((e[i] - m)*rs + 1e-4f);
  }
  *(ushort4v*)&out[b4] = o;
}

// csr_fill + w1 fused
__global__ void csr_fill(const int* __restrict__ ei, const int* __restrict__ rowp,
                         const int* __restrict__ cnt, int* __restrict__ fillc,
                         const float* __restrict__ dis1,
                         int* __restrict__ ccol, int* __restrict__ crow, int* __restrict__ ceid,
                         int2* __restrict__ cw1){
  int id = blockIdx.x*blockDim.x + threadIdx.x;
  if (id < NE){
    int r = ei[id], c = ei[NE + id];
    int pos = atomicAdd(&fillc[r], 1);
    int idx = rowp[r] + pos;
    ccol[idx] = c; crow[idx] = r; ceid[idx] = id;
    cw1[idx] = make_int2(c, __float_as_int(dis1[r]*dis1[c]));
  } else if (id < NE + NN){
    int i = id - NE;
    int idx = rowp[i] + cnt[i];
    ccol[idx] = i; crow[idx] = i; ceid[idx] = -1;
    cw1[idx] = make_int2(i, __float_as_int(dis1[i]*dis1[i]));
  }
}

// ---------------- dual BN stats on bf16 X (atomic out) ----------------
__global__ __launch_bounds__(1024) void bnstats_dual(const unsigned short* __restrict__ X,
                                                     const float* __restrict__ na,
                                                     float* __restrict__ dstat){
  __shared__ float lds[1024*17];
  const int t = threadIdx.x;
  const int cid = t & 127;
  const int rid = t >> 7;
  float sC[4]={0,0,0,0}, qC[4]={0,0,0,0}, sO[4]={0,0,0,0}, qO[4]={0,0,0,0};
  const int rowsPer = (NN + BNG - 1)/BNG;
  int r0 = blockIdx.x*rowsPer, r1 = r0 + rowsPer; if (r1 > NN) r1 = NN;
  for (int r = r0 + rid; r < r1; r += 8){
    float a0 = na[2*r], a1 = na[2*r+1];
    uint2 u = *(const uint2*)&X[(size_t)r*HID + cid*4];
    float e[4] = {bf2f(u.x & 0xffffu), bf2f(u.x >> 16), bf2f(u.y & 0xffffu), bf2f(u.y >> 16)};
#pragma unroll
    for (int i=0;i<4;i++){
      float vc = e[i]*a0, vo = e[i]*a1;
      sC[i]+=vc; qC[i]+=vc*vc; sO[i]+=vo; qO[i]+=vo*vo;
    }
  }
  int base = (rid*128 + cid)*17;
#pragma unroll
  for (int i=0;i<4;i++){
    lds[base+i]=sC[i]; lds[base+4+i]=qC[i]; lds[base+8+i]=sO[i]; lds[base+12+i]=qO[i];
  }
  __syncthreads();
  for (int idx = t; idx < 2048; idx += 1024){
    int ci = idx >> 4, i = idx & 15;
    float acc = 0.f;
    for (int g=0; g<8; ++g) acc += lds[(g*128 + ci)*17 + i];
    int grp = i >> 2, col = ci*4 + (i & 3);
    atomicAdd(&dstat[grp*HID + col], acc);
  }
}

// ---------------- attention (bf16 X), weights staged in LDS ----------------
__global__ void att_node(const unsigned short* __restrict__ X, const float* __restrict__ nW,
                         const float* __restrict__ nb, const float* __restrict__ eW,
                         float* __restrict__ na, float* __restrict__ eab){
  __shared__ float wnl[1024], wet[1024], web[1024];
  int t = threadIdx.x;
  for (int i=t; i<1024; i+=256){ wnl[i]=nW[i]; wet[i]=eW[i]; web[i]=eW[1024+i]; }
  __syncthreads();
  int wv = blockIdx.x*4 + (t >> 6);
  int l = t & 63;
  uint4 u = ((const uint4*)(X + (size_t)wv*HID))[l];
  float xv[8] = {bf2f(u.x&0xffffu), bf2f(u.x>>16), bf2f(u.y&0xffffu), bf2f(u.y>>16),
                 bf2f(u.z&0xffffu), bf2f(u.z>>16), bf2f(u.w&0xffffu), bf2f(u.w>>16)};
  float s0=0,s1=0,s2=0,s3=0,s4=0,s5=0;
#pragma unroll
  for (int j=0; j<8; ++j){
    int k = l*8 + j;
    float x = xv[j];
    s0 += x * wnl[2*k];   s1 += x * wnl[2*k+1];
    s2 += x * wet[2*k];   s3 += x * wet[2*k+1];
    s4 += x * web[2*k];   s5 += x * web[2*k+1];
  }
  for (int m=1; m<64; m<<=1){
    s0 += __shfl_xor(s0,m); s1 += __shfl_xor(s1,m); s2 += __shfl_xor(s2,m);
    s3 += __shfl_xor(s3,m); s4 += __shfl_xor(s4,m); s5 += __shfl_xor(s5,m);
  }
  if (l == 0){
    float z0 = s0 + nb[0], z1 = s1 + nb[1];
    float mx = fmaxf(z0,z1);
    float e0 = expf(z0-mx), e1 = expf(z1-mx);
    float inv = 1.0f/(e0+e1);
    na[2*wv] = e0*inv; na[2*wv+1] = e1*inv;
    eab[4*wv] = s2; eab[4*wv+1] = s3; eab[4*wv+2] = s4; eab[4*wv+3] = s5;
  }
}

__global__ void att_edge(const int* __restrict__ ei, const float* __restrict__ eab,
                         const float* __restrict__ eb, float* __restrict__ att,
                         float* __restrict__ degc, float* __restrict__ dego){
  int e = blockIdx.x*blockDim.x + threadIdx.x;
  if (e >= NE) return;
  int r = ei[e], c = ei[NE+e];
  float z0 = eab[4*r]   + eab[4*c+2] + eb[0];
  float z1 = eab[4*r+1] + eab[4*c+3] + eb[1];
  float mx = fmaxf(z0,z1);
  float e0 = expf(z0-mx), e1 = expf(z1-mx);
  float inv = 1.0f/(e0+e1);
  float a0 = e0*inv, a1 = e1*inv;
  att[2*e] = a0; att[2*e+1] = a1;
  atomicAdd(&degc[r], a0);
  atomicAdd(&dego[r], a1);
}

__global__ void wco_kernel(const int* __restrict__ crow, const int* __restrict__ ccol,
                           const int* __restrict__ ceid, const float* __restrict__ att,
                           const float* __restrict__ degc, const float* __restrict__ dego,
                           const float* __restrict__ na,
                           float* __restrict__ wcv, float* __restrict__ wov,
                           float* __restrict__ Sc, float* __restrict__ So){
  int j = blockIdx.x*blockDim.x + threadIdx.x;
  if (j >= NE + NN) return;
  int r = crow[j], c = ccol[j], e = ceid[j];
  float a0 = (e < 0) ? 1.0f : att[2*e];
  float a1 = (e < 0) ? 1.0f : att[2*e+1];
  float wc = rsqrtf(degc[r]) * a0 * rsqrtf(degc[c]);
  float wo = rsqrtf(dego[r]) * a1 * rsqrtf(dego[c]);
  wcv[j] = wc * na[2*c];
  wov[j] = wo * na[2*c+1];
  atomicAdd(&Sc[r], wc);
  atomicAdd(&So[r], wo);
}

// ---------------- wave-per-row aggregation (int2 pairs), 8-deep ILP, BN affine epilogue ----------------
__global__ __launch_bounds__(256) void aggregate_bn(const unsigned short* __restrict__ A,
                                                    const int* __restrict__ rowp,
                                                    const int2* __restrict__ cw,
                                                    const float* __restrict__ stats,
                                                    float invM,
                                                    unsigned short* __restrict__ out){
  int row = blockIdx.x*4 + (threadIdx.x >> 6);
  int l = threadIdx.x & 63;
  const uint4* Av = (const uint4*)A;
  int s = rowp[row], e = rowp[row+1];
  float acc[8] = {0,0,0,0,0,0,0,0};
  float sw = 0.f;
  int j = s;
  for (; j+7 < e; j += 8){
    int2 p[8]; uint4 v[8];
#pragma unroll
    for (int k=0;k<8;k++) p[k] = cw[j+k];
#pragma unroll
    for (int k=0;k<8;k++) v[k] = Av[(size_t)p[k].x*64 + l];
#pragma unroll
    for (int k=0;k<8;k++){ float w = __int_as_float(p[k].y); fma8(acc, v[k], w); sw += w; }
  }
  for (; j+3 < e; j += 4){
    int2 p[4]; uint4 v[4];
#pragma unroll
    for (int k=0;k<4;k++) p[k] = cw[j+k];
#pragma unroll
    for (int k=0;k<4;k++) v[k] = Av[(size_t)p[k].x*64 + l];
#pragma unroll
    for (int k=0;k<4;k++){ float w = __int_as_float(p[k].y); fma8(acc, v[k], w); sw += w; }
  }
  for (; j < e; ++j){
    int2 p = cw[j];
    float w = __int_as_float(p.y);
    uint4 v = Av[(size_t)p.x*64 + l];
    fma8(acc, v, w);
    sw += w;
  }
  float g[8];
#pragma unroll
  for (int i=0;i<8;i++){
    int c = l*8 + i;
    float m = stats[c]*invM;
    float rs = rsqrtf(stats[512+c]*invM - m*m + 1e-5f);
    g[i] = rs*acc[i] + sw*(1e-4f - m*rs);
  }
  uint4 o;
  o.x = pk2(g[0],g[1]); o.y = pk2(g[2],g[3]); o.z = pk2(g[4],g[5]); o.w = pk2(g[6],g[7]);
  ((uint4*)out)[(size_t)row*64 + l] = o;
}

__global__ __launch_bounds__(256) void aggregate_dual(const unsigned short* __restrict__ A,
                                                      const int* __restrict__ rowp,
                                                      const int* __restrict__ ccol,
                                                      const float* __restrict__ wc,
                                                      const float* __restrict__ wo,
                                                      const float* __restrict__ Sc,
                                                      const float* __restrict__ So,
                                                      const float* __restrict__ dstat,
                                                      float invM,
                                                      unsigned short* __restrict__ outC,
                                                      unsigned short* __restrict__ outO){
  int row = blockIdx.x*4 + (threadIdx.x >> 6);
  int l = threadIdx.x & 63;
  const uint4* Av = (const uint4*)A;
  int s = rowp[row], e = rowp[row+1];
  float aC[8] = {0,0,0,0,0,0,0,0};
  float aO[8] = {0,0,0,0,0,0,0,0};
  int j = s;
  for (; j+7 < e; j += 8){
    int cc[8]; uint4 v[8];
#pragma unroll
    for (int k=0;k<8;k++) cc[k] = ccol[j+k];
#pragma unroll
    for (int k=0;k<8;k++) v[k] = Av[(size_t)cc[k]*64 + l];
#pragma unroll
    for (int k=0;k<8;k++){ fma8(aC, v[k], wc[j+k]); fma8(aO, v[k], wo[j+k]); }
  }
  for (; j+3 < e; j += 4){
    int cc[4]; uint4 v[4];
#pragma unroll
    for (int k=0;k<4;k++) cc[k] = ccol[j+k];
#pragma unroll
    for (int k=0;k<4;k++) v[k] = Av[(size_t)cc[k]*64 + l];
#pragma unroll
    for (int k=0;k<4;k++){ fma8(aC, v[k], wc[j+k]); fma8(aO, v[k], wo[j+k]); }
  }
  for (; j < e; ++j){
    uint4 v = Av[(size_t)ccol[j]*64 + l];
    fma8(aC, v, wc[j]); fma8(aO, v, wo[j]);
  }
  float ScR = Sc[row], SoR = So[row];
  float gC[8], gO[8];
#pragma unroll
  for (int i=0;i<8;i++){
    int c = l*8 + i;
    float mc = dstat[c]*invM;
    float rc = rsqrtf(dstat[512+c]*invM - mc*mc + 1e-5f);
    float mo = dstat[1024+c]*invM;
    float ro = rsqrtf(dstat[1536+c]*invM - mo*mo + 1e-5f);
    gC[i] = rc*aC[i] + ScR*(1e-4f - mc*rc);
    gO[i] = ro*aO[i] + SoR*(1e-4f - mo*ro);
  }
  uint4 oc, oo;
  oc.x = pk2(gC[0],gC[1]); oc.y = pk2(gC[2],gC[3]); oc.z = pk2(gC[4],gC[5]); oc.w = pk2(gC[6],gC[7]);
  oo.x = pk2(gO[0],gO[1]); oo.y = pk2(gO[2],gO[3]); oo.z = pk2(gO[4],gO[5]); oo.w = pk2(gO[6],gO[7]);
  ((uint4*)outC)[(size_t)row*64 + l] = oc;
  ((uint4*)outO)[(size_t)row*64 + l] = oo;
}

// ---------------- bf16 MFMA GEMM: XCD-chunked 1D grid, 3-buffer ring (vmcnt(8)), LDS-staged C ----------------
__global__ __launch_bounds__(256) void gemm_bt(const unsigned short* __restrict__ A,
                                               const unsigned short* __restrict__ Bt,
                                               unsigned short* __restrict__ O,
                                               const float* __restrict__ bias,
                                               float* __restrict__ stats,
                                               int M, int K, int relu, int split,
                                               const unsigned short* A2,
                                               const unsigned short* Bt2,
                                               unsigned short* O2,
                                               const float* bias2){
  extern __shared__ unsigned short smem[];
  unsigned short* Cs = smem;
  const int tid = threadIdx.x;
  const int w = tid >> 6, l = tid & 63;

  int lin = blockIdx.x;
  int total = gridDim.x;
  int q = total >> 3, r = total & 7;
  int xcd = lin & 7, idx = lin >> 3;
  int swz = (xcd < r ? xcd*(q+1) : r*(q+1) + (xcd - r)*q) + idx;
  if (split && swz >= split){ A = A2; Bt = Bt2; O = O2; bias = bias2; swz -= split; }
  const int m0 = (swz >> 2)*128, n0 = (swz & 3)*128;

  const int wm = w >> 1, wn = w & 1;
  const int lr = l & 15, lh = l >> 4;

  f32x4 acc[4][4];
#pragma unroll
  for (int i=0;i<4;i++)
#pragma unroll
    for (int j=0;j<4;j++) acc[i][j] = 0.0f;

  const int q0 = w*2, q1 = w*2+1;
  const int sub = l >> 2;
  const int kc  = (l & 3)*8;
  int ma0 = m0 + q0*16 + sub; if (ma0 >= M) ma0 = M-1;
  int ma1 = m0 + q1*16 + sub; if (ma1 >= M) ma1 = M-1;
  const int nb0 = n0 + q0*16 + sub;
  const int nb1 = n0 + q1*16 + sub;
  const unsigned short* Ar0 = A + (size_t)ma0*K + kc;
  const unsigned short* Ar1 = A + (size_t)ma1*K + kc;
  const unsigned short* Br0 = Bt + (size_t)nb0*K + kc;
  const unsigned short* Br1 = Bt + (size_t)nb1*K + kc;

  const int NT = K >> 5;
  gload16(&smem[0*8192 + q0*512], Ar0);
  gload16(&smem[0*8192 + q1*512], Ar1);
  gload16(&smem[0*8192 + 4096 + q0*512], Br0);
  gload16(&smem[0*8192 + 4096 + q1*512], Br1);
  if (NT > 1){
    gload16(&smem[1*8192 + q0*512], Ar0 + 32);
    gload16(&smem[1*8192 + q1*512], Ar1 + 32);
    gload16(&smem[1*8192 + 4096 + q0*512], Br0 + 32);
    gload16(&smem[1*8192 + 4096 + q1*512], Br1 + 32);
  }
  int cur = 0;
  for (int t=0; t<NT; ++t){
    if (t+2 < NT){
      int k1 = (t+2) << 5;
      int nb = cur + 2; if (nb >= 3) nb -= 3;
      gload16(&smem[nb*8192 + q0*512], Ar0 + k1);
      gload16(&smem[nb*8192 + q1*512], Ar1 + k1);
      gload16(&smem[nb*8192 + 4096 + q0*512], Br0 + k1);
      gload16(&smem[nb*8192 + 4096 + q1*512], Br1 + k1);
      asm volatile("s_waitcnt vmcnt(8)" ::: "memory");
    } else if (t+1 < NT){
      asm volatile("s_waitcnt vmcnt(4)" ::: "memory");
    } else {
      asm volatile("s_waitcnt vmcnt(0)" ::: "memory");
    }
    __builtin_amdgcn_s_barrier();
    asm volatile("" ::: "memory");
    short8 af[4], bfr[4];
#pragma unroll
    for (int fm=0; fm<4; ++fm) af[fm]  = *(const short8*)&smem[cur*8192 + (wm*64 + fm*16 + lr)*32 + lh*8];
#pragma unroll
    for (int fn=0; fn<4; ++fn) bfr[fn] = *(const short8*)&smem[cur*8192 + 4096 + (wn*64 + fn*16 + lr)*32 + lh*8];
#pragma unroll
    for (int fm=0; fm<4; ++fm)
#pragma unroll
      for (int fn=0; fn<4; ++fn)
        acc[fm][fn] = __builtin_amdgcn_mfma_f32_16x16x32_bf16(af[fm], bfr[fn], acc[fm][fn], 0, 0, 0);
    asm volatile("" ::: "memory");
    __builtin_amdgcn_s_barrier();
    asm volatile("" ::: "memory");
    cur += 1; if (cur >= 3) cur = 0;
  }
  int dep = __float_as_int(acc[0][0][0]);
  int z_;
  asm volatile("v_and_b32 %0, 0, %1" : "=v"(z_) : "v"(dep));
  const float* biasp = bias + z_;

  float bv[4], cs[4]={0,0,0,0}, cq[4]={0,0,0,0};
  int col[4];
#pragma unroll
  for (int fn=0; fn<4; ++fn){ col[fn] = n0 + wn*64 + fn*16 + lr; bv[fn] = biasp[col[fn]]; }
#pragma unroll
  for (int fm=0; fm<4; ++fm){
#pragma unroll
    for (int j=0; j<4; ++j){
      int trow = wm*64 + fm*16 + lh*4 + j;
      bool valid = (m0 + trow) < M;
#pragma unroll
      for (int fn=0; fn<4; ++fn){
        float v = acc[fm][fn][j] + bv[fn];
        if (relu) v = fmaxf(v, 0.f);
        Cs[trow*136 + wn*64 + fn*16 + lr] = f2bf(v);
        if (valid){ cs[fn] += v; cq[fn] += v*v; }
      }
    }
  }
  __syncthreads();
#pragma unroll
  for (int i=0;i<8;i++){
    int trow = i*16 + (tid>>4);
    int colb = (tid&15)*8;
    uint4 vv = *(const uint4*)&Cs[trow*136 + colb];
    int grow = m0 + trow;
    if (grow < M) *(uint4*)&O[(size_t)grow*HID + n0 + colb] = vv;
  }
  if (stats){
#pragma unroll
    for (int m=16; m<64; m<<=1){
#pragma unroll
      for (int fn=0; fn<4; ++fn){ cs[fn] += __shfl_xor(cs[fn], m); cq[fn] += __shfl_xor(cq[fn], m); }
    }
    if (lh == 0){
#pragma unroll
      for (int fn=0; fn<4; ++fn){
        atomicAdd(&stats[col[fn]], cs[fn]);
        atomicAdd(&stats[512+col[fn]], cq[fn]);
      }
    }
  }
}

// batched fc1 gemm: M=1536 (3 branches x 512 rows), 3-buffer ring
struct FC1P { const unsigned short* Bt[3]; const float* bias[3]; };
__global__ __launch_bounds__(256) void gemm_fc1(const unsigned short* __restrict__ A, FC1P p,
                                                unsigned short* __restrict__ O,
                                                float* __restrict__ statsB){
  extern __shared__ unsigned short smem[];
  const int tid = threadIdx.x;
  const int w = tid >> 6, l = tid & 63;
  const int m0 = blockIdx.x*128, n0 = blockIdx.y*128;
  const int branch = blockIdx.x >> 2;
  const unsigned short* Bt = p.Bt[branch];
  const float* bias = p.bias[branch];
  float* stats = statsB + branch*1024;
  const int K = HID;
  const int wm = w >> 1, wn = w & 1;
  const int lr = l & 15, lh = l >> 4;

  f32x4 acc[4][4];
#pragma unroll
  for (int i=0;i<4;i++)
#pragma unroll
    for (int j=0;j<4;j++) acc[i][j] = 0.0f;

  const int q0 = w*2, q1 = w*2+1;
  const int sub = l >> 2;
  const int kc  = (l & 3)*8;
  const int ma0 = m0 + q0*16 + sub;
  const int ma1 = m0 + q1*16 + sub;
  const int nb0 = n0 + q0*16 + sub;
  const int nb1 = n0 + q1*16 + sub;
  const unsigned short* Ar0 = A + (size_t)ma0*K + kc;
  const unsigned short* Ar1 = A + (size_t)ma1*K + kc;
  const unsigned short* Br0 = Bt + (size_t)nb0*K + kc;
  const unsigned short* Br1 = Bt + (size_t)nb1*K + kc;

  const int NT = K >> 5;
  gload16(&smem[0*8192 + q0*512], Ar0);
  gload16(&smem[0*8192 + q1*512], Ar1);
  gload16(&smem[0*8192 + 4096 + q0*512], Br0);
  gload16(&smem[0*8192 + 4096 + q1*512], Br1);
  gload16(&smem[1*8192 + q0*512], Ar0 + 32);
  gload16(&smem[1*8192 + q1*512], Ar1 + 32);
  gload16(&smem[1*8192 + 4096 + q0*512], Br0 + 32);
  gload16(&smem[1*8192 + 4096 + q1*512], Br1 + 32);
  int cur = 0;
  for (int t=0; t<NT; ++t){
    if (t+2 < NT){
      int k1 = (t+2) << 5;
      int nb = cur + 2; if (nb >= 3) nb -= 3;
      gload16(&smem[nb*8192 + q0*512], Ar0 + k1);
      gload16(&smem[nb*8192 + q1*512], Ar1 + k1);
      gload16(&smem[nb*8192 + 4096 + q0*512], Br0 + k1);
      gload16(&smem[nb*8192 + 4096 + q1*512], Br1 + k1);
      asm volatile("s_waitcnt vmcnt(8)" ::: "memory");
    } else if (t+1 < NT){
      asm volatile("s_waitcnt vmcnt(4)" ::: "memory");
    } else {
      asm volatile("s_waitcnt vmcnt(0)" ::: "memory");
    }
    __builtin_amdgcn_s_barrier();
    asm volatile("" ::: "memory");
    short8 af[4], bfr[4];
#pragma unroll
    for (int fm=0; fm<4; ++fm) af[fm]  = *(const short8*)&smem[cur*8192 + (wm*64 + fm*16 + lr)*32 + lh*8];
#pragma unroll
    for (int fn=0; fn<4; ++fn) bfr[fn] = *(const short8*)&smem[cur*8192 + 4096 + (wn*64 + fn*16 + lr)*32 + lh*8];
#pragma unroll
    for (int fm=0; fm<4; ++fm)
#pragma unroll
      for (int fn=0; fn<4; ++fn)
        acc[fm][fn] = __builtin_amdgcn_mfma_f32_16x16x32_bf16(af[fm], bfr[fn], acc[fm][fn], 0, 0, 0);
    asm volatile("" ::: "memory");
    __builtin_amdgcn_s_barrier();
    asm volatile("" ::: "memory");
    cur += 1; if (cur >= 3) cur = 0;
  }
  int dep = __float_as_int(acc[0][0][0]);
  int z_;
  asm volatile("v_and_b32 %0, 0, %1" : "=v"(z_) : "v"(dep));
  const float* biasp = bias + z_;

  float bv[4], cs[4]={0,0,0,0}, cq[4]={0,0,0,0};
  int col[4];
#pragma unroll
  for (int fn=0; fn<4; ++fn){ col[fn] = n0 + wn*64 + fn*16 + lr; bv[fn] = biasp[col[fn]]; }
#pragma unroll
  for (int fm=0; fm<4; ++fm){
#pragma unroll
    for (int j=0; j<4; ++j){
      int row = m0 + wm*64 + fm*16 + lh*4 + j;
      bool real = (row & 511) < NG;
#pragma unroll
      for (int fn=0; fn<4; ++fn){
        float v = fmaxf(acc[fm][fn][j] + bv[fn], 0.f);
        O[(size_t)row*HID + col[fn]] = f2bf(v);
        if (real){ cs[fn] += v; cq[fn] += v*v; }
      }
    }
  }
#pragma unroll
  for (int m=16; m<64; m<<=1){
#pragma unroll
    for (int fn=0; fn<4; ++fn){ cs[fn] += __shfl_xor(cs[fn], m); cq[fn] += __shfl_xor(cq[fn], m); }
  }
  if (lh == 0){
#pragma unroll
    for (int fn=0; fn<4; ++fn){
      atomicAdd(&stats[col[fn]], cs[fn]);
      atomicAdd(&stats[512+col[fn]], cq[fn]);
    }
  }
}

// ---------------- pooling: wave-decomposed, 16B/lane, LDS cross-wave reduce ----------------
__global__ __launch_bounds__(256) void pool2(const unsigned short* __restrict__ XC,
                                             const unsigned short* __restrict__ XO,
                                             const int* __restrict__ batch,
                                             float* __restrict__ gc, float* __restrict__ go,
                                             float* __restrict__ rst){
  __shared__ float red[4*512];
  int g = blockIdx.x;
  int t = threadIdx.x;
  int w = t >> 6, l = t & 63;
  const unsigned short* X = blockIdx.y ? XO : XC;
  float* out = blockIdx.y ? go : gc;
  float* st = rst + blockIdx.y*1024;
  int lo = 0, hi = NN;
  while (lo < hi){ int mid = (lo+hi) >> 1; if (batch[mid] < g) lo = mid+1; else hi = mid; }
  int s = lo;
  lo = 0; hi = NN;
  while (lo < hi){ int mid = (lo+hi) >> 1; if (batch[mid] < g+1) lo = mid+1; else hi = mid; }
  int e = lo;
  // wave w handles rows s+w, s+w+4, ... ; lane l covers columns l*8..l*8+7 (16B)
  float acc[8] = {0,0,0,0,0,0,0,0};
  const uint4* Xv = (const uint4*)X;
  int i = s + w;
  for (; i + 4 < e; i += 8){
    uint4 v0 = Xv[(size_t)i*64 + l];
    uint4 v1 = Xv[(size_t)(i+4)*64 + l];
    add8(acc, v0); add8(acc, v1);
  }
  for (; i < e; i += 4){
    uint4 v = Xv[(size_t)i*64 + l];
    add8(acc, v);
  }
#pragma unroll
  for (int k=0;k<8;k++) red[w*512 + l*8 + k] = acc[k];
  __syncthreads();
  // thread t reduces columns 2t, 2t+1 across the 4 waves
  int c0 = t*2, c1 = t*2+1;
  float a0 = red[c0] + red[512+c0] + red[1024+c0] + red[1536+c0];
  float a1 = red[c1] + red[512+c1] + red[1024+c1] + red[1536+c1];
  out[(size_t)g*HID + c0] = a0;
  out[(size_t)g*HID + c1] = a1;
  atomicAdd(&st[c0], a0); atomicAdd(&st[512+c0], a0*a0);
  atomicAdd(&st[c1], a1); atomicAdd(&st[512+c1], a1*a1);
}

// ---------------- readout BN1 stats, branch 2 only (gc[perm]+go), atomic out ----------------
__global__ __launch_bounds__(256) void bnstats_co(const float* __restrict__ gc, const float* __restrict__ go,
                                                  const int* __restrict__ perm, float* __restrict__ st2){
  __shared__ float lds[256*9];
  int t = threadIdx.x;
  int cid = t & 127, rid = t >> 7;
  float s[4]={0,0,0,0}, q[4]={0,0,0,0};
  const int rowsPer = (NG + NB3 - 1)/NB3;
  int r0 = blockIdx.x*rowsPer, r1 = r0 + rowsPer; if (r1 > NG) r1 = NG;
  for (int r = r0 + rid; r < r1; r += 2){
    int ps = perm[r];
    float4 a = *(const float4*)&gc[(size_t)ps*HID + cid*4];
    float4 b = *(const float4*)&go[(size_t)r*HID + cid*4];
    float e[4] = {a.x+b.x, a.y+b.y, a.z+b.z, a.w+b.w};
#pragma unroll
    for (int i=0;i<4;i++){ s[i]+=e[i]; q[i]+=e[i]*e[i]; }
  }
  int base = (rid*128 + cid)*9;
#pragma unroll
  for (int i=0;i<4;i++){ lds[base+i]=s[i]; lds[base+4+i]=q[i]; }
  __syncthreads();
  for (int o = t; o < 1024; o += 256){
    int issq = o >> 9, col = o & 511;
    int ci = col >> 2, i = col & 3;
    float acc = lds[(0*128 + ci)*9 + issq*4 + i] + lds[(1*128 + ci)*9 + issq*4 + i];
    atomicAdd(&st2[issq*512 + col], acc);
  }
}

// ---------------- cast 3 branches to bf16 with inline BN from raw sums ----------------
__global__ void bncast3(const float* __restrict__ gc, const float* __restrict__ go,
                        const int* __restrict__ perm, const float* __restrict__ rst,
                        float invM, unsigned short* __restrict__ out){
  int idx = blockIdx.x*blockDim.x + threadIdx.x;
  if (idx >= 1536*128) return;
  int r = idx >> 7;
  int cg = idx & 127;
  int br = r >> 9, lr = r & 511;
  ushort4v o;
  if (lr >= NG){ o[0]=0; o[1]=0; o[2]=0; o[3]=0; }
  else {
    float4 v;
    if (br == 0)      v = *(const float4*)&gc[(size_t)lr*HID + cg*4];
    else if (br == 1) v = *(const float4*)&go[(size_t)lr*HID + cg*4];
    else {
      int ps = perm[lr];
      float4 a = *(const float4*)&gc[(size_t)ps*HID + cg*4];
      float4 b = *(const float4*)&go[(size_t)lr*HID + cg*4];
      v = make_float4(a.x+b.x, a.y+b.y, a.z+b.z, a.w+b.w);
    }
    const float* ms = rst + br*1024;
    int c = cg*4;
    float e[4] = {v.x, v.y, v.z, v.w};
#pragma unroll
    for (int i=0;i<4;i++){
      float m = ms[c+i]*invM;
      float rs = rsqrtf(ms[512+c+i]*invM - m*m + 1e-5f);
      o[i] = f2bf((e[i] - m)*rs + 1e-4f);
    }
  }
  *(ushort4v*)&out[(size_t)r*HID + cg*4] = o;
}

// ---------------- final: batched BN2 -> fc2 -> log_softmax ----------------
struct ROP { const float* W2[3]; const float* b2[3]; };
__global__ void readout_final3(const unsigned short* __restrict__ T, const float* __restrict__ statsB,
                               float invM, ROP p, float* __restrict__ out){
  int g = blockIdx.x;
  int br = blockIdx.y;
  int l = threadIdx.x;
  const float* stats = statsB + br*1024;
  const float* W2 = p.W2[br];
  const float* b2 = p.b2[br];
  float acc[NCLS];
#pragma unroll
  for (int c=0; c<NCLS; ++c) acc[c] = 0.f;
  uint4 u = ((const uint4*)(T + (size_t)(br*512 + g)*HID))[l];
  float xv[8] = {bf2f(u.x&0xffffu), bf2f(u.x>>16), bf2f(u.y&0xffffu), bf2f(u.y>>16),
                 bf2f(u.z&0xffffu), bf2f(u.z>>16), bf2f(u.w&0xffffu), bf2f(u.w>>16)};
#pragma unroll
  for (int j=0; j<8; ++j){
    int k = l*8 + j;
    float m = stats[k]*invM;
    float rs = rsqrtf(stats[512+k]*invM - m*m + 1e-5f);
    float v = (xv[j] - m)*rs + 1e-4f;
#pragma unroll
    for (int c=0; c<NCLS; ++c) acc[c] += v * W2[k*NCLS + c];
  }
  for (int m=1; m<64; m<<=1){
#pragma unroll
    for (int c=0; c<NCLS; ++c) acc[c] += __shfl_xor(acc[c], m);
  }
  if (l == 0){
    float z[NCLS];
    float mx = -1e30f;
#pragma unroll
    for (int c=0; c<NCLS; ++c){ z[c] = acc[c] + b2[c]; mx = fmaxf(mx, z[c]); }
    float s = 0.f;
#pragma unroll
    for (int c=0; c<NCLS; ++c) s += expf(z[c]-mx);
    float lse = mx + logf(s);
#pragma unroll
    for (int c=0; c<NCLS; ++c) out[(size_t)(br*NG + g)*NCLS + c] = z[c] - lse;
  }
}

extern "C" void kernel_launch(void* const* d_in, const int* in_sizes, int n_in,
                              void* d_out, int out_size, void* d_ws, size_t ws_size,
                              hipStream_t stream){
  (void)in_sizes; (void)n_in; (void)out_size;
  const float* x      = (const float*)d_in[0];
  const int*   ei     = (const int*)d_in[1];
  const int*   batch  = (const int*)d_in[2];
  const int*   perm   = (const int*)d_in[3];
  const float* convfW = (const float*)d_in[4];
  const float* convfB = (const float*)d_in[5];
  const float* convsW = (const float*)d_in[6];
  const float* convsB = (const float*)d_in[7];
  const float* eattW  = (const float*)d_in[8];
  const float* eattB  = (const float*)d_in[9];
  const float* nattW  = (const float*)d_in[10];
  const float* nattB  = (const float*)d_in[11];
  const float* ctxW   = (const float*)d_in[12];
  const float* ctxB   = (const float*)d_in[13];
  const float* objW   = (const float*)d_in[14];
  const float* objB   = (const float*)d_in[15];
  const float* fc1W[3] = {(const float*)d_in[16], (const float*)d_in[20], (const float*)d_in[24]};
  const float* fc1B[3] = {(const float*)d_in[17], (const float*)d_in[21], (const float*)d_in[25]};
  const float* fc2W[3] = {(const float*)d_in[18], (const float*)d_in[22], (const float*)d_in[26]};
  const float* fc2B[3] = {(const float*)d_in[19], (const float*)d_in[23], (const float*)d_in[27]};
  float* out = (float*)d_out;

  char* p = (char*)d_ws;
  auto alloc = [&](size_t bytes)->char*{ char* r = p; p += (bytes + 255) & ~((size_t)255); return r; };
  const int T = NE + NN;
  unsigned short* Xbf = (unsigned short*)alloc((size_t)NN*HID*2);
  unsigned short* Gbf = (unsigned short*)alloc((size_t)NN*HID*2);
  unsigned short* GbfO= (unsigned short*)alloc((size_t)NN*HID*2);
  unsigned short* XbfO= (unsigned short*)alloc((size_t)NN*HID*2);
  unsigned short* Abf = (unsigned short*)alloc((size_t)NN*FIN*2);
  unsigned short* WtF = (unsigned short*)alloc((size_t)HID*FIN*2);
  unsigned short* WtL = (unsigned short*)alloc((size_t)3*HID*HID*2);
  unsigned short* WtC = (unsigned short*)alloc((size_t)HID*HID*2);
  unsigned short* WtO = (unsigned short*)alloc((size_t)HID*HID*2);
  unsigned short* WtR = (unsigned short*)alloc((size_t)3*HID*HID*2);
  int* cnt   = (int*)alloc((size_t)NN*4);
  int* fillc = (int*)alloc((size_t)NN*4);
  int* rowp  = (int*)alloc((size_t)(NN+1)*4);
  int* bsum  = (int*)alloc(32*4);
  int* ccol  = (int*)alloc((size_t)T*4);
  int* crow  = (int*)alloc((size_t)T*4);
  int* ceid  = (int*)alloc((size_t)T*4);
  int2* cw1  = (int2*)alloc((size_t)T*8);
  float* wcv = (float*)alloc((size_t)T*4);
  float* wov = (float*)alloc((size_t)T*4);
  float* dis1 = (float*)alloc((size_t)NN*4);
  float* degc = (float*)alloc((size_t)NN*4);
  float* dego = (float*)alloc((size_t)NN*4);
  float* Sc   = (float*)alloc((size_t)NN*4);
  float* So   = (float*)alloc((size_t)NN*4);
  float* statsA = (float*)alloc((size_t)STATSA_N*4);
  float* na   = (float*)alloc((size_t)NN*2*4);
  float* eab  = (float*)alloc((size_t)NN*4*4);
  float* att  = (float*)alloc((size_t)NE*2*4);
  float* gc   = (float*)alloc((size_t)NG*HID*4);
  float* go   = (float*)alloc((size_t)NG*HID*4);
  if ((size_t)(p - (char*)d_ws) > ws_size){
    sentinel_k<<<1,1,0,stream>>>(out);
    return;
  }
  unsigned short* Abf3 = Abf;
  unsigned short* Gbf3 = GbfO;
  float* stats6 = statsA;
  float* cstat  = statsA + 6144;
  float* dstat  = statsA + 6400;
  float* rst    = statsA + 8448;
  const float invNN = 1.0f/(float)NN;
  const float invNG = 1.0f/(float)NG;
  const int GEMM_LDS = 3*8192*2;

  // setup
  W2BT wp;
  wp.src[0]=convfW; wp.dst[0]=WtF;
  for (int i=0;i<3;i++){ wp.src[1+i]=convsW+(size_t)i*HID*HID; wp.dst[1+i]=WtL+(size_t)i*HID*HID; }
  wp.src[4]=ctxW; wp.dst[4]=WtC;
  wp.src[5]=objW; wp.dst[5]=WtO;
  for (int i=0;i<3;i++){ wp.src[6+i]=fc1W[i]; wp.dst[6+i]=WtR+(size_t)i*HID*HID; }
  setup_all<<<(FIN*HID + 8*HID*HID + 255)/256, 256, 0, stream>>>(wp, cnt, fillc, degc, dego, Sc, So, statsA);

  d1_count_stats<<<BNG + (NE+1023)/1024, 1024, 0, stream>>>(ei, cnt, x, cstat);
  d2_scan<<<(NN+1023)/1024, 1024, 0, stream>>>(cnt, rowp, dis1, bsum);
  d3_scan_cast<<<20 + (NN*FIN/4 + 1023)/1024, 1024, 0, stream>>>(rowp, bsum, x, cstat, invNN, Abf);
  csr_fill<<<(T+255)/256,256,0,stream>>>(ei, rowp, cnt, fillc, dis1, ccol, crow, ceid, cw1);

  const int NBLK = ((NN+127)/128)*4;   // 628

  gemm_bt<<<NBLK,256,GEMM_LDS,stream>>>(Abf, WtF, Xbf, convfB, stats6, NN, FIN, 1,
                                        0, nullptr, nullptr, nullptr, nullptr);

  for (int i=0;i<3;i++){
    aggregate_bn<<<NN/4,256,0,stream>>>(Xbf, rowp, cw1, stats6 + i*1024, invNN, Gbf);
    gemm_bt<<<NBLK,256,GEMM_LDS,stream>>>(Gbf, WtL+(size_t)i*HID*HID, Xbf,
                                          convsB+(size_t)i*HID,
                                          (i<2) ? (stats6 + (i+1)*1024) : nullptr,
                                          NN, HID, 1, 0, nullptr, nullptr, nullptr, nullptr);
  }

  att_node<<<NN/4,256,0,stream>>>(Xbf, nattW, nattB, eattW, na, eab);
  att_edge<<<(NE+255)/256,256,0,stream>>>(ei, eab, eattB, att, degc, dego);
  wco_kernel<<<(T+255)/256,256,0,stream>>>(crow, ccol, ceid, att, degc, dego, na, wcv, wov, Sc, So);

  bnstats_dual<<<BNG,1024,0,stream>>>(Xbf, na, dstat);
  aggregate_dual<<<NN/4,256,0,stream>>>(Xbf, rowp, ccol, wcv, wov, Sc, So, dstat, invNN, Gbf, GbfO);
  gemm_bt<<<2*NBLK,256,GEMM_LDS,stream>>>(Gbf, WtC, Xbf, ctxB, nullptr, NN, HID, 1,
                                          NBLK, GbfO, WtO, XbfO, objB);
  pool2<<<dim3(NG,2),256,0,stream>>>(Xbf, XbfO, batch, gc, go, rst);

  bnstats_co<<<NB3,256,0,stream>>>(gc, go, perm, rst + 2*1024);
  bncast3<<<(1536*128+255)/256,256,0,stream>>>(gc, go, perm, rst, invNG, Abf3);
  FC1P fp;
  for (int i=0;i<3;i++){ fp.Bt[i] = WtR+(size_t)i*HID*HID; fp.bias[i] = fc1B[i]; }
  gemm_fc1<<<dim3(12,4),256,GEMM_LDS,stream>>>(Abf3, fp, Gbf3, stats6 + 3*1024);
  ROP rp;
  for (int i=0;i<3;i++){ rp.W2[i] = fc2W[i]; rp.b2[i] = fc2B[i]; }
  readout_final3<<<dim3(NG,3),64,0,stream>>>(Gbf3, stats6 + 3*1024, invNG, rp, out);
}

// Round 12
// 400.093 us; speedup vs baseline: 1.1730x; 1.0704x over previous
//
#include <hip/hip_runtime.h>
#include <stdint.h>

#define NN 20000
#define NE 160000
#define NG 500
#define FIN 128
#define HID 512
#define NCLS 10
#define BNG 256
#define NB3 32

typedef __attribute__((ext_vector_type(8))) short short8;
typedef __attribute__((ext_vector_type(4))) float f32x4;
typedef __attribute__((ext_vector_type(4))) unsigned short ushort4v;

__device__ __forceinline__ float bf2f(unsigned int u){
  union{unsigned int i; float f;} x; x.i = u<<16; return x.f;
}
__device__ __forceinline__ unsigned short f2bf(float f){
  union{float f; unsigned int i;} x; x.f=f;
  unsigned int r = x.i + 0x7fffu + ((x.i>>16)&1u);
  return (unsigned short)(r>>16);
}
__device__ __forceinline__ unsigned int pk2(float a, float b){
  return (unsigned int)f2bf(a) | ((unsigned int)f2bf(b) << 16);
}

__device__ __forceinline__ void gload16(unsigned short* lds, const unsigned short* g){
  __builtin_amdgcn_global_load_lds((const __attribute__((address_space(1))) unsigned int*)g,
                                   (__attribute__((address_space(3))) unsigned int*)lds,
                                   16, 0, 0);
}

__device__ __forceinline__ void fma8(float* acc, uint4 v, float w){
  acc[0] += w*bf2f(v.x & 0xffffu); acc[1] += w*bf2f(v.x >> 16);
  acc[2] += w*bf2f(v.y & 0xffffu); acc[3] += w*bf2f(v.y >> 16);
  acc[4] += w*bf2f(v.z & 0xffffu); acc[5] += w*bf2f(v.z >> 16);
  acc[6] += w*bf2f(v.w & 0xffffu); acc[7] += w*bf2f(v.w >> 16);
}
__device__ __forceinline__ void add8(float* acc, uint4 v){
  acc[0] += bf2f(v.x & 0xffffu); acc[1] += bf2f(v.x >> 16);
  acc[2] += bf2f(v.y & 0xffffu); acc[3] += bf2f(v.y >> 16);
  acc[4] += bf2f(v.z & 0xffffu); acc[5] += bf2f(v.z >> 16);
  acc[6] += bf2f(v.w & 0xffffu); acc[7] += bf2f(v.w >> 16);
}

__global__ void sentinel_k(float* out){ out[0] = 12345.0f; }

// statsA layout (floats, all zeroed in setup):
//   [0..1023]      L0-input stats   [1024..2047] L1   [2048..3071] L2
//   [3072..6143]   fc1-out stats x3
//   [6144..6399]   conv-input stats (F=128)
//   [6400..8447]   dual stats
//   [8448..11519]  readout BN1 stats x3
#define STATSA_N 12288

// ---------------- setup ----------------
struct W2BT { const float* src[9]; unsigned short* dst[9]; };
__global__ void setup_all(W2BT p, int* __restrict__ cnt, int* __restrict__ fillc,
                          float* __restrict__ degc, float* __restrict__ dego,
                          float* __restrict__ Sc, float* __restrict__ So,
                          float* __restrict__ statsA){
  int idx = blockIdx.x*blockDim.x + threadIdx.x;
  if (idx < FIN*HID + 8*HID*HID){
    int seg, off, K;
    if (idx < FIN*HID){ seg = 0; off = idx; K = FIN; }
    else {
      int r = idx - FIN*HID;
      seg = 1 + (r >> 18); off = r & (HID*HID-1); K = HID;
    }
    int k = off >> 9, n = off & 511;
    p.dst[seg][(size_t)n*K + k] = f2bf(p.src[seg][off]);
  }
  if (idx < NN){ cnt[idx]=0; fillc[idx]=0; degc[idx]=1.0f; dego[idx]=1.0f; Sc[idx]=0.f; So[idx]=0.f; }
  if (idx < STATSA_N) statsA[idx] = 0.f;
}

// ---------------- D1: csr_count + conv BN stats (atomic out) ----------------
__global__ __launch_bounds__(1024) void d1_count_stats(const int* __restrict__ ei, int* __restrict__ cnt,
                                                       const float* __restrict__ X, float* __restrict__ cstat){
  __shared__ float lds[1024*9];
  const int t = threadIdx.x;
  if (blockIdx.x >= BNG){
    int e = (blockIdx.x - BNG)*1024 + t;
    if (e < NE) atomicAdd(&cnt[ei[e]], 1);
    return;
  }
  const int cg = FIN >> 2;
  const int cid = t & (cg-1);
  const int rid = t / cg;
  const int rpb = 1024 / cg;
  float s0=0,s1=0,s2=0,s3=0,q0=0,q1=0,q2=0,q3=0;
  const int rowsPer = (NN + BNG - 1)/BNG;
  int r0 = blockIdx.x*rowsPer, r1 = r0 + rowsPer; if (r1 > NN) r1 = NN;
  for (int r = r0 + rid; r < r1; r += rpb){
    float4 v = *(const float4*)&X[(size_t)r*FIN + cid*4];
    s0+=v.x; q0+=v.x*v.x; s1+=v.y; q1+=v.y*v.y; s2+=v.z; q2+=v.z*v.z; s3+=v.w; q3+=v.w*v.w;
  }
  int base = (rid*cg + cid)*9;
  lds[base+0]=s0; lds[base+1]=s1; lds[base+2]=s2; lds[base+3]=s3;
  lds[base+4]=q0; lds[base+5]=q1; lds[base+6]=q2; lds[base+7]=q3;
  __syncthreads();
  if (t < cg*8){
    int ci = t >> 3, i = t & 7;
    float acc = 0.f;
    for (int g=0; g<rpb; ++g) acc += lds[(g*cg + ci)*9 + i];
    int col = ci*4 + (i & 3);
    atomicAdd(&cstat[(i < 4) ? col : FIN + col], acc);
  }
}

// ---------------- D2: rowptr scan stage 1 ----------------
__global__ __launch_bounds__(1024) void d2_scan(const int* __restrict__ cnt, int* __restrict__ rowp,
                                                float* __restrict__ dis1, int* __restrict__ bsum){
  __shared__ int buf[1024];
  int t = threadIdx.x;
  int i = blockIdx.x*1024 + t;
  int v = 0;
  if (i < NN){ v = cnt[i] + 1; dis1[i] = rsqrtf((float)v); }
  buf[t] = v;
  __syncthreads();
  for (int off=1; off<1024; off<<=1){
    int xv = (t >= off) ? buf[t-off] : 0;
    __syncthreads();
    buf[t] += xv;
    __syncthreads();
  }
  if (i < NN) rowp[i+1] = buf[t];
  if (t == 1023) bsum[blockIdx.x] = buf[1023];
}

// ---------------- D3: scan stage 2 + conv bncast (inline BN) ----------------
__global__ __launch_bounds__(1024) void d3_scan_cast(int* __restrict__ rowp, const int* __restrict__ bsum,
                                                     const float* __restrict__ X, const float* __restrict__ cstat,
                                                     float invM, unsigned short* __restrict__ out){
  __shared__ int base;
  int t = threadIdx.x;
  if (blockIdx.x < 20){
    int bx = blockIdx.x;
    if (t == 0){
      int a = 0;
      for (int b=0; b<bx; ++b) a += bsum[b];
      base = a;
    }
    __syncthreads();
    int i = bx*1024 + t;
    if (i < NN) rowp[i+1] += base;
    if (i == 0) rowp[0] = 0;
    return;
  }
  int idx = (blockIdx.x - 20)*1024 + t;
  int total4 = NN*FIN/4;
  if (idx >= total4) return;
  int b4 = idx*4;
  int c = b4 & (FIN-1);
  float4 v = *(const float4*)&X[b4];
  float e[4] = {v.x, v.y, v.z, v.w};
  ushort4v o;
#pragma unroll
  for (int i=0;i<4;i++){
    float m = cstat[c+i]*invM;
    float rs = rsqrtf(cstat[FIN+c+i]*invM - m*m + 1e-5f);
    o[i] = f2bf((e[i] - m)*rs + 1e-4f);
  }
  *(ushort4v*)&out[b4] = o;
}

// csr_fill + w1 fused
__global__ void csr_fill(const int* __restrict__ ei, const int* __restrict__ rowp,
                         const int* __restrict__ cnt, int* __restrict__ fillc,
                         const float* __restrict__ dis1,
                         int* __restrict__ ccol, int* __restrict__ crow, int* __restrict__ ceid,
                         int2* __restrict__ cw1){
  int id = blockIdx.x*blockDim.x + threadIdx.x;
  if (id < NE){
    int r = ei[id], c = ei[NE + id];
    int pos = atomicAdd(&fillc[r], 1);
    int idx = rowp[r] + pos;
    ccol[idx] = c; crow[idx] = r; ceid[idx] = id;
    cw1[idx] = make_int2(c, __float_as_int(dis1[r]*dis1[c]));
  } else if (id < NE + NN){
    int i = id - NE;
    int idx = rowp[i] + cnt[i];
    ccol[idx] = i; crow[idx] = i; ceid[idx] = -1;
    cw1[idx] = make_int2(i, __float_as_int(dis1[i]*dis1[i]));
  }
}

// ---------------- dual BN stats on bf16 X (atomic out) ----------------
__global__ __launch_bounds__(1024) void bnstats_dual(const unsigned short* __restrict__ X,
                                                     const float* __restrict__ na,
                                                     float* __restrict__ dstat){
  __shared__ float lds[1024*17];
  const int t = threadIdx.x;
  const int cid = t & 127;
  const int rid = t >> 7;
  float sC[4]={0,0,0,0}, qC[4]={0,0,0,0}, sO[4]={0,0,0,0}, qO[4]={0,0,0,0};
  const int rowsPer = (NN + BNG - 1)/BNG;
  int r0 = blockIdx.x*rowsPer, r1 = r0 + rowsPer; if (r1 > NN) r1 = NN;
  for (int r = r0 + rid; r < r1; r += 8){
    float a0 = na[2*r], a1 = na[2*r+1];
    uint2 u = *(const uint2*)&X[(size_t)r*HID + cid*4];
    float e[4] = {bf2f(u.x & 0xffffu), bf2f(u.x >> 16), bf2f(u.y & 0xffffu), bf2f(u.y >> 16)};
#pragma unroll
    for (int i=0;i<4;i++){
      float vc = e[i]*a0, vo = e[i]*a1;
      sC[i]+=vc; qC[i]+=vc*vc; sO[i]+=vo; qO[i]+=vo*vo;
    }
  }
  int base = (rid*128 + cid)*17;
#pragma unroll
  for (int i=0;i<4;i++){
    lds[base+i]=sC[i]; lds[base+4+i]=qC[i]; lds[base+8+i]=sO[i]; lds[base+12+i]=qO[i];
  }
  __syncthreads();
  for (int idx = t; idx < 2048; idx += 1024){
    int ci = idx >> 4, i = idx & 15;
    float acc = 0.f;
    for (int g=0; g<8; ++g) acc += lds[(g*128 + ci)*17 + i];
    int grp = i >> 2, col = ci*4 + (i & 3);
    atomicAdd(&dstat[grp*HID + col], acc);
  }
}

// ---------------- attention (bf16 X), weights staged in LDS ----------------
__global__ void att_node(const unsigned short* __restrict__ X, const float* __restrict__ nW,
                         const float* __restrict__ nb, const float* __restrict__ eW,
                         float* __restrict__ na, float* __restrict__ eab){
  __shared__ float wnl[1024], wet[1024], web[1024];
  int t = threadIdx.x;
  for (int i=t; i<1024; i+=256){ wnl[i]=nW[i]; wet[i]=eW[i]; web[i]=eW[1024+i]; }
  __syncthreads();
  int wv = blockIdx.x*4 + (t >> 6);
  int l = t & 63;
  uint4 u = ((const uint4*)(X + (size_t)wv*HID))[l];
  float xv[8] = {bf2f(u.x&0xffffu), bf2f(u.x>>16), bf2f(u.y&0xffffu), bf2f(u.y>>16),
                 bf2f(u.z&0xffffu), bf2f(u.z>>16), bf2f(u.w&0xffffu), bf2f(u.w>>16)};
  float s0=0,s1=0,s2=0,s3=0,s4=0,s5=0;
#pragma unroll
  for (int j=0; j<8; ++j){
    int k = l*8 + j;
    float x = xv[j];
    s0 += x * wnl[2*k];   s1 += x * wnl[2*k+1];
    s2 += x * wet[2*k];   s3 += x * wet[2*k+1];
    s4 += x * web[2*k];   s5 += x * web[2*k+1];
  }
  for (int m=1; m<64; m<<=1){
    s0 += __shfl_xor(s0,m); s1 += __shfl_xor(s1,m); s2 += __shfl_xor(s2,m);
    s3 += __shfl_xor(s3,m); s4 += __shfl_xor(s4,m); s5 += __shfl_xor(s5,m);
  }
  if (l == 0){
    float z0 = s0 + nb[0], z1 = s1 + nb[1];
    float mx = fmaxf(z0,z1);
    float e0 = expf(z0-mx), e1 = expf(z1-mx);
    float inv = 1.0f/(e0+e1);
    na[2*wv] = e0*inv; na[2*wv+1] = e1*inv;
    eab[4*wv] = s2; eab[4*wv+1] = s3; eab[4*wv+2] = s4; eab[4*wv+3] = s5;
  }
}

__global__ void att_edge(const int* __restrict__ ei, const float* __restrict__ eab,
                         const float* __restrict__ eb, float* __restrict__ att,
                         float* __restrict__ degc, float* __restrict__ dego){
  int e = blockIdx.x*blockDim.x + threadIdx.x;
  if (e >= NE) return;
  int r = ei[e], c = ei[NE+e];
  float z0 = eab[4*r]   + eab[4*c+2] + eb[0];
  float z1 = eab[4*r+1] + eab[4*c+3] + eb[1];
  float mx = fmaxf(z0,z1);
  float e0 = expf(z0-mx), e1 = expf(z1-mx);
  float inv = 1.0f/(e0+e1);
  float a0 = e0*inv, a1 = e1*inv;
  att[2*e] = a0; att[2*e+1] = a1;
  atomicAdd(&degc[r], a0);
  atomicAdd(&dego[r], a1);
}

__global__ void wco_kernel(const int* __restrict__ crow, const int* __restrict__ ccol,
                           const int* __restrict__ ceid, const float* __restrict__ att,
                           const float* __restrict__ degc, const float* __restrict__ dego,
                           const float* __restrict__ na,
                           float* __restrict__ wcv, float* __restrict__ wov,
                           float* __restrict__ Sc, float* __restrict__ So){
  int j = blockIdx.x*blockDim.x + threadIdx.x;
  if (j >= NE + NN) return;
  int r = crow[j], c = ccol[j], e = ceid[j];
  float a0 = (e < 0) ? 1.0f : att[2*e];
  float a1 = (e < 0) ? 1.0f : att[2*e+1];
  float wc = rsqrtf(degc[r]) * a0 * rsqrtf(degc[c]);
  float wo = rsqrtf(dego[r]) * a1 * rsqrtf(dego[c]);
  wcv[j] = wc * na[2*c];
  wov[j] = wo * na[2*c+1];
  atomicAdd(&Sc[r], wc);
  atomicAdd(&So[r], wo);
}

// ---------------- wave-per-row aggregation (int2 pairs), 8-deep ILP, BN affine epilogue ----------------
__global__ __launch_bounds__(256) void aggregate_bn(const unsigned short* __restrict__ A,
                                                    const int* __restrict__ rowp,
                                                    const int2* __restrict__ cw,
                                                    const float* __restrict__ stats,
                                                    float invM,
                                                    unsigned short* __restrict__ out){
  int row = blockIdx.x*4 + (threadIdx.x >> 6);
  int l = threadIdx.x & 63;
  const uint4* Av = (const uint4*)A;
  int s = rowp[row], e = rowp[row+1];
  float acc[8] = {0,0,0,0,0,0,0,0};
  float sw = 0.f;
  int j = s;
  for (; j+7 < e; j += 8){
    int2 p[8]; uint4 v[8];
#pragma unroll
    for (int k=0;k<8;k++) p[k] = cw[j+k];
#pragma unroll
    for (int k=0;k<8;k++) v[k] = Av[(size_t)p[k].x*64 + l];
#pragma unroll
    for (int k=0;k<8;k++){ float w = __int_as_float(p[k].y); fma8(acc, v[k], w); sw += w; }
  }
  for (; j+3 < e; j += 4){
    int2 p[4]; uint4 v[4];
#pragma unroll
    for (int k=0;k<4;k++) p[k] = cw[j+k];
#pragma unroll
    for (int k=0;k<4;k++) v[k] = Av[(size_t)p[k].x*64 + l];
#pragma unroll
    for (int k=0;k<4;k++){ float w = __int_as_float(p[k].y); fma8(acc, v[k], w); sw += w; }
  }
  for (; j < e; ++j){
    int2 p = cw[j];
    float w = __int_as_float(p.y);
    uint4 v = Av[(size_t)p.x*64 + l];
    fma8(acc, v, w);
    sw += w;
  }
  float g[8];
#pragma unroll
  for (int i=0;i<8;i++){
    int c = l*8 + i;
    float m = stats[c]*invM;
    float rs = rsqrtf(stats[512+c]*invM - m*m + 1e-5f);
    g[i] = rs*acc[i] + sw*(1e-4f - m*rs);
  }
  uint4 o;
  o.x = pk2(g[0],g[1]); o.y = pk2(g[2],g[3]); o.z = pk2(g[4],g[5]); o.w = pk2(g[6],g[7]);
  ((uint4*)out)[(size_t)row*64 + l] = o;
}

__global__ __launch_bounds__(256) void aggregate_dual(const unsigned short* __restrict__ A,
                                                      const int* __restrict__ rowp,
                                                      const int* __restrict__ ccol,
                                                      const float* __restrict__ wc,
                                                      const float* __restrict__ wo,
                                                      const float* __restrict__ Sc,
                                                      const float* __restrict__ So,
                                                      const float* __restrict__ dstat,
                                                      float invM,
                                                      unsigned short* __restrict__ outC,
                                                      unsigned short* __restrict__ outO){
  int row = blockIdx.x*4 + (threadIdx.x >> 6);
  int l = threadIdx.x & 63;
  const uint4* Av = (const uint4*)A;
  int s = rowp[row], e = rowp[row+1];
  float aC[8] = {0,0,0,0,0,0,0,0};
  float aO[8] = {0,0,0,0,0,0,0,0};
  int j = s;
  for (; j+7 < e; j += 8){
    int cc[8]; uint4 v[8];
#pragma unroll
    for (int k=0;k<8;k++) cc[k] = ccol[j+k];
#pragma unroll
    for (int k=0;k<8;k++) v[k] = Av[(size_t)cc[k]*64 + l];
#pragma unroll
    for (int k=0;k<8;k++){ fma8(aC, v[k], wc[j+k]); fma8(aO, v[k], wo[j+k]); }
  }
  for (; j+3 < e; j += 4){
    int cc[4]; uint4 v[4];
#pragma unroll
    for (int k=0;k<4;k++) cc[k] = ccol[j+k];
#pragma unroll
    for (int k=0;k<4;k++) v[k] = Av[(size_t)cc[k]*64 + l];
#pragma unroll
    for (int k=0;k<4;k++){ fma8(aC, v[k], wc[j+k]); fma8(aO, v[k], wo[j+k]); }
  }
  for (; j < e; ++j){
    uint4 v = Av[(size_t)ccol[j]*64 + l];
    fma8(aC, v, wc[j]); fma8(aO, v, wo[j]);
  }
  float ScR = Sc[row], SoR = So[row];
  float gC[8], gO[8];
#pragma unroll
  for (int i=0;i<8;i++){
    int c = l*8 + i;
    float mc = dstat[c]*invM;
    float rc = rsqrtf(dstat[512+c]*invM - mc*mc + 1e-5f);
    float mo = dstat[1024+c]*invM;
    float ro = rsqrtf(dstat[1536+c]*invM - mo*mo + 1e-5f);
    gC[i] = rc*aC[i] + ScR*(1e-4f - mc*rc);
    gO[i] = ro*aO[i] + SoR*(1e-4f - mo*ro);
  }
  uint4 oc, oo;
  oc.x = pk2(gC[0],gC[1]); oc.y = pk2(gC[2],gC[3]); oc.z = pk2(gC[4],gC[5]); oc.w = pk2(gC[6],gC[7]);
  oo.x = pk2(gO[0],gO[1]); oo.y = pk2(gO[2],gO[3]); oo.z = pk2(gO[4],gO[5]); oo.w = pk2(gO[6],gO[7]);
  ((uint4*)outC)[(size_t)row*64 + l] = oc;
  ((uint4*)outO)[(size_t)row*64 + l] = oo;
}

// ---------------- bf16 MFMA GEMM: XCD-chunked 1D grid, 3-buffer ring (vmcnt(8)), LDS-staged C ----------------
__global__ __launch_bounds__(256) void gemm_bt(const unsigned short* __restrict__ A,
                                               const unsigned short* __restrict__ Bt,
                                               unsigned short* __restrict__ O,
                                               const float* __restrict__ bias,
                                               float* __restrict__ stats,
                                               int M, int K, int relu, int split,
                                               const unsigned short* A2,
                                               const unsigned short* Bt2,
                                               unsigned short* O2,
                                               const float* bias2){
  extern __shared__ unsigned short smem[];
  unsigned short* Cs = smem;
  const int tid = threadIdx.x;
  const int w = tid >> 6, l = tid & 63;

  int lin = blockIdx.x;
  int total = gridDim.x;
  int q = total >> 3, r = total & 7;
  int xcd = lin & 7, idx = lin >> 3;
  int swz = (xcd < r ? xcd*(q+1) : r*(q+1) + (xcd - r)*q) + idx;
  if (split && swz >= split){ A = A2; Bt = Bt2; O = O2; bias = bias2; swz -= split; }
  const int m0 = (swz >> 2)*128, n0 = (swz & 3)*128;

  const int wm = w >> 1, wn = w & 1;
  const int lr = l & 15, lh = l >> 4;

  f32x4 acc[4][4];
#pragma unroll
  for (int i=0;i<4;i++)
#pragma unroll
    for (int j=0;j<4;j++) acc[i][j] = 0.0f;

  const int q0 = w*2, q1 = w*2+1;
  const int sub = l >> 2;
  const int kc  = (l & 3)*8;
  int ma0 = m0 + q0*16 + sub; if (ma0 >= M) ma0 = M-1;
  int ma1 = m0 + q1*16 + sub; if (ma1 >= M) ma1 = M-1;
  const int nb0 = n0 + q0*16 + sub;
  const int nb1 = n0 + q1*16 + sub;
  const unsigned short* Ar0 = A + (size_t)ma0*K + kc;
  const unsigned short* Ar1 = A + (size_t)ma1*K + kc;
  const unsigned short* Br0 = Bt + (size_t)nb0*K + kc;
  const unsigned short* Br1 = Bt + (size_t)nb1*K + kc;

  const int NT = K >> 5;
  gload16(&smem[0*8192 + q0*512], Ar0);
  gload16(&smem[0*8192 + q1*512], Ar1);
  gload16(&smem[0*8192 + 4096 + q0*512], Br0);
  gload16(&smem[0*8192 + 4096 + q1*512], Br1);
  if (NT > 1){
    gload16(&smem[1*8192 + q0*512], Ar0 + 32);
    gload16(&smem[1*8192 + q1*512], Ar1 + 32);
    gload16(&smem[1*8192 + 4096 + q0*512], Br0 + 32);
    gload16(&smem[1*8192 + 4096 + q1*512], Br1 + 32);
  }
  int cur = 0;
  for (int t=0; t<NT; ++t){
    if (t+2 < NT){
      int k1 = (t+2) << 5;
      int nb = cur + 2; if (nb >= 3) nb -= 3;
      gload16(&smem[nb*8192 + q0*512], Ar0 + k1);
      gload16(&smem[nb*8192 + q1*512], Ar1 + k1);
      gload16(&smem[nb*8192 + 4096 + q0*512], Br0 + k1);
      gload16(&smem[nb*8192 + 4096 + q1*512], Br1 + k1);
      asm volatile("s_waitcnt vmcnt(8)" ::: "memory");
    } else if (t+1 < NT){
      asm volatile("s_waitcnt vmcnt(4)" ::: "memory");
    } else {
      asm volatile("s_waitcnt vmcnt(0)" ::: "memory");
    }
    __builtin_amdgcn_s_barrier();
    asm volatile("" ::: "memory");
    short8 af[4], bfr[4];
#pragma unroll
    for (int fm=0; fm<4; ++fm) af[fm]  = *(const short8*)&smem[cur*8192 + (wm*64 + fm*16 + lr)*32 + lh*8];
#pragma unroll
    for (int fn=0; fn<4; ++fn) bfr[fn] = *(const short8*)&smem[cur*8192 + 4096 + (wn*64 + fn*16 + lr)*32 + lh*8];
#pragma unroll
    for (int fm=0; fm<4; ++fm)
#pragma unroll
      for (int fn=0; fn<4; ++fn)
        acc[fm][fn] = __builtin_amdgcn_mfma_f32_16x16x32_bf16(af[fm], bfr[fn], acc[fm][fn], 0, 0, 0);
    asm volatile("" ::: "memory");
    __builtin_amdgcn_s_barrier();
    asm volatile("" ::: "memory");
    cur += 1; if (cur >= 3) cur = 0;
  }
  int dep = __float_as_int(acc[0][0][0]);
  int z_;
  asm volatile("v_and_b32 %0, 0, %1" : "=v"(z_) : "v"(dep));
  const float* biasp = bias + z_;

  float bv[4], cs[4]={0,0,0,0}, cq[4]={0,0,0,0};
  int col[4];
#pragma unroll
  for (int fn=0; fn<4; ++fn){ col[fn] = n0 + wn*64 + fn*16 + lr; bv[fn] = biasp[col[fn]]; }
#pragma unroll
  for (int fm=0; fm<4; ++fm){
#pragma unroll
    for (int j=0; j<4; ++j){
      int trow = wm*64 + fm*16 + lh*4 + j;
      bool valid = (m0 + trow) < M;
#pragma unroll
      for (int fn=0; fn<4; ++fn){
        float v = acc[fm][fn][j] + bv[fn];
        if (relu) v = fmaxf(v, 0.f);
        Cs[trow*136 + wn*64 + fn*16 + lr] = f2bf(v);
        if (valid){ cs[fn] += v; cq[fn] += v*v; }
      }
    }
  }
  __syncthreads();
#pragma unroll
  for (int i=0;i<8;i++){
    int trow = i*16 + (tid>>4);
    int colb = (tid&15)*8;
    uint4 vv = *(const uint4*)&Cs[trow*136 + colb];
    int grow = m0 + trow;
    if (grow < M) *(uint4*)&O[(size_t)grow*HID + n0 + colb] = vv;
  }
  if (stats){
#pragma unroll
    for (int m=16; m<64; m<<=1){
#pragma unroll
      for (int fn=0; fn<4; ++fn){ cs[fn] += __shfl_xor(cs[fn], m); cq[fn] += __shfl_xor(cq[fn], m); }
    }
    if (lh == 0){
#pragma unroll
      for (int fn=0; fn<4; ++fn){
        atomicAdd(&stats[col[fn]], cs[fn]);
        atomicAdd(&stats[512+col[fn]], cq[fn]);
      }
    }
  }
}

// batched fc1 gemm: M=1536 (3 branches x 512 rows), 3-buffer ring
struct FC1P { const unsigned short* Bt[3]; const float* bias[3]; };
__global__ __launch_bounds__(256) void gemm_fc1(const unsigned short* __restrict__ A, FC1P p,
                                                unsigned short* __restrict__ O,
                                                float* __restrict__ statsB){
  extern __shared__ unsigned short smem[];
  const int tid = threadIdx.x;
  const int w = tid >> 6, l = tid & 63;
  const int m0 = blockIdx.x*128, n0 = blockIdx.y*128;
  const int branch = blockIdx.x >> 2;
  const unsigned short* Bt = p.Bt[branch];
  const float* bias = p.bias[branch];
  float* stats = statsB + branch*1024;
  const int K = HID;
  const int wm = w >> 1, wn = w & 1;
  const int lr = l & 15, lh = l >> 4;

  f32x4 acc[4][4];
#pragma unroll
  for (int i=0;i<4;i++)
#pragma unroll
    for (int j=0;j<4;j++) acc[i][j] = 0.0f;

  const int q0 = w*2, q1 = w*2+1;
  const int sub = l >> 2;
  const int kc  = (l & 3)*8;
  const int ma0 = m0 + q0*16 + sub;
  const int ma1 = m0 + q1*16 + sub;
  const int nb0 = n0 + q0*16 + sub;
  const int nb1 = n0 + q1*16 + sub;
  const unsigned short* Ar0 = A + (size_t)ma0*K + kc;
  const unsigned short* Ar1 = A + (size_t)ma1*K + kc;
  const unsigned short* Br0 = Bt + (size_t)nb0*K + kc;
  const unsigned short* Br1 = Bt + (size_t)nb1*K + kc;

  const int NT = K >> 5;
  gload16(&smem[0*8192 + q0*512], Ar0);
  gload16(&smem[0*8192 + q1*512], Ar1);
  gload16(&smem[0*8192 + 4096 + q0*512], Br0);
  gload16(&smem[0*8192 + 4096 + q1*512], Br1);
  gload16(&smem[1*8192 + q0*512], Ar0 + 32);
  gload16(&smem[1*8192 + q1*512], Ar1 + 32);
  gload16(&smem[1*8192 + 4096 + q0*512], Br0 + 32);
  gload16(&smem[1*8192 + 4096 + q1*512], Br1 + 32);
  int cur = 0;
  for (int t=0; t<NT; ++t){
    if (t+2 < NT){
      int k1 = (t+2) << 5;
      int nb = cur + 2; if (nb >= 3) nb -= 3;
      gload16(&smem[nb*8192 + q0*512], Ar0 + k1);
      gload16(&smem[nb*8192 + q1*512], Ar1 + k1);
      gload16(&smem[nb*8192 + 4096 + q0*512], Br0 + k1);
      gload16(&smem[nb*8192 + 4096 + q1*512], Br1 + k1);
      asm volatile("s_waitcnt vmcnt(8)" ::: "memory");
    } else if (t+1 < NT){
      asm volatile("s_waitcnt vmcnt(4)" ::: "memory");
    } else {
      asm volatile("s_waitcnt vmcnt(0)" ::: "memory");
    }
    __builtin_amdgcn_s_barrier();
    asm volatile("" ::: "memory");
    short8 af[4], bfr[4];
#pragma unroll
    for (int fm=0; fm<4; ++fm) af[fm]  = *(const short8*)&smem[cur*8192 + (wm*64 + fm*16 + lr)*32 + lh*8];
#pragma unroll
    for (int fn=0; fn<4; ++fn) bfr[fn] = *(const short8*)&smem[cur*8192 + 4096 + (wn*64 + fn*16 + lr)*32 + lh*8];
#pragma unroll
    for (int fm=0; fm<4; ++fm)
#pragma unroll
      for (int fn=0; fn<4; ++fn)
        acc[fm][fn] = __builtin_amdgcn_mfma_f32_16x16x32_bf16(af[fm], bfr[fn], acc[fm][fn], 0, 0, 0);
    asm volatile("" ::: "memory");
    __builtin_amdgcn_s_barrier();
    asm volatile("" ::: "memory");
    cur += 1; if (cur >= 3) cur = 0;
  }
  int dep = __float_as_int(acc[0][0][0]);
  int z_;
  asm volatile("v_and_b32 %0, 0, %1" : "=v"(z_) : "v"(dep));
  const float* biasp = bias + z_;

  float bv[4], cs[4]={0,0,0,0}, cq[4]={0,0,0,0};
  int col[4];
#pragma unroll
  for (int fn=0; fn<4; ++fn){ col[fn] = n0 + wn*64 + fn*16 + lr; bv[fn] = biasp[col[fn]]; }
#pragma unroll
  for (int fm=0; fm<4; ++fm){
#pragma unroll
    for (int j=0; j<4; ++j){
      int row = m0 + wm*64 + fm*16 + lh*4 + j;
      bool real = (row & 511) < NG;
#pragma unroll
      for (int fn=0; fn<4; ++fn){
        float v = fmaxf(acc[fm][fn][j] + bv[fn], 0.f);
        O[(size_t)row*HID + col[fn]] = f2bf(v);
        if (real){ cs[fn] += v; cq[fn] += v*v; }
      }
    }
  }
#pragma unroll
  for (int m=16; m<64; m<<=1){
#pragma unroll
    for (int fn=0; fn<4; ++fn){ cs[fn] += __shfl_xor(cs[fn], m); cq[fn] += __shfl_xor(cq[fn], m); }
  }
  if (lh == 0){
#pragma unroll
    for (int fn=0; fn<4; ++fn){
      atomicAdd(&stats[col[fn]], cs[fn]);
      atomicAdd(&stats[512+col[fn]], cq[fn]);
    }
  }
}

// ---------------- pooling: wave-decomposed, 16B/lane, LDS cross-wave reduce (NO stats) ----------------
__global__ __launch_bounds__(256) void pool2(const unsigned short* __restrict__ XC,
                                             const unsigned short* __restrict__ XO,
                                             const int* __restrict__ batch,
                                             float* __restrict__ gc, float* __restrict__ go){
  __shared__ float red[4*512];
  int g = blockIdx.x;
  int t = threadIdx.x;
  int w = t >> 6, l = t & 63;
  const unsigned short* X = blockIdx.y ? XO : XC;
  float* out = blockIdx.y ? go : gc;
  int lo = 0, hi = NN;
  while (lo < hi){ int mid = (lo+hi) >> 1; if (batch[mid] < g) lo = mid+1; else hi = mid; }
  int s = lo;
  lo = 0; hi = NN;
  while (lo < hi){ int mid = (lo+hi) >> 1; if (batch[mid] < g+1) lo = mid+1; else hi = mid; }
  int e = lo;
  float acc[8] = {0,0,0,0,0,0,0,0};
  const uint4* Xv = (const uint4*)X;
  int i = s + w;
  for (; i + 4 < e; i += 8){
    uint4 v0 = Xv[(size_t)i*64 + l];
    uint4 v1 = Xv[(size_t)(i+4)*64 + l];
    add8(acc, v0); add8(acc, v1);
  }
  for (; i < e; i += 4){
    uint4 v = Xv[(size_t)i*64 + l];
    add8(acc, v);
  }
#pragma unroll
  for (int k=0;k<8;k++) red[w*512 + l*8 + k] = acc[k];
  __syncthreads();
  int c0 = t*2, c1 = t*2+1;
  float a0 = red[c0] + red[512+c0] + red[1024+c0] + red[1536+c0];
  float a1 = red[c1] + red[512+c1] + red[1024+c1] + red[1536+c1];
  out[(size_t)g*HID + c0] = a0;
  out[(size_t)g*HID + c1] = a1;
}

// ---------------- readout BN1 stats, all 3 branches, grid (NB3,3), LDS reduce + atomic out ----------------
__global__ __launch_bounds__(256) void bnstats_r3(const float* __restrict__ gc, const float* __restrict__ go,
                                                  const int* __restrict__ perm, float* __restrict__ rst){
  __shared__ float lds[256*9];
  int br = blockIdx.y;
  int t = threadIdx.x;
  int cid = t & 127, rid = t >> 7;
  float s[4]={0,0,0,0}, q[4]={0,0,0,0};
  const int rowsPer = (NG + NB3 - 1)/NB3;
  int r0 = blockIdx.x*rowsPer, r1 = r0 + rowsPer; if (r1 > NG) r1 = NG;
  for (int r = r0 + rid; r < r1; r += 2){
    float4 v;
    if (br == 0)      v = *(const float4*)&gc[(size_t)r*HID + cid*4];
    else if (br == 1) v = *(const float4*)&go[(size_t)r*HID + cid*4];
    else {
      int ps = perm[r];
      float4 a = *(const float4*)&gc[(size_t)ps*HID + cid*4];
      float4 b = *(const float4*)&go[(size_t)r*HID + cid*4];
      v = make_float4(a.x+b.x, a.y+b.y, a.z+b.z, a.w+b.w);
    }
    float e[4] = {v.x, v.y, v.z, v.w};
#pragma unroll
    for (int i=0;i<4;i++){ s[i]+=e[i]; q[i]+=e[i]*e[i]; }
  }
  int base = (rid*128 + cid)*9;
#pragma unroll
  for (int i=0;i<4;i++){ lds[base+i]=s[i]; lds[base+4+i]=q[i]; }
  __syncthreads();
  for (int o = t; o < 1024; o += 256){
    int issq = o >> 9, col = o & 511;
    int ci = col >> 2, i = col & 3;
    float acc = lds[(0*128 + ci)*9 + issq*4 + i] + lds[(1*128 + ci)*9 + issq*4 + i];
    atomicAdd(&rst[br*1024 + issq*512 + col], acc);
  }
}

// ---------------- cast 3 branches to bf16 with inline BN from raw sums ----------------
__global__ void bncast3(const float* __restrict__ gc, const float* __restrict__ go,
                        const int* __restrict__ perm, const float* __restrict__ rst,
                        float invM, unsigned short* __restrict__ out){
  int idx = blockIdx.x*blockDim.x + threadIdx.x;
  if (idx >= 1536*128) return;
  int r = idx >> 7;
  int cg = idx & 127;
  int br = r >> 9, lr = r & 511;
  ushort4v o;
  if (lr >= NG){ o[0]=0; o[1]=0; o[2]=0; o[3]=0; }
  else {
    float4 v;
    if (br == 0)      v = *(const float4*)&gc[(size_t)lr*HID + cg*4];
    else if (br == 1) v = *(const float4*)&go[(size_t)lr*HID + cg*4];
    else {
      int ps = perm[lr];
      float4 a = *(const float4*)&gc[(size_t)ps*HID + cg*4];
      float4 b = *(const float4*)&go[(size_t)lr*HID + cg*4];
      v = make_float4(a.x+b.x, a.y+b.y, a.z+b.z, a.w+b.w);
    }
    const float* ms = rst + br*1024;
    int c = cg*4;
    float e[4] = {v.x, v.y, v.z, v.w};
#pragma unroll
    for (int i=0;i<4;i++){
      float m = ms[c+i]*invM;
      float rs = rsqrtf(ms[512+c+i]*invM - m*m + 1e-5f);
      o[i] = f2bf((e[i] - m)*rs + 1e-4f);
    }
  }
  *(ushort4v*)&out[(size_t)r*HID + cg*4] = o;
}

// ---------------- final: batched BN2 -> fc2 -> log_softmax ----------------
struct ROP { const float* W2[3]; const float* b2[3]; };
__global__ void readout_final3(const unsigned short* __restrict__ T, const float* __restrict__ statsB,
                               float invM, ROP p, float* __restrict__ out){
  int g = blockIdx.x;
  int br = blockIdx.y;
  int l = threadIdx.x;
  const float* stats = statsB + br*1024;
  const float* W2 = p.W2[br];
  const float* b2 = p.b2[br];
  float acc[NCLS];
#pragma unroll
  for (int c=0; c<NCLS; ++c) acc[c] = 0.f;
  uint4 u = ((const uint4*)(T + (size_t)(br*512 + g)*HID))[l];
  float xv[8] = {bf2f(u.x&0xffffu), bf2f(u.x>>16), bf2f(u.y&0xffffu), bf2f(u.y>>16),
                 bf2f(u.z&0xffffu), bf2f(u.z>>16), bf2f(u.w&0xffffu), bf2f(u.w>>16)};
#pragma unroll
  for (int j=0; j<8; ++j){
    int k = l*8 + j;
    float m = stats[k]*invM;
    float rs = rsqrtf(stats[512+k]*invM - m*m + 1e-5f);
    float v = (xv[j] - m)*rs + 1e-4f;
#pragma unroll
    for (int c=0; c<NCLS; ++c) acc[c] += v * W2[k*NCLS + c];
  }
  for (int m=1; m<64; m<<=1){
#pragma unroll
    for (int c=0; c<NCLS; ++c) acc[c] += __shfl_xor(acc[c], m);
  }
  if (l == 0){
    float z[NCLS];
    float mx = -1e30f;
#pragma unroll
    for (int c=0; c<NCLS; ++c){ z[c] = acc[c] + b2[c]; mx = fmaxf(mx, z[c]); }
    float s = 0.f;
#pragma unroll
    for (int c=0; c<NCLS; ++c) s += expf(z[c]-mx);
    float lse = mx + logf(s);
#pragma unroll
    for (int c=0; c<NCLS; ++c) out[(size_t)(br*NG + g)*NCLS + c] = z[c] - lse;
  }
}

extern "C" void kernel_launch(void* const* d_in, const int* in_sizes, int n_in,
                              void* d_out, int out_size, void* d_ws, size_t ws_size,
                              hipStream_t stream){
  (void)in_sizes; (void)n_in; (void)out_size;
  const float* x      = (const float*)d_in[0];
  const int*   ei     = (const int*)d_in[1];
  const int*   batch  = (const int*)d_in[2];
  const int*   perm   = (const int*)d_in[3];
  const float* convfW = (const float*)d_in[4];
  const float* convfB = (const float*)d_in[5];
  const float* convsW = (const float*)d_in[6];
  const float* convsB = (const float*)d_in[7];
  const float* eattW  = (const float*)d_in[8];
  const float* eattB  = (const float*)d_in[9];
  const float* nattW  = (const float*)d_in[10];
  const float* nattB  = (const float*)d_in[11];
  const float* ctxW   = (const float*)d_in[12];
  const float* ctxB   = (const float*)d_in[13];
  const float* objW   = (const float*)d_in[14];
  const float* objB   = (const float*)d_in[15];
  const float* fc1W[3] = {(const float*)d_in[16], (const float*)d_in[20], (const float*)d_in[24]};
  const float* fc1B[3] = {(const float*)d_in[17], (const float*)d_in[21], (const float*)d_in[25]};
  const float* fc2W[3] = {(const float*)d_in[18], (const float*)d_in[22], (const float*)d_in[26]};
  const float* fc2B[3] = {(const float*)d_in[19], (const float*)d_in[23], (const float*)d_in[27]};
  float* out = (float*)d_out;

  char* p = (char*)d_ws;
  auto alloc = [&](size_t bytes)->char*{ char* r = p; p += (bytes + 255) & ~((size_t)255); return r; };
  const int T = NE + NN;
  unsigned short* Xbf = (unsigned short*)alloc((size_t)NN*HID*2);
  unsigned short* Gbf = (unsigned short*)alloc((size_t)NN*HID*2);
  unsigned short* GbfO= (unsigned short*)alloc((size_t)NN*HID*2);
  unsigned short* XbfO= (unsigned short*)alloc((size_t)NN*HID*2);
  unsigned short* Abf = (unsigned short*)alloc((size_t)NN*FIN*2);
  unsigned short* WtF = (unsigned short*)alloc((size_t)HID*FIN*2);
  unsigned short* WtL = (unsigned short*)alloc((size_t)3*HID*HID*2);
  unsigned short* WtC = (unsigned short*)alloc((size_t)HID*HID*2);
  unsigned short* WtO = (unsigned short*)alloc((size_t)HID*HID*2);
  unsigned short* WtR = (unsigned short*)alloc((size_t)3*HID*HID*2);
  int* cnt   = (int*)alloc((size_t)NN*4);
  int* fillc = (int*)alloc((size_t)NN*4);
  int* rowp  = (int*)alloc((size_t)(NN+1)*4);
  int* bsum  = (int*)alloc(32*4);
  int* ccol  = (int*)alloc((size_t)T*4);
  int* crow  = (int*)alloc((size_t)T*4);
  int* ceid  = (int*)alloc((size_t)T*4);
  int2* cw1  = (int2*)alloc((size_t)T*8);
  float* wcv = (float*)alloc((size_t)T*4);
  float* wov = (float*)alloc((size_t)T*4);
  float* dis1 = (float*)alloc((size_t)NN*4);
  float* degc = (float*)alloc((size_t)NN*4);
  float* dego = (float*)alloc((size_t)NN*4);
  float* Sc   = (float*)alloc((size_t)NN*4);
  float* So   = (float*)alloc((size_t)NN*4);
  float* statsA = (float*)alloc((size_t)STATSA_N*4);
  float* na   = (float*)alloc((size_t)NN*2*4);
  float* eab  = (float*)alloc((size_t)NN*4*4);
  float* att  = (float*)alloc((size_t)NE*2*4);
  float* gc   = (float*)alloc((size_t)NG*HID*4);
  float* go   = (float*)alloc((size_t)NG*HID*4);
  if ((size_t)(p - (char*)d_ws) > ws_size){
    sentinel_k<<<1,1,0,stream>>>(out);
    return;
  }
  unsigned short* Abf3 = Abf;
  unsigned short* Gbf3 = GbfO;
  float* stats6 = statsA;
  float* cstat  = statsA + 6144;
  float* dstat  = statsA + 6400;
  float* rst    = statsA + 8448;
  const float invNN = 1.0f/(float)NN;
  const float invNG = 1.0f/(float)NG;
  const int GEMM_LDS = 3*8192*2;

  // setup
  W2BT wp;
  wp.src[0]=convfW; wp.dst[0]=WtF;
  for (int i=0;i<3;i++){ wp.src[1+i]=convsW+(size_t)i*HID*HID; wp.dst[1+i]=WtL+(size_t)i*HID*HID; }
  wp.src[4]=ctxW; wp.dst[4]=WtC;
  wp.src[5]=objW; wp.dst[5]=WtO;
  for (int i=0;i<3;i++){ wp.src[6+i]=fc1W[i]; wp.dst[6+i]=WtR+(size_t)i*HID*HID; }
  setup_all<<<(FIN*HID + 8*HID*HID + 255)/256, 256, 0, stream>>>(wp, cnt, fillc, degc, dego, Sc, So, statsA);

  d1_count_stats<<<BNG + (NE+1023)/1024, 1024, 0, stream>>>(ei, cnt, x, cstat);
  d2_scan<<<(NN+1023)/1024, 1024, 0, stream>>>(cnt, rowp, dis1, bsum);
  d3_scan_cast<<<20 + (NN*FIN/4 + 1023)/1024, 1024, 0, stream>>>(rowp, bsum, x, cstat, invNN, Abf);
  csr_fill<<<(T+255)/256,256,0,stream>>>(ei, rowp, cnt, fillc, dis1, ccol, crow, ceid, cw1);

  const int NBLK = ((NN+127)/128)*4;   // 628

  gemm_bt<<<NBLK,256,GEMM_LDS,stream>>>(Abf, WtF, Xbf, convfB, stats6, NN, FIN, 1,
                                        0, nullptr, nullptr, nullptr, nullptr);

  for (int i=0;i<3;i++){
    aggregate_bn<<<NN/4,256,0,stream>>>(Xbf, rowp, cw1, stats6 + i*1024, invNN, Gbf);
    gemm_bt<<<NBLK,256,GEMM_LDS,stream>>>(Gbf, WtL+(size_t)i*HID*HID, Xbf,
                                          convsB+(size_t)i*HID,
                                          (i<2) ? (stats6 + (i+1)*1024) : nullptr,
                                          NN, HID, 1, 0, nullptr, nullptr, nullptr, nullptr);
  }

  att_node<<<NN/4,256,0,stream>>>(Xbf, nattW, nattB, eattW, na, eab);
  att_edge<<<(NE+255)/256,256,0,stream>>>(ei, eab, eattB, att, degc, dego);
  wco_kernel<<<(T+255)/256,256,0,stream>>>(crow, ccol, ceid, att, degc, dego, na, wcv, wov, Sc, So);

  bnstats_dual<<<BNG,1024,0,stream>>>(Xbf, na, dstat);
  aggregate_dual<<<NN/4,256,0,stream>>>(Xbf, rowp, ccol, wcv, wov, Sc, So, dstat, invNN, Gbf, GbfO);
  gemm_bt<<<2*NBLK,256,GEMM_LDS,stream>>>(Gbf, WtC, Xbf, ctxB, nullptr, NN, HID, 1,
                                          NBLK, GbfO, WtO, XbfO, objB);
  pool2<<<dim3(NG,2),256,0,stream>>>(Xbf, XbfO, batch, gc, go);

  bnstats_r3<<<dim3(NB3,3),256,0,stream>>>(gc, go, perm, rst);
  bncast3<<<(1536*128+255)/256,256,0,stream>>>(gc, go, perm, rst, invNG, Abf3);
  FC1P fp;
  for (int i=0;i<3;i++){ fp.Bt[i] = WtR+(size_t)i*HID*HID; fp.bias[i] = fc1B[i]; }
  gemm_fc1<<<dim3(12,4),256,GEMM_LDS,stream>>>(Abf3, fp, Gbf3, stats6 + 3*1024);
  ROP rp;
  for (int i=0;i<3;i++){ rp.W2[i] = fc2W[i]; rp.b2[i] = fc2B[i]; }
  readout_final3<<<dim3(NG,3),64,0,stream>>>(Gbf3, stats6 + 3*1024, invNG, rp, out);
}

// Round 13
// 393.559 us; speedup vs baseline: 1.1925x; 1.0166x over previous
//
#include <hip/hip_runtime.h>
#include <stdint.h>

#define NN 20000
#define NE 160000
#define NG 500
#define FIN 128
#define HID 512
#define NCLS 10
#define BNG 256
#define NB3 32

typedef __attribute__((ext_vector_type(8))) short short8;
typedef __attribute__((ext_vector_type(4))) float f32x4;
typedef __attribute__((ext_vector_type(4))) unsigned short ushort4v;

__device__ __forceinline__ float bf2f(unsigned int u){
  union{unsigned int i; float f;} x; x.i = u<<16; return x.f;
}
__device__ __forceinline__ unsigned short f2bf(float f){
  union{float f; unsigned int i;} x; x.f=f;
  unsigned int r = x.i + 0x7fffu + ((x.i>>16)&1u);
  return (unsigned short)(r>>16);
}
__device__ __forceinline__ unsigned int pk2(float a, float b){
  return (unsigned int)f2bf(a) | ((unsigned int)f2bf(b) << 16);
}

__device__ __forceinline__ void gload16(unsigned short* lds, const unsigned short* g){
  __builtin_amdgcn_global_load_lds((const __attribute__((address_space(1))) unsigned int*)g,
                                   (__attribute__((address_space(3))) unsigned int*)lds,
                                   16, 0, 0);
}

__device__ __forceinline__ void fma8(float* acc, uint4 v, float w){
  acc[0] += w*bf2f(v.x & 0xffffu); acc[1] += w*bf2f(v.x >> 16);
  acc[2] += w*bf2f(v.y & 0xffffu); acc[3] += w*bf2f(v.y >> 16);
  acc[4] += w*bf2f(v.z & 0xffffu); acc[5] += w*bf2f(v.z >> 16);
  acc[6] += w*bf2f(v.w & 0xffffu); acc[7] += w*bf2f(v.w >> 16);
}
__device__ __forceinline__ void add8(float* acc, uint4 v){
  acc[0] += bf2f(v.x & 0xffffu); acc[1] += bf2f(v.x >> 16);
  acc[2] += bf2f(v.y & 0xffffu); acc[3] += bf2f(v.y >> 16);
  acc[4] += bf2f(v.z & 0xffffu); acc[5] += bf2f(v.z >> 16);
  acc[6] += bf2f(v.w & 0xffffu); acc[7] += bf2f(v.w >> 16);
}

__global__ void sentinel_k(float* out){ out[0] = 12345.0f; }

#define STATSA_N 12288

// ---------------- setup ----------------
struct W2BT { const float* src[9]; unsigned short* dst[9]; };
__global__ void setup_all(W2BT p, int* __restrict__ cnt, int* __restrict__ fillc,
                          float* __restrict__ degc, float* __restrict__ dego,
                          float* __restrict__ Sc, float* __restrict__ So,
                          float* __restrict__ statsA){
  int idx = blockIdx.x*blockDim.x + threadIdx.x;
  if (idx < FIN*HID + 8*HID*HID){
    int seg, off, K;
    if (idx < FIN*HID){ seg = 0; off = idx; K = FIN; }
    else {
      int r = idx - FIN*HID;
      seg = 1 + (r >> 18); off = r & (HID*HID-1); K = HID;
    }
    int k = off >> 9, n = off & 511;
    p.dst[seg][(size_t)n*K + k] = f2bf(p.src[seg][off]);
  }
  if (idx < NN){ cnt[idx]=0; fillc[idx]=0; degc[idx]=1.0f; dego[idx]=1.0f; Sc[idx]=0.f; So[idx]=0.f; }
  if (idx < STATSA_N) statsA[idx] = 0.f;
}

// ---------------- D1: csr_count + conv BN stats (atomic out) ----------------
__global__ __launch_bounds__(1024) void d1_count_stats(const int* __restrict__ ei, int* __restrict__ cnt,
                                                       const float* __restrict__ X, float* __restrict__ cstat){
  __shared__ float lds[1024*9];
  const int t = threadIdx.x;
  if (blockIdx.x >= BNG){
    int e = (blockIdx.x - BNG)*1024 + t;
    if (e < NE) atomicAdd(&cnt[ei[e]], 1);
    return;
  }
  const int cg = FIN >> 2;
  const int cid = t & (cg-1);
  const int rid = t / cg;
  const int rpb = 1024 / cg;
  float s0=0,s1=0,s2=0,s3=0,q0=0,q1=0,q2=0,q3=0;
  const int rowsPer = (NN + BNG - 1)/BNG;
  int r0 = blockIdx.x*rowsPer, r1 = r0 + rowsPer; if (r1 > NN) r1 = NN;
  for (int r = r0 + rid; r < r1; r += rpb){
    float4 v = *(const float4*)&X[(size_t)r*FIN + cid*4];
    s0+=v.x; q0+=v.x*v.x; s1+=v.y; q1+=v.y*v.y; s2+=v.z; q2+=v.z*v.z; s3+=v.w; q3+=v.w*v.w;
  }
  int base = (rid*cg + cid)*9;
  lds[base+0]=s0; lds[base+1]=s1; lds[base+2]=s2; lds[base+3]=s3;
  lds[base+4]=q0; lds[base+5]=q1; lds[base+6]=q2; lds[base+7]=q3;
  __syncthreads();
  if (t < cg*8){
    int ci = t >> 3, i = t & 7;
    float acc = 0.f;
    for (int g=0; g<rpb; ++g) acc += lds[(g*cg + ci)*9 + i];
    int col = ci*4 + (i & 3);
    atomicAdd(&cstat[(i < 4) ? col : FIN + col], acc);
  }
}

// ---------------- D2: rowptr scan stage 1 ----------------
__global__ __launch_bounds__(1024) void d2_scan(const int* __restrict__ cnt, int* __restrict__ rowp,
                                                float* __restrict__ dis1, int* __restrict__ bsum){
  __shared__ int buf[1024];
  int t = threadIdx.x;
  int i = blockIdx.x*1024 + t;
  int v = 0;
  if (i < NN){ v = cnt[i] + 1; dis1[i] = rsqrtf((float)v); }
  buf[t] = v;
  __syncthreads();
  for (int off=1; off<1024; off<<=1){
    int xv = (t >= off) ? buf[t-off] : 0;
    __syncthreads();
    buf[t] += xv;
    __syncthreads();
  }
  if (i < NN) rowp[i+1] = buf[t];
  if (t == 1023) bsum[blockIdx.x] = buf[1023];
}

// ---------------- D3: scan stage 2 + conv bncast (inline BN) ----------------
__global__ __launch_bounds__(1024) void d3_scan_cast(int* __restrict__ rowp, const int* __restrict__ bsum,
                                                     const float* __restrict__ X, const float* __restrict__ cstat,
                                                     float invM, unsigned short* __restrict__ out){
  __shared__ int base;
  int t = threadIdx.x;
  if (blockIdx.x < 20){
    int bx = blockIdx.x;
    if (t == 0){
      int a = 0;
      for (int b=0; b<bx; ++b) a += bsum[b];
      base = a;
    }
    __syncthreads();
    int i = bx*1024 + t;
    if (i < NN) rowp[i+1] += base;
    if (i == 0) rowp[0] = 0;
    return;
  }
  int idx = (blockIdx.x - 20)*1024 + t;
  int total4 = NN*FIN/4;
  if (idx >= total4) return;
  int b4 = idx*4;
  int c = b4 & (FIN-1);
  float4 v = *(const float4*)&X[b4];
  float e[4] = {v.x, v.y, v.z, v.w};
  ushort4v o;
#pragma unroll
  for (int i=0;i<4;i++){
    float m = cstat[c+i]*invM;
    float rs = rsqrtf(cstat[FIN+c+i]*invM - m*m + 1e-5f);
    o[i] = f2bf((e[i] - m)*rs + 1e-4f);
  }
  *(ushort4v*)&out[b4] = o;
}

// csr_fill + w1 fused
__global__ void csr_fill(const int* __restrict__ ei, const int* __restrict__ rowp,
                         const int* __restrict__ cnt, int* __restrict__ fillc,
                         const float* __restrict__ dis1,
                         int* __restrict__ ccol, int* __restrict__ crow, int* __restrict__ ceid,
                         int2* __restrict__ cw1){
  int id = blockIdx.x*blockDim.x + threadIdx.x;
  if (id < NE){
    int r = ei[id], c = ei[NE + id];
    int pos = atomicAdd(&fillc[r], 1);
    int idx = rowp[r] + pos;
    ccol[idx] = c; crow[idx] = r; ceid[idx] = id;
    cw1[idx] = make_int2(c, __float_as_int(dis1[r]*dis1[c]));
  } else if (id < NE + NN){
    int i = id - NE;
    int idx = rowp[i] + cnt[i];
    ccol[idx] = i; crow[idx] = i; ceid[idx] = -1;
    cw1[idx] = make_int2(i, __float_as_int(dis1[i]*dis1[i]));
  }
}

// ---------------- attention (bf16 X), weights staged in LDS ----------------
__global__ void att_node(const unsigned short* __restrict__ X, const float* __restrict__ nW,
                         const float* __restrict__ nb, const float* __restrict__ eW,
                         float* __restrict__ na, float* __restrict__ eab){
  __shared__ float wnl[1024], wet[1024], web[1024];
  int t = threadIdx.x;
  for (int i=t; i<1024; i+=256){ wnl[i]=nW[i]; wet[i]=eW[i]; web[i]=eW[1024+i]; }
  __syncthreads();
  int wv = blockIdx.x*4 + (t >> 6);
  int l = t & 63;
  uint4 u = ((const uint4*)(X + (size_t)wv*HID))[l];
  float xv[8] = {bf2f(u.x&0xffffu), bf2f(u.x>>16), bf2f(u.y&0xffffu), bf2f(u.y>>16),
                 bf2f(u.z&0xffffu), bf2f(u.z>>16), bf2f(u.w&0xffffu), bf2f(u.w>>16)};
  float s0=0,s1=0,s2=0,s3=0,s4=0,s5=0;
#pragma unroll
  for (int j=0; j<8; ++j){
    int k = l*8 + j;
    float x = xv[j];
    s0 += x * wnl[2*k];   s1 += x * wnl[2*k+1];
    s2 += x * wet[2*k];   s3 += x * wet[2*k+1];
    s4 += x * web[2*k];   s5 += x * web[2*k+1];
  }
  for (int m=1; m<64; m<<=1){
    s0 += __shfl_xor(s0,m); s1 += __shfl_xor(s1,m); s2 += __shfl_xor(s2,m);
    s3 += __shfl_xor(s3,m); s4 += __shfl_xor(s4,m); s5 += __shfl_xor(s5,m);
  }
  if (l == 0){
    float z0 = s0 + nb[0], z1 = s1 + nb[1];
    float mx = fmaxf(z0,z1);
    float e0 = expf(z0-mx), e1 = expf(z1-mx);
    float inv = 1.0f/(e0+e1);
    na[2*wv] = e0*inv; na[2*wv+1] = e1*inv;
    eab[4*wv] = s2; eab[4*wv+1] = s3; eab[4*wv+2] = s4; eab[4*wv+3] = s5;
  }
}

// ---------------- fused: att_edge degree accumulation + dual BN stats (blockIdx split) ----------------
__global__ __launch_bounds__(1024) void att_edge_dual(const int* __restrict__ ei,
                                                      const float* __restrict__ eab,
                                                      const float* __restrict__ eb,
                                                      float* __restrict__ degc, float* __restrict__ dego,
                                                      const unsigned short* __restrict__ X,
                                                      const float* __restrict__ na,
                                                      float* __restrict__ dstat){
  __shared__ float lds[1024*17];
  const int t = threadIdx.x;
  if (blockIdx.x >= BNG){
    int e = (blockIdx.x - BNG)*1024 + t;
    if (e < NE){
      int r = ei[e], c = ei[NE+e];
      float z0 = eab[4*r]   + eab[4*c+2] + eb[0];
      float z1 = eab[4*r+1] + eab[4*c+3] + eb[1];
      float mx = fmaxf(z0,z1);
      float e0 = expf(z0-mx), e1 = expf(z1-mx);
      float inv = 1.0f/(e0+e1);
      atomicAdd(&degc[r], e0*inv);
      atomicAdd(&dego[r], e1*inv);
    }
    return;
  }
  const int cid = t & 127;
  const int rid = t >> 7;
  float sC[4]={0,0,0,0}, qC[4]={0,0,0,0}, sO[4]={0,0,0,0}, qO[4]={0,0,0,0};
  const int rowsPer = (NN + BNG - 1)/BNG;
  int r0 = blockIdx.x*rowsPer, r1 = r0 + rowsPer; if (r1 > NN) r1 = NN;
  for (int r = r0 + rid; r < r1; r += 8){
    float a0 = na[2*r], a1 = na[2*r+1];
    uint2 u = *(const uint2*)&X[(size_t)r*HID + cid*4];
    float e[4] = {bf2f(u.x & 0xffffu), bf2f(u.x >> 16), bf2f(u.y & 0xffffu), bf2f(u.y >> 16)};
#pragma unroll
    for (int i=0;i<4;i++){
      float vc = e[i]*a0, vo = e[i]*a1;
      sC[i]+=vc; qC[i]+=vc*vc; sO[i]+=vo; qO[i]+=vo*vo;
    }
  }
  int base = (rid*128 + cid)*17;
#pragma unroll
  for (int i=0;i<4;i++){
    lds[base+i]=sC[i]; lds[base+4+i]=qC[i]; lds[base+8+i]=sO[i]; lds[base+12+i]=qO[i];
  }
  __syncthreads();
  for (int idx = t; idx < 2048; idx += 1024){
    int ci = idx >> 4, i = idx & 15;
    float acc = 0.f;
    for (int g=0; g<8; ++g) acc += lds[(g*128 + ci)*17 + i];
    int grp = i >> 2, col = ci*4 + (i & 3);
    atomicAdd(&dstat[grp*HID + col], acc);
  }
}

// wco: recompute edge softmax inline from eab (att buffer eliminated)
__global__ void wco_kernel(const int* __restrict__ crow, const int* __restrict__ ccol,
                           const int* __restrict__ ceid, const float* __restrict__ eab,
                           const float* __restrict__ eb,
                           const float* __restrict__ degc, const float* __restrict__ dego,
                           const float* __restrict__ na,
                           float* __restrict__ wcv, float* __restrict__ wov,
                           float* __restrict__ Sc, float* __restrict__ So){
  int j = blockIdx.x*blockDim.x + threadIdx.x;
  if (j >= NE + NN) return;
  int r = crow[j], c = ccol[j], e = ceid[j];
  float a0 = 1.0f, a1 = 1.0f;
  if (e >= 0){
    float z0 = eab[4*r]   + eab[4*c+2] + eb[0];
    float z1 = eab[4*r+1] + eab[4*c+3] + eb[1];
    float mx = fmaxf(z0,z1);
    float e0 = expf(z0-mx), e1 = expf(z1-mx);
    float inv = 1.0f/(e0+e1);
    a0 = e0*inv; a1 = e1*inv;
  }
  float wc = rsqrtf(degc[r]) * a0 * rsqrtf(degc[c]);
  float wo = rsqrtf(dego[r]) * a1 * rsqrtf(dego[c]);
  wcv[j] = wc * na[2*c];
  wov[j] = wo * na[2*c+1];
  atomicAdd(&Sc[r], wc);
  atomicAdd(&So[r], wo);
}

// ---------------- wave-per-row aggregation (int2 pairs), 8-deep ILP, BN affine epilogue ----------------
__global__ __launch_bounds__(256) void aggregate_bn(const unsigned short* __restrict__ A,
                                                    const int* __restrict__ rowp,
                                                    const int2* __restrict__ cw,
                                                    const float* __restrict__ stats,
                                                    float invM,
                                                    unsigned short* __restrict__ out){
  int row = blockIdx.x*4 + (threadIdx.x >> 6);
  int l = threadIdx.x & 63;
  const uint4* Av = (const uint4*)A;
  int s = rowp[row], e = rowp[row+1];
  float acc[8] = {0,0,0,0,0,0,0,0};
  float sw = 0.f;
  int j = s;
  for (; j+7 < e; j += 8){
    int2 p[8]; uint4 v[8];
#pragma unroll
    for (int k=0;k<8;k++) p[k] = cw[j+k];
#pragma unroll
    for (int k=0;k<8;k++) v[k] = Av[(size_t)p[k].x*64 + l];
#pragma unroll
    for (int k=0;k<8;k++){ float w = __int_as_float(p[k].y); fma8(acc, v[k], w); sw += w; }
  }
  for (; j+3 < e; j += 4){
    int2 p[4]; uint4 v[4];
#pragma unroll
    for (int k=0;k<4;k++) p[k] = cw[j+k];
#pragma unroll
    for (int k=0;k<4;k++) v[k] = Av[(size_t)p[k].x*64 + l];
#pragma unroll
    for (int k=0;k<4;k++){ float w = __int_as_float(p[k].y); fma8(acc, v[k], w); sw += w; }
  }
  for (; j < e; ++j){
    int2 p = cw[j];
    float w = __int_as_float(p.y);
    uint4 v = Av[(size_t)p.x*64 + l];
    fma8(acc, v, w);
    sw += w;
  }
  float g[8];
#pragma unroll
  for (int i=0;i<8;i++){
    int c = l*8 + i;
    float m = stats[c]*invM;
    float rs = rsqrtf(stats[512+c]*invM - m*m + 1e-5f);
    g[i] = rs*acc[i] + sw*(1e-4f - m*rs);
  }
  uint4 o;
  o.x = pk2(g[0],g[1]); o.y = pk2(g[2],g[3]); o.z = pk2(g[4],g[5]); o.w = pk2(g[6],g[7]);
  ((uint4*)out)[(size_t)row*64 + l] = o;
}

__global__ __launch_bounds__(256) void aggregate_dual(const unsigned short* __restrict__ A,
                                                      const int* __restrict__ rowp,
                                                      const int* __restrict__ ccol,
                                                      const float* __restrict__ wc,
                                                      const float* __restrict__ wo,
                                                      const float* __restrict__ Sc,
                                                      const float* __restrict__ So,
                                                      const float* __restrict__ dstat,
                                                      float invM,
                                                      unsigned short* __restrict__ outC,
                                                      unsigned short* __restrict__ outO){
  int row = blockIdx.x*4 + (threadIdx.x >> 6);
  int l = threadIdx.x & 63;
  const uint4* Av = (const uint4*)A;
  int s = rowp[row], e = rowp[row+1];
  float aC[8] = {0,0,0,0,0,0,0,0};
  float aO[8] = {0,0,0,0,0,0,0,0};
  int j = s;
  for (; j+7 < e; j += 8){
    int cc[8]; uint4 v[8];
#pragma unroll
    for (int k=0;k<8;k++) cc[k] = ccol[j+k];
#pragma unroll
    for (int k=0;k<8;k++) v[k] = Av[(size_t)cc[k]*64 + l];
#pragma unroll
    for (int k=0;k<8;k++){ fma8(aC, v[k], wc[j+k]); fma8(aO, v[k], wo[j+k]); }
  }
  for (; j+3 < e; j += 4){
    int cc[4]; uint4 v[4];
#pragma unroll
    for (int k=0;k<4;k++) cc[k] = ccol[j+k];
#pragma unroll
    for (int k=0;k<4;k++) v[k] = Av[(size_t)cc[k]*64 + l];
#pragma unroll
    for (int k=0;k<4;k++){ fma8(aC, v[k], wc[j+k]); fma8(aO, v[k], wo[j+k]); }
  }
  for (; j < e; ++j){
    uint4 v = Av[(size_t)ccol[j]*64 + l];
    fma8(aC, v, wc[j]); fma8(aO, v, wo[j]);
  }
  float ScR = Sc[row], SoR = So[row];
  float gC[8], gO[8];
#pragma unroll
  for (int i=0;i<8;i++){
    int c = l*8 + i;
    float mc = dstat[c]*invM;
    float rc = rsqrtf(dstat[512+c]*invM - mc*mc + 1e-5f);
    float mo = dstat[1024+c]*invM;
    float ro = rsqrtf(dstat[1536+c]*invM - mo*mo + 1e-5f);
    gC[i] = rc*aC[i] + ScR*(1e-4f - mc*rc);
    gO[i] = ro*aO[i] + SoR*(1e-4f - mo*ro);
  }
  uint4 oc, oo;
  oc.x = pk2(gC[0],gC[1]); oc.y = pk2(gC[2],gC[3]); oc.z = pk2(gC[4],gC[5]); oc.w = pk2(gC[6],gC[7]);
  oo.x = pk2(gO[0],gO[1]); oo.y = pk2(gO[2],gO[3]); oo.z = pk2(gO[4],gO[5]); oo.w = pk2(gO[6],gO[7]);
  ((uint4*)outC)[(size_t)row*64 + l] = oc;
  ((uint4*)outO)[(size_t)row*64 + l] = oo;
}

// ---------------- bf16 MFMA GEMM: XCD-chunked 1D grid, 3-buffer ring (vmcnt(8)), LDS-staged C ----------------
__global__ __launch_bounds__(256) void gemm_bt(const unsigned short* __restrict__ A,
                                               const unsigned short* __restrict__ Bt,
                                               unsigned short* __restrict__ O,
                                               const float* __restrict__ bias,
                                               float* __restrict__ stats,
                                               int M, int K, int relu, int split,
                                               const unsigned short* A2,
                                               const unsigned short* Bt2,
                                               unsigned short* O2,
                                               const float* bias2){
  extern __shared__ unsigned short smem[];
  unsigned short* Cs = smem;
  const int tid = threadIdx.x;
  const int w = tid >> 6, l = tid & 63;

  int lin = blockIdx.x;
  int total = gridDim.x;
  int q = total >> 3, r = total & 7;
  int xcd = lin & 7, idx = lin >> 3;
  int swz = (xcd < r ? xcd*(q+1) : r*(q+1) + (xcd - r)*q) + idx;
  if (split && swz >= split){ A = A2; Bt = Bt2; O = O2; bias = bias2; swz -= split; }
  const int m0 = (swz >> 2)*128, n0 = (swz & 3)*128;

  const int wm = w >> 1, wn = w & 1;
  const int lr = l & 15, lh = l >> 4;

  f32x4 acc[4][4];
#pragma unroll
  for (int i=0;i<4;i++)
#pragma unroll
    for (int j=0;j<4;j++) acc[i][j] = 0.0f;

  const int q0 = w*2, q1 = w*2+1;
  const int sub = l >> 2;
  const int kc  = (l & 3)*8;
  int ma0 = m0 + q0*16 + sub; if (ma0 >= M) ma0 = M-1;
  int ma1 = m0 + q1*16 + sub; if (ma1 >= M) ma1 = M-1;
  const int nb0 = n0 + q0*16 + sub;
  const int nb1 = n0 + q1*16 + sub;
  const unsigned short* Ar0 = A + (size_t)ma0*K + kc;
  const unsigned short* Ar1 = A + (size_t)ma1*K + kc;
  const unsigned short* Br0 = Bt + (size_t)nb0*K + kc;
  const unsigned short* Br1 = Bt + (size_t)nb1*K + kc;

  const int NT = K >> 5;
  gload16(&smem[0*8192 + q0*512], Ar0);
  gload16(&smem[0*8192 + q1*512], Ar1);
  gload16(&smem[0*8192 + 4096 + q0*512], Br0);
  gload16(&smem[0*8192 + 4096 + q1*512], Br1);
  if (NT > 1){
    gload16(&smem[1*8192 + q0*512], Ar0 + 32);
    gload16(&smem[1*8192 + q1*512], Ar1 + 32);
    gload16(&smem[1*8192 + 4096 + q0*512], Br0 + 32);
    gload16(&smem[1*8192 + 4096 + q1*512], Br1 + 32);
  }
  int cur = 0;
  for (int t=0; t<NT; ++t){
    if (t+2 < NT){
      int k1 = (t+2) << 5;
      int nb = cur + 2; if (nb >= 3) nb -= 3;
      gload16(&smem[nb*8192 + q0*512], Ar0 + k1);
      gload16(&smem[nb*8192 + q1*512], Ar1 + k1);
      gload16(&smem[nb*8192 + 4096 + q0*512], Br0 + k1);
      gload16(&smem[nb*8192 + 4096 + q1*512], Br1 + k1);
      asm volatile("s_waitcnt vmcnt(8)" ::: "memory");
    } else if (t+1 < NT){
      asm volatile("s_waitcnt vmcnt(4)" ::: "memory");
    } else {
      asm volatile("s_waitcnt vmcnt(0)" ::: "memory");
    }
    __builtin_amdgcn_s_barrier();
    asm volatile("" ::: "memory");
    short8 af[4], bfr[4];
#pragma unroll
    for (int fm=0; fm<4; ++fm) af[fm]  = *(const short8*)&smem[cur*8192 + (wm*64 + fm*16 + lr)*32 + lh*8];
#pragma unroll
    for (int fn=0; fn<4; ++fn) bfr[fn] = *(const short8*)&smem[cur*8192 + 4096 + (wn*64 + fn*16 + lr)*32 + lh*8];
#pragma unroll
    for (int fm=0; fm<4; ++fm)
#pragma unroll
      for (int fn=0; fn<4; ++fn)
        acc[fm][fn] = __builtin_amdgcn_mfma_f32_16x16x32_bf16(af[fm], bfr[fn], acc[fm][fn], 0, 0, 0);
    asm volatile("" ::: "memory");
    __builtin_amdgcn_s_barrier();
    asm volatile("" ::: "memory");
    cur += 1; if (cur >= 3) cur = 0;
  }
  int dep = __float_as_int(acc[0][0][0]);
  int z_;
  asm volatile("v_and_b32 %0, 0, %1" : "=v"(z_) : "v"(dep));
  const float* biasp = bias + z_;

  float bv[4], cs[4]={0,0,0,0}, cq[4]={0,0,0,0};
  int col[4];
#pragma unroll
  for (int fn=0; fn<4; ++fn){ col[fn] = n0 + wn*64 + fn*16 + lr; bv[fn] = biasp[col[fn]]; }
#pragma unroll
  for (int fm=0; fm<4; ++fm){
#pragma unroll
    for (int j=0; j<4; ++j){
      int trow = wm*64 + fm*16 + lh*4 + j;
      bool valid = (m0 + trow) < M;
#pragma unroll
      for (int fn=0; fn<4; ++fn){
        float v = acc[fm][fn][j] + bv[fn];
        if (relu) v = fmaxf(v, 0.f);
        Cs[trow*136 + wn*64 + fn*16 + lr] = f2bf(v);
        if (valid){ cs[fn] += v; cq[fn] += v*v; }
      }
    }
  }
  __syncthreads();
#pragma unroll
  for (int i=0;i<8;i++){
    int trow = i*16 + (tid>>4);
    int colb = (tid&15)*8;
    uint4 vv = *(const uint4*)&Cs[trow*136 + colb];
    int grow = m0 + trow;
    if (grow < M) *(uint4*)&O[(size_t)grow*HID + n0 + colb] = vv;
  }
  if (stats){
#pragma unroll
    for (int m=16; m<64; m<<=1){
#pragma unroll
      for (int fn=0; fn<4; ++fn){ cs[fn] += __shfl_xor(cs[fn], m); cq[fn] += __shfl_xor(cq[fn], m); }
    }
    if (lh == 0){
#pragma unroll
      for (int fn=0; fn<4; ++fn){
        atomicAdd(&stats[col[fn]], cs[fn]);
        atomicAdd(&stats[512+col[fn]], cq[fn]);
      }
    }
  }
}

// batched fc1 gemm: M=1536 (3 branches x 512 rows), 3-buffer ring
struct FC1P { const unsigned short* Bt[3]; const float* bias[3]; };
__global__ __launch_bounds__(256) void gemm_fc1(const unsigned short* __restrict__ A, FC1P p,
                                                unsigned short* __restrict__ O,
                                                float* __restrict__ statsB){
  extern __shared__ unsigned short smem[];
  const int tid = threadIdx.x;
  const int w = tid >> 6, l = tid & 63;
  const int m0 = blockIdx.x*128, n0 = blockIdx.y*128;
  const int branch = blockIdx.x >> 2;
  const unsigned short* Bt = p.Bt[branch];
  const float* bias = p.bias[branch];
  float* stats = statsB + branch*1024;
  const int K = HID;
  const int wm = w >> 1, wn = w & 1;
  const int lr = l & 15, lh = l >> 4;

  f32x4 acc[4][4];
#pragma unroll
  for (int i=0;i<4;i++)
#pragma unroll
    for (int j=0;j<4;j++) acc[i][j] = 0.0f;

  const int q0 = w*2, q1 = w*2+1;
  const int sub = l >> 2;
  const int kc  = (l & 3)*8;
  const int ma0 = m0 + q0*16 + sub;
  const int ma1 = m0 + q1*16 + sub;
  const int nb0 = n0 + q0*16 + sub;
  const int nb1 = n0 + q1*16 + sub;
  const unsigned short* Ar0 = A + (size_t)ma0*K + kc;
  const unsigned short* Ar1 = A + (size_t)ma1*K + kc;
  const unsigned short* Br0 = Bt + (size_t)nb0*K + kc;
  const unsigned short* Br1 = Bt + (size_t)nb1*K + kc;

  const int NT = K >> 5;
  gload16(&smem[0*8192 + q0*512], Ar0);
  gload16(&smem[0*8192 + q1*512], Ar1);
  gload16(&smem[0*8192 + 4096 + q0*512], Br0);
  gload16(&smem[0*8192 + 4096 + q1*512], Br1);
  gload16(&smem[1*8192 + q0*512], Ar0 + 32);
  gload16(&smem[1*8192 + q1*512], Ar1 + 32);
  gload16(&smem[1*8192 + 4096 + q0*512], Br0 + 32);
  gload16(&smem[1*8192 + 4096 + q1*512], Br1 + 32);
  int cur = 0;
  for (int t=0; t<NT; ++t){
    if (t+2 < NT){
      int k1 = (t+2) << 5;
      int nb = cur + 2; if (nb >= 3) nb -= 3;
      gload16(&smem[nb*8192 + q0*512], Ar0 + k1);
      gload16(&smem[nb*8192 + q1*512], Ar1 + k1);
      gload16(&smem[nb*8192 + 4096 + q0*512], Br0 + k1);
      gload16(&smem[nb*8192 + 4096 + q1*512], Br1 + k1);
      asm volatile("s_waitcnt vmcnt(8)" ::: "memory");
    } else if (t+1 < NT){
      asm volatile("s_waitcnt vmcnt(4)" ::: "memory");
    } else {
      asm volatile("s_waitcnt vmcnt(0)" ::: "memory");
    }
    __builtin_amdgcn_s_barrier();
    asm volatile("" ::: "memory");
    short8 af[4], bfr[4];
#pragma unroll
    for (int fm=0; fm<4; ++fm) af[fm]  = *(const short8*)&smem[cur*8192 + (wm*64 + fm*16 + lr)*32 + lh*8];
#pragma unroll
    for (int fn=0; fn<4; ++fn) bfr[fn] = *(const short8*)&smem[cur*8192 + 4096 + (wn*64 + fn*16 + lr)*32 + lh*8];
#pragma unroll
    for (int fm=0; fm<4; ++fm)
#pragma unroll
      for (int fn=0; fn<4; ++fn)
        acc[fm][fn] = __builtin_amdgcn_mfma_f32_16x16x32_bf16(af[fm], bfr[fn], acc[fm][fn], 0, 0, 0);
    asm volatile("" ::: "memory");
    __builtin_amdgcn_s_barrier();
    asm volatile("" ::: "memory");
    cur += 1; if (cur >= 3) cur = 0;
  }
  int dep = __float_as_int(acc[0][0][0]);
  int z_;
  asm volatile("v_and_b32 %0, 0, %1" : "=v"(z_) : "v"(dep));
  const float* biasp = bias + z_;

  float bv[4], cs[4]={0,0,0,0}, cq[4]={0,0,0,0};
  int col[4];
#pragma unroll
  for (int fn=0; fn<4; ++fn){ col[fn] = n0 + wn*64 + fn*16 + lr; bv[fn] = biasp[col[fn]]; }
#pragma unroll
  for (int fm=0; fm<4; ++fm){
#pragma unroll
    for (int j=0; j<4; ++j){
      int row = m0 + wm*64 + fm*16 + lh*4 + j;
      bool real = (row & 511) < NG;
#pragma unroll
      for (int fn=0; fn<4; ++fn){
        float v = fmaxf(acc[fm][fn][j] + bv[fn], 0.f);
        O[(size_t)row*HID + col[fn]] = f2bf(v);
        if (real){ cs[fn] += v; cq[fn] += v*v; }
      }
    }
  }
#pragma unroll
  for (int m=16; m<64; m<<=1){
#pragma unroll
    for (int fn=0; fn<4; ++fn){ cs[fn] += __shfl_xor(cs[fn], m); cq[fn] += __shfl_xor(cq[fn], m); }
  }
  if (lh == 0){
#pragma unroll
    for (int fn=0; fn<4; ++fn){
      atomicAdd(&stats[col[fn]], cs[fn]);
      atomicAdd(&stats[512+col[fn]], cq[fn]);
    }
  }
}

// ---------------- pooling: wave-decomposed, 16B/lane, LDS cross-wave reduce (NO stats) ----------------
__global__ __launch_bounds__(256) void pool2(const unsigned short* __restrict__ XC,
                                             const unsigned short* __restrict__ XO,
                                             const int* __restrict__ batch,
                                             float* __restrict__ gc, float* __restrict__ go){
  __shared__ float red[4*512];
  int g = blockIdx.x;
  int t = threadIdx.x;
  int w = t >> 6, l = t & 63;
  const unsigned short* X = blockIdx.y ? XO : XC;
  float* out = blockIdx.y ? go : gc;
  int lo = 0, hi = NN;
  while (lo < hi){ int mid = (lo+hi) >> 1; if (batch[mid] < g) lo = mid+1; else hi = mid; }
  int s = lo;
  lo = 0; hi = NN;
  while (lo < hi){ int mid = (lo+hi) >> 1; if (batch[mid] < g+1) lo = mid+1; else hi = mid; }
  int e = lo;
  float acc[8] = {0,0,0,0,0,0,0,0};
  const uint4* Xv = (const uint4*)X;
  int i = s + w;
  for (; i + 4 < e; i += 8){
    uint4 v0 = Xv[(size_t)i*64 + l];
    uint4 v1 = Xv[(size_t)(i+4)*64 + l];
    add8(acc, v0); add8(acc, v1);
  }
  for (; i < e; i += 4){
    uint4 v = Xv[(size_t)i*64 + l];
    add8(acc, v);
  }
#pragma unroll
  for (int k=0;k<8;k++) red[w*512 + l*8 + k] = acc[k];
  __syncthreads();
  int c0 = t*2, c1 = t*2+1;
  float a0 = red[c0] + red[512+c0] + red[1024+c0] + red[1536+c0];
  float a1 = red[c1] + red[512+c1] + red[1024+c1] + red[1536+c1];
  out[(size_t)g*HID + c0] = a0;
  out[(size_t)g*HID + c1] = a1;
}

// ---------------- readout BN1 stats, all 3 branches, grid (NB3,3), LDS reduce + atomic out ----------------
__global__ __launch_bounds__(256) void bnstats_r3(const float* __restrict__ gc, const float* __restrict__ go,
                                                  const int* __restrict__ perm, float* __restrict__ rst){
  __shared__ float lds[256*9];
  int br = blockIdx.y;
  int t = threadIdx.x;
  int cid = t & 127, rid = t >> 7;
  float s[4]={0,0,0,0}, q[4]={0,0,0,0};
  const int rowsPer = (NG + NB3 - 1)/NB3;
  int r0 = blockIdx.x*rowsPer, r1 = r0 + rowsPer; if (r1 > NG) r1 = NG;
  for (int r = r0 + rid; r < r1; r += 2){
    float4 v;
    if (br == 0)      v = *(const float4*)&gc[(size_t)r*HID + cid*4];
    else if (br == 1) v = *(const float4*)&go[(size_t)r*HID + cid*4];
    else {
      int ps = perm[r];
      float4 a = *(const float4*)&gc[(size_t)ps*HID + cid*4];
      float4 b = *(const float4*)&go[(size_t)r*HID + cid*4];
      v = make_float4(a.x+b.x, a.y+b.y, a.z+b.z, a.w+b.w);
    }
    float e[4] = {v.x, v.y, v.z, v.w};
#pragma unroll
    for (int i=0;i<4;i++){ s[i]+=e[i]; q[i]+=e[i]*e[i]; }
  }
  int base = (rid*128 + cid)*9;
#pragma unroll
  for (int i=0;i<4;i++){ lds[base+i]=s[i]; lds[base+4+i]=q[i]; }
  __syncthreads();
  for (int o = t; o < 1024; o += 256){
    int issq = o >> 9, col = o & 511;
    int ci = col >> 2, i = col & 3;
    float acc = lds[(0*128 + ci)*9 + issq*4 + i] + lds[(1*128 + ci)*9 + issq*4 + i];
    atomicAdd(&rst[br*1024 + issq*512 + col], acc);
  }
}

// ---------------- cast 3 branches to bf16 with inline BN from raw sums ----------------
__global__ void bncast3(const float* __restrict__ gc, const float* __restrict__ go,
                        const int* __restrict__ perm, const float* __restrict__ rst,
                        float invM, unsigned short* __restrict__ out){
  int idx = blockIdx.x*blockDim.x + threadIdx.x;
  if (idx >= 1536*128) return;
  int r = idx >> 7;
  int cg = idx & 127;
  int br = r >> 9, lr = r & 511;
  ushort4v o;
  if (lr >= NG){ o[0]=0; o[1]=0; o[2]=0; o[3]=0; }
  else {
    float4 v;
    if (br == 0)      v = *(const float4*)&gc[(size_t)lr*HID + cg*4];
    else if (br == 1) v = *(const float4*)&go[(size_t)lr*HID + cg*4];
    else {
      int ps = perm[lr];
      float4 a = *(const float4*)&gc[(size_t)ps*HID + cg*4];
      float4 b = *(const float4*)&go[(size_t)lr*HID + cg*4];
      v = make_float4(a.x+b.x, a.y+b.y, a.z+b.z, a.w+b.w);
    }
    const float* ms = rst + br*1024;
    int c = cg*4;
    float e[4] = {v.x, v.y, v.z, v.w};
#pragma unroll
    for (int i=0;i<4;i++){
      float m = ms[c+i]*invM;
      float rs = rsqrtf(ms[512+c+i]*invM - m*m + 1e-5f);
      o[i] = f2bf((e[i] - m)*rs + 1e-4f);
    }
  }
  *(ushort4v*)&out[(size_t)r*HID + cg*4] = o;
}

// ---------------- final: batched BN2 -> fc2 -> log_softmax ----------------
struct ROP { const float* W2[3]; const float* b2[3]; };
__global__ void readout_final3(const unsigned short* __restrict__ T, const float* __restrict__ statsB,
                               float invM, ROP p, float* __restrict__ out){
  int g = blockIdx.x;
  int br = blockIdx.y;
  int l = threadIdx.x;
  const float* stats = statsB + br*1024;
  const float* W2 = p.W2[br];
  const float* b2 = p.b2[br];
  float acc[NCLS];
#pragma unroll
  for (int c=0; c<NCLS; ++c) acc[c] = 0.f;
  uint4 u = ((const uint4*)(T + (size_t)(br*512 + g)*HID))[l];
  float xv[8] = {bf2f(u.x&0xffffu), bf2f(u.x>>16), bf2f(u.y&0xffffu), bf2f(u.y>>16),
                 bf2f(u.z&0xffffu), bf2f(u.z>>16), bf2f(u.w&0xffffu), bf2f(u.w>>16)};
#pragma unroll
  for (int j=0; j<8; ++j){
    int k = l*8 + j;
    float m = stats[k]*invM;
    float rs = rsqrtf(stats[512+k]*invM - m*m + 1e-5f);
    float v = (xv[j] - m)*rs + 1e-4f;
#pragma unroll
    for (int c=0; c<NCLS; ++c) acc[c] += v * W2[k*NCLS + c];
  }
  for (int m=1; m<64; m<<=1){
#pragma unroll
    for (int c=0; c<NCLS; ++c) acc[c] += __shfl_xor(acc[c], m);
  }
  if (l == 0){
    float z[NCLS];
    float mx = -1e30f;
#pragma unroll
    for (int c=0; c<NCLS; ++c){ z[c] = acc[c] + b2[c]; mx = fmaxf(mx, z[c]); }
    float s = 0.f;
#pragma unroll
    for (int c=0; c<NCLS; ++c) s += expf(z[c]-mx);
    float lse = mx + logf(s);
#pragma unroll
    for (int c=0; c<NCLS; ++c) out[(size_t)(br*NG + g)*NCLS + c] = z[c] - lse;
  }
}

extern "C" void kernel_launch(void* const* d_in, const int* in_sizes, int n_in,
                              void* d_out, int out_size, void* d_ws, size_t ws_size,
                              hipStream_t stream){
  (void)in_sizes; (void)n_in; (void)out_size;
  const float* x      = (const float*)d_in[0];
  const int*   ei     = (const int*)d_in[1];
  const int*   batch  = (const int*)d_in[2];
  const int*   perm   = (const int*)d_in[3];
  const float* convfW = (const float*)d_in[4];
  const float* convfB = (const float*)d_in[5];
  const float* convsW = (const float*)d_in[6];
  const float* convsB = (const float*)d_in[7];
  const float* eattW  = (const float*)d_in[8];
  const float* eattB  = (const float*)d_in[9];
  const float* nattW  = (const float*)d_in[10];
  const float* nattB  = (const float*)d_in[11];
  const float* ctxW   = (const float*)d_in[12];
  const float* ctxB   = (const float*)d_in[13];
  const float* objW   = (const float*)d_in[14];
  const float* objB   = (const float*)d_in[15];
  const float* fc1W[3] = {(const float*)d_in[16], (const float*)d_in[20], (const float*)d_in[24]};
  const float* fc1B[3] = {(const float*)d_in[17], (const float*)d_in[21], (const float*)d_in[25]};
  const float* fc2W[3] = {(const float*)d_in[18], (const float*)d_in[22], (const float*)d_in[26]};
  const float* fc2B[3] = {(const float*)d_in[19], (const float*)d_in[23], (const float*)d_in[27]};
  float* out = (float*)d_out;

  char* p = (char*)d_ws;
  auto alloc = [&](size_t bytes)->char*{ char* r = p; p += (bytes + 255) & ~((size_t)255); return r; };
  const int T = NE + NN;
  unsigned short* Xbf = (unsigned short*)alloc((size_t)NN*HID*2);
  unsigned short* Gbf = (unsigned short*)alloc((size_t)NN*HID*2);
  unsigned short* GbfO= (unsigned short*)alloc((size_t)NN*HID*2);
  unsigned short* XbfO= (unsigned short*)alloc((size_t)NN*HID*2);
  unsigned short* Abf = (unsigned short*)alloc((size_t)NN*FIN*2);
  unsigned short* WtF = (unsigned short*)alloc((size_t)HID*FIN*2);
  unsigned short* WtL = (unsigned short*)alloc((size_t)3*HID*HID*2);
  unsigned short* WtC = (unsigned short*)alloc((size_t)HID*HID*2);
  unsigned short* WtO = (unsigned short*)alloc((size_t)HID*HID*2);
  unsigned short* WtR = (unsigned short*)alloc((size_t)3*HID*HID*2);
  int* cnt   = (int*)alloc((size_t)NN*4);
  int* fillc = (int*)alloc((size_t)NN*4);
  int* rowp  = (int*)alloc((size_t)(NN+1)*4);
  int* bsum  = (int*)alloc(32*4);
  int* ccol  = (int*)alloc((size_t)T*4);
  int* crow  = (int*)alloc((size_t)T*4);
  int* ceid  = (int*)alloc((size_t)T*4);
  int2* cw1  = (int2*)alloc((size_t)T*8);
  float* wcv = (float*)alloc((size_t)T*4);
  float* wov = (float*)alloc((size_t)T*4);
  float* dis1 = (float*)alloc((size_t)NN*4);
  float* degc = (float*)alloc((size_t)NN*4);
  float* dego = (float*)alloc((size_t)NN*4);
  float* Sc   = (float*)alloc((size_t)NN*4);
  float* So   = (float*)alloc((size_t)NN*4);
  float* statsA = (float*)alloc((size_t)STATSA_N*4);
  float* na   = (float*)alloc((size_t)NN*2*4);
  float* eab  = (float*)alloc((size_t)NN*4*4);
  float* gc   = (float*)alloc((size_t)NG*HID*4);
  float* go   = (float*)alloc((size_t)NG*HID*4);
  if ((size_t)(p - (char*)d_ws) > ws_size){
    sentinel_k<<<1,1,0,stream>>>(out);
    return;
  }
  unsigned short* Abf3 = Abf;
  unsigned short* Gbf3 = GbfO;
  float* stats6 = statsA;
  float* cstat  = statsA + 6144;
  float* dstat  = statsA + 6400;
  float* rst    = statsA + 8448;
  const float invNN = 1.0f/(float)NN;
  const float invNG = 1.0f/(float)NG;
  const int GEMM_LDS = 3*8192*2;

  // setup
  W2BT wp;
  wp.src[0]=convfW; wp.dst[0]=WtF;
  for (int i=0;i<3;i++){ wp.src[1+i]=convsW+(size_t)i*HID*HID; wp.dst[1+i]=WtL+(size_t)i*HID*HID; }
  wp.src[4]=ctxW; wp.dst[4]=WtC;
  wp.src[5]=objW; wp.dst[5]=WtO;
  for (int i=0;i<3;i++){ wp.src[6+i]=fc1W[i]; wp.dst[6+i]=WtR+(size_t)i*HID*HID; }
  setup_all<<<(FIN*HID + 8*HID*HID + 255)/256, 256, 0, stream>>>(wp, cnt, fillc, degc, dego, Sc, So, statsA);

  d1_count_stats<<<BNG + (NE+1023)/1024, 1024, 0, stream>>>(ei, cnt, x, cstat);
  d2_scan<<<(NN+1023)/1024, 1024, 0, stream>>>(cnt, rowp, dis1, bsum);
  d3_scan_cast<<<20 + (NN*FIN/4 + 1023)/1024, 1024, 0, stream>>>(rowp, bsum, x, cstat, invNN, Abf);
  csr_fill<<<(T+255)/256,256,0,stream>>>(ei, rowp, cnt, fillc, dis1, ccol, crow, ceid, cw1);

  const int NBLK = ((NN+127)/128)*4;   // 628

  gemm_bt<<<NBLK,256,GEMM_LDS,stream>>>(Abf, WtF, Xbf, convfB, stats6, NN, FIN, 1,
                                        0, nullptr, nullptr, nullptr, nullptr);

  for (int i=0;i<3;i++){
    aggregate_bn<<<NN/4,256,0,stream>>>(Xbf, rowp, cw1, stats6 + i*1024, invNN, Gbf);
    gemm_bt<<<NBLK,256,GEMM_LDS,stream>>>(Gbf, WtL+(size_t)i*HID*HID, Xbf,
                                          convsB+(size_t)i*HID,
                                          (i<2) ? (stats6 + (i+1)*1024) : nullptr,
                                          NN, HID, 1, 0, nullptr, nullptr, nullptr, nullptr);
  }

  att_node<<<NN/4,256,0,stream>>>(Xbf, nattW, nattB, eattW, na, eab);
  // fused: edge-degree accumulation + dual BN stats (both depend only on att_node)
  att_edge_dual<<<BNG + (NE+1023)/1024, 1024, 0, stream>>>(ei, eab, eattB, degc, dego, Xbf, na, dstat);
  wco_kernel<<<(T+255)/256,256,0,stream>>>(crow, ccol, ceid, eab, eattB, degc, dego, na, wcv, wov, Sc, So);

  aggregate_dual<<<NN/4,256,0,stream>>>(Xbf, rowp, ccol, wcv, wov, Sc, So, dstat, invNN, Gbf, GbfO);
  gemm_bt<<<2*NBLK,256,GEMM_LDS,stream>>>(Gbf, WtC, Xbf, ctxB, nullptr, NN, HID, 1,
                                          NBLK, GbfO, WtO, XbfO, objB);
  pool2<<<dim3(NG,2),256,0,stream>>>(Xbf, XbfO, batch, gc, go);

  bnstats_r3<<<dim3(NB3,3),256,0,stream>>>(gc, go, perm, rst);
  bncast3<<<(1536*128+255)/256,256,0,stream>>>(gc, go, perm, rst, invNG, Abf3);
  FC1P fp;
  for (int i=0;i<3;i++){ fp.Bt[i] = WtR+(size_t)i*HID*HID; fp.bias[i] = fc1B[i]; }
  gemm_fc1<<<dim3(12,4),256,GEMM_LDS,stream>>>(Abf3, fp, Gbf3, stats6 + 3*1024);
  ROP rp;
  for (int i=0;i<3;i++){ rp.W2[i] = fc2W[i]; rp.b2[i] = fc2B[i]; }
  readout_final3<<<dim3(NG,3),64,0,stream>>>(Gbf3, stats6 + 3*1024, invNG, rp, out);
}